// Round 11
// baseline (1749.394 us; speedup 1.0000x reference)
//
#include <hip/hip_runtime.h>
#include <hip/hip_bf16.h>

typedef __hip_bfloat16 bf16;
typedef __attribute__((ext_vector_type(8))) short bf16x8;
typedef __attribute__((ext_vector_type(4))) float f32x4;

#define NN 30000      // nodes
#define NE 240000     // edges
#define NG 1500       // graphs
#define EMB 300
#define HID 600
#define NTASK 12
#define SEM 320       // padded stride for EMB-dim tensors
#define SHID 608      // padded stride for HID-dim tensors
#define CG 75         // 4-channel groups (EMB/4) — 75 thr/node: best TLP (round-9 lesson)
#define NBLK_SCAN 118 // (NN+255)/256

__device__ __forceinline__ float tof(bf16 v){ return __bfloat162float(v); }
__device__ __forceinline__ bf16  tob(float v){ return __float2bfloat16(v); }
__device__ __forceinline__ float b2f(unsigned short u){ return __uint_as_float(((unsigned)u)<<16); }

// ---------------- utility ----------------
__global__ __launch_bounds__(256) void k_zero_i(int* __restrict__ p, int n){
    int i = blockIdx.x*256 + threadIdx.x;
    if (i < n) p[i] = 0;
}

// ---------------- CSR build (by dst) ----------------
__global__ __launch_bounds__(256) void k_hist(const int* __restrict__ dst, int* __restrict__ deg){
    int e = blockIdx.x*256 + threadIdx.x;
    if (e < NE) atomicAdd(&deg[dst[e]], 1);
}

__global__ __launch_bounds__(256) void k_scanA(const int* __restrict__ deg, int* __restrict__ bsum){
    __shared__ int red[256];
    int b = blockIdx.x, t = threadIdx.x;
    int i = b*256 + t;
    red[t] = (i < NN) ? deg[i] : 0;
    __syncthreads();
    for (int off=128; off>0; off>>=1){ if (t<off) red[t]+=red[t+off]; __syncthreads(); }
    if (t==0) bsum[b] = red[0];
}

__global__ __launch_bounds__(128) void k_scanB(const int* __restrict__ bsum, int* __restrict__ boff){
    __shared__ int s[128];
    int t = threadIdx.x;
    int v = (t < NBLK_SCAN) ? bsum[t] : 0;
    s[t] = v;
    __syncthreads();
    for (int off=1; off<128; off<<=1){
        int add = (t>=off) ? s[t-off] : 0;
        __syncthreads();
        s[t] += add;
        __syncthreads();
    }
    if (t < NBLK_SCAN) boff[t] = s[t] - v;   // exclusive
}

__global__ __launch_bounds__(256) void k_scanC(const int* __restrict__ deg, const int* __restrict__ boff,
                                               int* __restrict__ indptr, int* __restrict__ cursor){
    __shared__ int s[256];
    int b = blockIdx.x, t = threadIdx.x;
    int i = b*256 + t;
    int v = (i < NN) ? deg[i] : 0;
    s[t] = v;
    __syncthreads();
    for (int off=1; off<256; off<<=1){
        int add = (t>=off) ? s[t-off] : 0;
        __syncthreads();
        s[t] += add;
        __syncthreads();
    }
    int excl = s[t] - v + boff[b];
    if (i < NN){ indptr[i] = excl; cursor[i] = excl; }
    if (i == 0) indptr[NN] = NE;
}

__global__ __launch_bounds__(256) void k_scatter(const int* __restrict__ dst, int* __restrict__ cursor,
                                                 int* __restrict__ eid){
    int e = blockIdx.x*256 + threadIdx.x;
    if (e < NE){ int p = atomicAdd(&cursor[dst[e]], 1); eid[p] = e; }
}

__global__ __launch_bounds__(256) void k_eprep(const int* __restrict__ eid, const int* __restrict__ src,
                                               const float* __restrict__ eattr, float4* __restrict__ epack){
    int k = blockIdx.x*256 + threadIdx.x;
    if (k >= NE) return;
    int e = eid[k];
    float4 p;
    p.x = __int_as_float(src[e]);
    p.y = eattr[e*3]; p.z = eattr[e*3+1]; p.w = eattr[e*3+2];
    epack[k] = p;
}

__global__ __launch_bounds__(256) void k_gstart(const int* __restrict__ batch, int* __restrict__ gstart){
    int g = blockIdx.x*256 + threadIdx.x;
    if (g > NG) return;
    if (g == NG){ gstart[NG] = NN; return; }
    int lo=0, hi=NN;
    while (lo<hi){ int mid=(lo+hi)>>1; if (batch[mid] < g) lo=mid+1; else hi=mid; }
    gstart[g] = lo;
}

// ---------------- weight prep: Wt[n][kp] bf16 = W[k][n] fp32, zero-padded k>=K ----------------
__global__ __launch_bounds__(256) void k_wprep(const float* __restrict__ W, bf16* __restrict__ Wt,
                                               int K, int Kp, int N){
    __shared__ float t[32][33];
    const float* Wz = W + (size_t)blockIdx.z*K*N;
    bf16* Wtz = Wt + (size_t)blockIdx.z*N*Kp;
    int n0 = blockIdx.x*32, k0 = blockIdx.y*32;
    int tx = threadIdx.x & 31, ty = threadIdx.x >> 5;
    #pragma unroll
    for (int i=0;i<4;i++){
        int k = k0 + ty + i*8, n = n0 + tx;
        t[ty+i*8][tx] = (k<K && n<N) ? Wz[(size_t)k*N+n] : 0.f;
    }
    __syncthreads();
    #pragma unroll
    for (int i=0;i<4;i++){
        int n = n0 + ty + i*8, k = k0 + tx;
        if (n<N && k<Kp) Wtz[(size_t)n*Kp+k] = tob(t[tx][ty+i*8]);
    }
}

// ---------------- node encoder ----------------
__global__ __launch_bounds__(256) void k_encoder(const float* __restrict__ x, const float* __restrict__ W,
                                                 const float* __restrict__ b, bf16* __restrict__ xfeat){
    int idx = blockIdx.x*256 + threadIdx.x;
    if (idx >= NN*EMB) return;
    int n = idx / EMB, c = idx - n*EMB;
    float acc = b[c];
    #pragma unroll
    for (int k=0;k<9;k++) acc += x[n*9+k] * W[k*EMB+c];
    xfeat[(size_t)n*SEM + c] = tob(acc);
}

// ---------------- agg: thread=(node, 4-ch group); 2-deep epack+gather pipeline ----------------
__global__ __launch_bounds__(256) void k_agg4(const bf16* __restrict__ cur, const float* __restrict__ We,
                      const float* __restrict__ be, const float4* __restrict__ epack,
                      const int* __restrict__ indptr, bf16* __restrict__ apx){
    int idx = blockIdx.x*256 + threadIdx.x;
    if (idx >= NN*CG) return;
    int n = idx / CG, cg = idx - n*CG;
    int c0 = cg*4;
    float w0[4], w1[4], w2[4], bbv[4], acc[4];
    #pragma unroll
    for (int j=0;j<4;j++){
        w0[j] = We[c0+j]; w1[j] = We[EMB+c0+j]; w2[j] = We[2*EMB+c0+j]; bbv[j] = be[c0+j];
    }
    ushort4 hs = *(const ushort4*)&cur[(size_t)n*SEM + c0];
    acc[0]=b2f(hs.x); acc[1]=b2f(hs.y); acc[2]=b2f(hs.z); acc[3]=b2f(hs.w);
    int k  = indptr[n], k1 = indptr[n+1];

    auto accum4 = [&](float4 e0, float4 e1, float4 e2, float4 e3,
                      ushort4 ha, ushort4 hb, ushort4 hc, ushort4 hd){
        float fa[4] = {b2f(ha.x), b2f(ha.y), b2f(ha.z), b2f(ha.w)};
        float fb[4] = {b2f(hb.x), b2f(hb.y), b2f(hb.z), b2f(hb.w)};
        float fc[4] = {b2f(hc.x), b2f(hc.y), b2f(hc.z), b2f(hc.w)};
        float fd[4] = {b2f(hd.x), b2f(hd.y), b2f(hd.z), b2f(hd.w)};
        #pragma unroll
        for (int j=0;j<4;j++){
            float va = fa[j] + e0.y*w0[j] + e0.z*w1[j] + e0.w*w2[j] + bbv[j];
            float vb = fb[j] + e1.y*w0[j] + e1.z*w1[j] + e1.w*w2[j] + bbv[j];
            float vc = fc[j] + e2.y*w0[j] + e2.z*w1[j] + e2.w*w2[j] + bbv[j];
            float vd = fd[j] + e3.y*w0[j] + e3.z*w1[j] + e3.w*w2[j] + bbv[j];
            acc[j] += fmaxf(va, 0.f) + fmaxf(vb, 0.f) + fmaxf(vc, 0.f) + fmaxf(vd, 0.f);
        }
    };

    if (k + 4 <= k1){
        float4 e0 = epack[k], e1 = epack[k+1], e2 = epack[k+2], e3 = epack[k+3];
        ushort4 h0 = *(const ushort4*)&cur[(size_t)__float_as_int(e0.x)*SEM + c0];
        ushort4 h1 = *(const ushort4*)&cur[(size_t)__float_as_int(e1.x)*SEM + c0];
        ushort4 h2 = *(const ushort4*)&cur[(size_t)__float_as_int(e2.x)*SEM + c0];
        ushort4 h3 = *(const ushort4*)&cur[(size_t)__float_as_int(e3.x)*SEM + c0];
        while (k + 8 <= k1){
            float4 f0 = epack[k+4], f1 = epack[k+5], f2 = epack[k+6], f3 = epack[k+7];
            ushort4 g0 = *(const ushort4*)&cur[(size_t)__float_as_int(f0.x)*SEM + c0];
            ushort4 g1 = *(const ushort4*)&cur[(size_t)__float_as_int(f1.x)*SEM + c0];
            ushort4 g2 = *(const ushort4*)&cur[(size_t)__float_as_int(f2.x)*SEM + c0];
            ushort4 g3 = *(const ushort4*)&cur[(size_t)__float_as_int(f3.x)*SEM + c0];
            accum4(e0,e1,e2,e3, h0,h1,h2,h3);
            e0=f0; e1=f1; e2=f2; e3=f3;
            h0=g0; h1=g1; h2=g2; h3=g3;
            k += 4;
        }
        accum4(e0,e1,e2,e3, h0,h1,h2,h3);
        k += 4;
    }
    for (; k < k1; k++){
        float4 e0 = epack[k];
        int s0 = __float_as_int(e0.x);
        ushort4 ha = *(const ushort4*)&cur[(size_t)s0*SEM + c0];
        float fa[4] = {b2f(ha.x), b2f(ha.y), b2f(ha.z), b2f(ha.w)};
        #pragma unroll
        for (int j=0;j<4;j++){
            float va = fa[j] + e0.y*w0[j] + e0.z*w1[j] + e0.w*w2[j] + bbv[j];
            acc[j] += fmaxf(va, 0.f);
        }
    }
    ushort4 o;
    o.x = __bfloat16_as_ushort(tob(acc[0]));
    o.y = __bfloat16_as_ushort(tob(acc[1]));
    o.z = __bfloat16_as_ushort(tob(acc[2]));
    o.w = __bfloat16_as_ushort(tob(acc[3]));
    *(ushort4*)&apx[(size_t)n*SEM + c0] = o;
}

// ---------------- pipelined MFMA bf16 GEMM, templated on n-frags/wave ----------------
// NF=4: TN=128 (as round 10); NF=8: TN=256 (2x MFMA/barrier, fewer A re-fetches)
// C[M][ldc] = bf16( [relu](A[M][Kp] @ Bt[N][Kp]^T + bias[N]) [+ R[M][ldc]] )
template<int NF>
__global__ __launch_bounds__(256) void k_gemmT(const bf16* __restrict__ A, const bf16* __restrict__ Bt,
        const float* __restrict__ bias, const bf16* __restrict__ R, bf16* __restrict__ C,
        int M, int N, int Kp, int ldc, int relu_out){
    constexpr int TN = NF*32;
    constexpr int SB = (TN*4)/256;        // B 16B-segs per thread (2 or 4)
    constexpr int PASSES = NF/4;          // epilogue 128-col passes
    __shared__ __align__(16) char ldsbuf[34816];   // staging (8K A + up to 16K B) / C-tile 128x136
    short (*Asl)[64][8] = reinterpret_cast<short(*)[64][8]>(ldsbuf);
    short (*Bsl)[64][8] = reinterpret_cast<short(*)[64][8]>(ldsbuf + 8192);
    short* Ct = reinterpret_cast<short*>(ldsbuf);
    const int CS = 136;
    int tid = threadIdx.x;
    int wave = tid >> 6, lane = tid & 63;
    int wm = wave >> 1, wn = wave & 1;
    int m0 = blockIdx.y*128, n0 = blockIdx.x*TN;

    // A staging: 2 segs/thread
    int arow = tid >> 1, aq = (tid & 1)*2;
    int grA = min(m0 + arow, M-1);
    const bf16* pA = A + (size_t)grA*Kp + aq*8;
    short* ldsA0 = &Asl[arow>>4][ aq   *16 + (arow&15)][0];
    short* ldsA1 = &Asl[arow>>4][(aq+1)*16 + (arow&15)][0];
    // B staging: SB segs/thread (contiguous in k for SB=4)
    const bf16* pB[SB]; short* ldsB[SB];
    #pragma unroll
    for (int s=0;s<SB;s++){
        int g = tid*SB + s; int br = g >> 2, bq = g & 3;
        int grB = min(n0 + br, N-1);
        pB[s] = Bt + (size_t)grB*Kp + bq*8;
        ldsB[s] = &Bsl[br>>4][bq*16 + (br&15)][0];
    }

    f32x4 acc[4][NF];
    #pragma unroll
    for (int i=0;i<4;i++){
        #pragma unroll
        for (int j=0;j<NF;j++) acc[i][j] = (f32x4){0.f,0.f,0.f,0.f};
    }

    int KC = Kp >> 5;
    uint4 ra0 = *(const uint4*)pA;
    uint4 ra1 = *(const uint4*)(pA + 8);
    uint4 rb[SB];
    #pragma unroll
    for (int s=0;s<SB;s++) rb[s] = *(const uint4*)pB[s];

    for (int kc=0; kc<KC; ++kc){
        *(uint4*)ldsA0 = ra0; *(uint4*)ldsA1 = ra1;
        #pragma unroll
        for (int s=0;s<SB;s++) *(uint4*)ldsB[s] = rb[s];
        __syncthreads();
        if (kc+1 < KC){
            const bf16* qA = pA + (kc+1)*32;
            ra0 = *(const uint4*)(qA); ra1 = *(const uint4*)(qA+8);
            #pragma unroll
            for (int s=0;s<SB;s++) rb[s] = *(const uint4*)(pB[s] + (kc+1)*32);
        }
        bf16x8 af[4], bfr[NF];
        #pragma unroll
        for (int i=0;i<4;i++) af[i]  = *(const bf16x8*)&Asl[wm*4+i][lane][0];
        #pragma unroll
        for (int j=0;j<NF;j++) bfr[j] = *(const bf16x8*)&Bsl[wn*NF+j][lane][0];
        #pragma unroll
        for (int i=0;i<4;i++){
            #pragma unroll
            for (int j=0;j<NF;j++)
                acc[i][j] = __builtin_amdgcn_mfma_f32_16x16x32_bf16(af[i], bfr[j], acc[i][j], 0, 0, 0);
        }
        __syncthreads();
    }

    // epilogue: PASSES x 128-col coalesced stores via LDS C-tile
    int lq = lane >> 4, lr = lane & 15;
    #pragma unroll
    for (int h=0; h<PASSES; h++){
        if (PASSES == 1 || wn == h){
            #pragma unroll
            for (int i=0;i<4;i++){
                int rl = (wm*4+i)*16 + lq*4;
                #pragma unroll
                for (int j=0;j<NF;j++){
                    int fl = (PASSES==1) ? (wn*4+j) : j;   // local frag within this 128-col pass
                    int cl = fl*16 + lr;
                    int gcol = n0 + h*128 + cl;
                    float bv = bias[min(gcol, N-1)];
                    #pragma unroll
                    for (int r=0;r<4;r++){
                        float v = acc[i][j][r] + bv;
                        if (relu_out) v = fmaxf(v, 0.f);
                        Ct[(rl+r)*CS + cl] = (short)__bfloat16_as_ushort(tob(v));
                    }
                }
            }
        }
        __syncthreads();
        #pragma unroll
        for (int p=0;p<8;p++){
            int rl = p*16 + (tid>>4);
            int cl = (tid&15)*8;
            int row = m0 + rl, col = n0 + h*128 + cl;
            if (row < M && col < N){
                union { short s8[8]; uint4 v; } u;
                u.v = *(uint4*)&Ct[rl*CS + cl];
                if (R){
                    const bf16* rp = &R[(size_t)row*ldc + col];
                    #pragma unroll
                    for (int e=0;e<8;e++){
                        float v = b2f((unsigned short)u.s8[e]) + tof(rp[e]);
                        u.s8[e] = (short)__bfloat16_as_ushort(tob(v));
                    }
                }
                *(uint4*)&C[(size_t)row*ldc + col] = u.v;
            }
        }
        if (h+1 < PASSES) __syncthreads();
    }
}

// ---------------- old-style MFMA machinery (kept for k_sim_mfma) ----------------
__device__ __forceinline__ void stage_tile(const short* __restrict__ P, int RB, int K, int r0, int k0,
                                           short (*lds)[64][8], int tid){
    #pragma unroll
    for (int s=0;s<2;s++){
        int seg = tid*2+s;
        int row = seg>>2, q = seg&3;
        int gr = r0 + row;
        int gk = k0 + q*8;
        union { short s8[8]; uint4 v; } u;
        if (gr < RB && gk + 8 <= K){
            const uint2* p = (const uint2*)(P + (size_t)gr*K + gk);
            uint2 lo = p[0], hi = p[1];
            u.v.x = lo.x; u.v.y = lo.y; u.v.z = hi.x; u.v.w = hi.y;
        } else {
            #pragma unroll
            for (int j=0;j<8;j++){
                int kk = gk + j;
                u.s8[j] = (gr < RB && kk < K) ? P[(size_t)gr*K + kk] : (short)0;
            }
        }
        *(uint4*)&lds[row>>4][q*16 + (row&15)][0] = u.v;
    }
}

// sim_cp[i][j] = exp( (hr_i . henv_j) * 5 / (na_i*nc_j + 1e-8) )
__global__ __launch_bounds__(256) void k_sim_mfma(const bf16* __restrict__ A, const bf16* __restrict__ Bt,
                      const float* __restrict__ na, const float* __restrict__ nc, float* __restrict__ C){
    __shared__ __align__(16) short Asl[8][64][8];
    __shared__ __align__(16) short Bsl[8][64][8];
    int tid = threadIdx.x;
    int wave = tid >> 6, lane = tid & 63;
    int wm = wave >> 1, wn = wave & 1;
    int m0 = blockIdx.y*128, n0 = blockIdx.x*128;
    f32x4 acc[4][4];
    #pragma unroll
    for (int i=0;i<4;i++){
        #pragma unroll
        for (int j=0;j<4;j++) acc[i][j] = (f32x4){0.f,0.f,0.f,0.f};
    }
    for (int k0=0; k0<SEM; k0+=32){
        stage_tile((const short*)A,  NG, SEM, m0, k0, Asl, tid);
        stage_tile((const short*)Bt, NG, SEM, n0, k0, Bsl, tid);
        __syncthreads();
        bf16x8 af[4], bfr[4];
        #pragma unroll
        for (int i=0;i<4;i++) af[i]  = *(const bf16x8*)&Asl[wm*4+i][lane][0];
        #pragma unroll
        for (int j=0;j<4;j++) bfr[j] = *(const bf16x8*)&Bsl[wn*4+j][lane][0];
        #pragma unroll
        for (int i=0;i<4;i++){
            #pragma unroll
            for (int j=0;j<4;j++)
                acc[i][j] = __builtin_amdgcn_mfma_f32_16x16x32_bf16(af[i], bfr[j], acc[i][j], 0, 0, 0);
        }
        __syncthreads();
    }
    int lq = lane >> 4, lr = lane & 15;
    #pragma unroll
    for (int i=0;i<4;i++){
        int rb = m0 + (wm*4+i)*16 + lq*4;
        #pragma unroll
        for (int j=0;j<4;j++){
            int col = n0 + (wn*4+j)*16 + lr;
            if (col >= NG) continue;
            float ncj = nc[col];
            #pragma unroll
            for (int r=0;r<4;r++){
                int row = rb + r;
                if (row >= NG) continue;
                C[(size_t)row*NG+col] = expf(acc[i][j][r] * 5.0f / (na[row]*ncj + 1e-8f));
            }
        }
    }
}

// ---------------- gate ----------------
__global__ __launch_bounds__(256) void k_gate(const bf16* __restrict__ mid, const float* __restrict__ Wg2,
                      const float* __restrict__ bg2, const float* __restrict__ gumbel, float* __restrict__ gate){
    int gw = blockIdx.x*4 + (threadIdx.x >> 6);
    int lane = threadIdx.x & 63;
    if (gw >= NN) return;
    float s0=0.f, s1=0.f;
    for (int i=lane;i<HID;i+=64){
        float h = tof(mid[(size_t)gw*SHID+i]);
        s0 += h * Wg2[i*2];
        s1 += h * Wg2[i*2+1];
    }
    for (int off=32; off>0; off>>=1){ s0 += __shfl_down(s0, off); s1 += __shfl_down(s1, off); }
    if (lane==0){
        float l0 = s0 + bg2[0] + gumbel[gw*2];
        float l1 = s1 + bg2[1] + gumbel[gw*2+1];
        float m = fmaxf(l0,l1);
        float e0 = expf(l0-m), e1 = expf(l1-m);
        gate[gw] = e1/(e0+e1);
    }
}

// ---------------- segment pooling ----------------
__global__ __launch_bounds__(320) void k_pool(const bf16* __restrict__ h, const float* __restrict__ gate,
                      const int* __restrict__ gstart, float* __restrict__ sumh, float* __restrict__ sumgh){
    int g = blockIdx.x, c = threadIdx.x;
    if (c >= EMB) return;
    int n0 = gstart[g], n1 = gstart[g+1];
    float sh=0.f, sg=0.f;
    for (int n=n0;n<n1;n++){
        float v = tof(h[(size_t)n*SEM+c]);
        float gt = gate[n];
        sh += v; sg += gt*v;
    }
    sumh[g*EMB+c] = sh; sumgh[g*EMB+c] = sg;
}

__global__ __launch_bounds__(256) void k_rnum(const float* __restrict__ gate, const int* __restrict__ gstart,
                      float* __restrict__ rnum, float* __restrict__ cntf){
    int g = blockIdx.x*4 + (threadIdx.x >> 6);
    int lane = threadIdx.x & 63;
    if (g >= NG) return;
    int n0 = gstart[g], n1 = gstart[g+1];
    float s=0.f;
    for (int n=n0+lane;n<n1;n+=64) s += gate[n];
    for (int off=32; off>0; off>>=1) s += __shfl_down(s, off);
    if (lane==0){ rnum[g] = s; cntf[g] = (float)(n1-n0); }
}

__global__ __launch_bounds__(256) void k_mean(const float* __restrict__ sumh, const float* __restrict__ sumgh,
                      const float* __restrict__ cntf, float* __restrict__ hr, float* __restrict__ henv,
                      float* __restrict__ hout, bf16* __restrict__ hrb, bf16* __restrict__ henvb){
    int idx = blockIdx.x*256 + threadIdx.x;
    if (idx >= NG*SEM) return;
    int g = idx / SEM, c = idx - g*SEM;
    if (c < EMB){
        int o = g*EMB + c;
        float inv = 1.f / fmaxf(cntf[g], 1.f);
        float sh = sumh[o], sg = sumgh[o];
        float r = sg*inv, e = (sh-sg)*inv;
        hr[o] = r; henv[o] = e; hout[o] = sh*inv;
        hrb[idx] = tob(r); henvb[idx] = tob(e);
    } else {
        hrb[idx] = tob(0.f); henvb[idx] = tob(0.f);   // zero pads (henvb is a B-operand!)
    }
}

__global__ __launch_bounds__(256) void k_pbuild(const float* __restrict__ hr, const float* __restrict__ henv,
                      const int* __restrict__ perm, bf16* __restrict__ P){
    int idx = blockIdx.x*256 + threadIdx.x;
    if (idx >= NG*SEM) return;
    int g = idx / SEM, c = idx - g*SEM;
    if (c < EMB){
        float v = hr[g*EMB+c];
        P[idx] = tob(v);
        P[(size_t)(NG+g)*SEM + c] = tob(v + henv[(size_t)perm[g]*EMB + c]);
    } else {
        P[idx] = tob(0.f);
        P[(size_t)(NG+g)*SEM + c] = tob(0.f);
    }
}

__global__ __launch_bounds__(256) void k_norm(const float* __restrict__ hr, const float* __restrict__ henv,
                      const float* __restrict__ hout, float* __restrict__ na, float* __restrict__ nc,
                      float* __restrict__ pos){
    int g = blockIdx.x*4 + (threadIdx.x >> 6);
    int lane = threadIdx.x & 63;
    if (g >= NG) return;
    float srr=0.f, soo=0.f, see=0.f, sro=0.f;
    for (int c=lane;c<EMB;c+=64){
        float r=hr[g*EMB+c], o=hout[g*EMB+c], e=henv[g*EMB+c];
        srr += r*r; soo += o*o; see += e*e; sro += r*o;
    }
    for (int off=32; off>0; off>>=1){
        srr += __shfl_down(srr,off); soo += __shfl_down(soo,off);
        see += __shfl_down(see,off); sro += __shfl_down(sro,off);
    }
    if (lane==0){
        float a = sqrtf(srr), b = sqrtf(soo), c2 = sqrtf(see);
        na[g] = a; nc[g] = c2;
        pos[g] = expf(sro/(a*b + 1e-8f) * 5.0f);
    }
}

__global__ __launch_bounds__(256) void k_rowsum(const float* __restrict__ simcp, float* __restrict__ S){
    __shared__ float red[256];
    int g = blockIdx.x, t = threadIdx.x;
    float s = 0.f;
    for (int j=t;j<NG;j+=256) s += simcp[(size_t)g*NG+j];
    red[t]=s; __syncthreads();
    for (int off=128; off>0; off>>=1){ if (t<off) red[t]+=red[t+off]; __syncthreads(); }
    if (t==0) S[g]=red[0];
}

__global__ __launch_bounds__(256) void k_pred(const bf16* __restrict__ hidP, const float* __restrict__ Wp2,
                      const float* __restrict__ bp2, float* __restrict__ out){
    int r = blockIdx.x*4 + (threadIdx.x >> 6);
    int lane = threadIdx.x & 63;
    if (r >= 2*NG) return;
    float acc[NTASK];
    #pragma unroll
    for (int t=0;t<NTASK;t++) acc[t] = 0.f;
    for (int i=lane;i<HID;i+=64){
        float h = tof(hidP[(size_t)r*SHID+i]);
        const float4* wp = (const float4*)&Wp2[i*NTASK];
        float4 wa = wp[0], wb = wp[1], wc = wp[2];
        acc[0]+=h*wa.x; acc[1]+=h*wa.y; acc[2]+=h*wa.z; acc[3]+=h*wa.w;
        acc[4]+=h*wb.x; acc[5]+=h*wb.y; acc[6]+=h*wb.z; acc[7]+=h*wb.w;
        acc[8]+=h*wc.x; acc[9]+=h*wc.y; acc[10]+=h*wc.z; acc[11]+=h*wc.w;
    }
    #pragma unroll
    for (int t=0;t<NTASK;t++){
        for (int off=32; off>0; off>>=1) acc[t] += __shfl_down(acc[t], off);
    }
    if (lane==0){
        float* dst = (r < NG) ? &out[NG*NTASK + r*NTASK] : &out[(r-NG)*NTASK];
        #pragma unroll
        for (int t=0;t<NTASK;t++) dst[t] = acc[t] + bp2[t];
    }
}

__global__ __launch_bounds__(256) void k_loss(const float* __restrict__ cntf, const float* __restrict__ rnum,
                      const float* __restrict__ pos, const float* __restrict__ S, float* __restrict__ out){
    __shared__ float ra[256], rb[256];
    int t = threadIdx.x;
    float a=0.f, b=0.f;
    for (int g=t; g<NG; g+=256){
        float r = rnum[g] + 1e-8f;
        float e = (cntf[g] - rnum[g]) + 1e-8f;
        a += fabsf(r/(r+e) - 0.4f);
        float p = pos[g];
        b += -logf(p/(S[g]+p));
    }
    ra[t]=a; rb[t]=b; __syncthreads();
    for (int off=128; off>0; off>>=1){ if (t<off){ ra[t]+=ra[t+off]; rb[t]+=rb[t+off]; } __syncthreads(); }
    if (t==0){
        out[2*NG*NTASK]   = ra[0]/NG;
        out[2*NG*NTASK+1] = rb[0]/NG;
    }
}

extern "C" void kernel_launch(void* const* d_in, const int* in_sizes, int n_in,
                              void* d_out, int out_size, void* d_ws, size_t ws_size,
                              hipStream_t stream) {
    const float* x      = (const float*)d_in[0];
    const float* eattr  = (const float*)d_in[1];
    const int*   eidx   = (const int*)d_in[2];
    const int*   batch  = (const int*)d_in[3];
    const float* gumbel = (const float*)d_in[4];
    const int*   perm   = (const int*)d_in[5];
    const float* W_enc  = (const float*)d_in[6];
    const float* b_enc  = (const float*)d_in[7];
    const float* We_g   = (const float*)d_in[8];
    const float* be_g   = (const float*)d_in[9];
    const float* W1_g   = (const float*)d_in[10];
    const float* b1_g   = (const float*)d_in[11];
    const float* W2_g   = (const float*)d_in[12];
    const float* b2_g   = (const float*)d_in[13];
    const float* We_r   = (const float*)d_in[14];
    const float* be_r   = (const float*)d_in[15];
    const float* W1_r   = (const float*)d_in[16];
    const float* b1_r   = (const float*)d_in[17];
    const float* W2_r   = (const float*)d_in[18];
    const float* b2_r   = (const float*)d_in[19];
    const float* Wg1    = (const float*)d_in[20];
    const float* bg1    = (const float*)d_in[21];
    const float* Wg2    = (const float*)d_in[22];
    const float* bg2    = (const float*)d_in[23];
    const float* Wp1    = (const float*)d_in[24];
    const float* bp1    = (const float*)d_in[25];
    const float* Wp2    = (const float*)d_in[26];
    const float* bp2    = (const float*)d_in[27];
    float* out = (float*)d_out;

    const int* srcArr = eidx;
    const int* dstArr = eidx + NE;

    // ---- workspace (bump allocator, 256B aligned) ----
    char* w = (char*)d_ws;
    size_t off = 0;
    auto alloc = [&](size_t bytes)->char*{ char* p = w + off; off += (bytes + 255) & ~(size_t)255; return p; };
    bf16* xfeat = (bf16*)alloc((size_t)NN*SEM*2);
    bf16* cur   = (bf16*)alloc((size_t)NN*SEM*2);
    bf16* apx   = (bf16*)alloc((size_t)NN*SEM*2);
    char* midc  = alloc((size_t)NN*SHID*2);           // 36.5 MB; reused after stacks
    bf16* mid   = (bf16*)midc;
    float* simcp = (float*)midc;                      // NG*NG*4 = 9 MB
    bf16* Pbuf   = (bf16*)(midc + 12*1024*1024);      // 2*NG*SEM*2 = 1.92 MB
    bf16* hidP   = (bf16*)(midc + 20*1024*1024);      // 2*NG*SHID*2 = 3.65 MB
    bf16* wt1g  = (bf16*)alloc((size_t)5*HID*SEM*2);
    bf16* wt2g  = (bf16*)alloc((size_t)5*EMB*SHID*2);
    bf16* wt1r  = (bf16*)alloc((size_t)2*HID*SEM*2);
    bf16* wt2r  = (bf16*)alloc((size_t)2*EMB*SHID*2);
    bf16* wtg1  = (bf16*)alloc((size_t)HID*SEM*2);
    bf16* wtp1  = (bf16*)alloc((size_t)HID*SEM*2);
    float4* epack = (float4*)alloc((size_t)NE*16);
    float* gate  = (float*)alloc((size_t)NN*4);
    float* sumh  = (float*)alloc((size_t)NG*EMB*4);
    float* sumgh = (float*)alloc((size_t)NG*EMB*4);
    float* hr    = (float*)alloc((size_t)NG*EMB*4);
    float* henv  = (float*)alloc((size_t)NG*EMB*4);
    float* hout  = (float*)alloc((size_t)NG*EMB*4);
    bf16* hrb    = (bf16*)alloc((size_t)NG*SEM*2);
    bf16* henvb  = (bf16*)alloc((size_t)NG*SEM*2);
    float* rnum  = (float*)alloc(NG*4);
    float* cntf  = (float*)alloc(NG*4);
    float* na    = (float*)alloc(NG*4);
    float* ncv   = (float*)alloc(NG*4);
    float* pos   = (float*)alloc(NG*4);
    float* Ssum  = (float*)alloc(NG*4);
    int* deg     = (int*)alloc((size_t)NN*4);
    int* indptr  = (int*)alloc((size_t)(NN+1)*4);
    int* cursor  = (int*)alloc((size_t)NN*4);
    int* eid     = (int*)alloc((size_t)NE*4);
    int* gstart  = (int*)alloc((size_t)(NG+1)*4);
    int* bsum    = (int*)alloc((size_t)NBLK_SCAN*4);
    int* boff    = (int*)alloc((size_t)NBLK_SCAN*4);

    const int NB_NE  = (NE+255)/256;
    const int NB_NC  = (NN*EMB+255)/256;
    const int NB_AG  = (NN*CG+255)/256;
    const int NB_GP  = (NG*SEM+255)/256;

    // ---- CSR build + edge pack + graph ranges ----
    k_zero_i <<<(NN+255)/256, 256, 0, stream>>>(deg, NN);
    k_hist   <<<NB_NE, 256, 0, stream>>>(dstArr, deg);
    k_scanA  <<<NBLK_SCAN, 256, 0, stream>>>(deg, bsum);
    k_scanB  <<<1, 128, 0, stream>>>(bsum, boff);
    k_scanC  <<<NBLK_SCAN, 256, 0, stream>>>(deg, boff, indptr, cursor);
    k_scatter<<<NB_NE, 256, 0, stream>>>(dstArr, cursor, eid);
    k_eprep  <<<NB_NE, 256, 0, stream>>>(eid, srcArr, eattr, epack);
    k_gstart <<<(NG+256)/256, 256, 0, stream>>>(batch, gstart);

    // ---- weight prep (transpose + bf16 + K-pad zeros) ----
    {
        dim3 g1t((HID+31)/32, SEM/32, 5);
        dim3 g2t((EMB+31)/32, SHID/32, 5);
        k_wprep<<<g1t, 256, 0, stream>>>(W1_g, wt1g, EMB, SEM, HID);
        k_wprep<<<g2t, 256, 0, stream>>>(W2_g, wt2g, HID, SHID, EMB);
        dim3 g1t2((HID+31)/32, SEM/32, 2);
        dim3 g2t2((EMB+31)/32, SHID/32, 2);
        k_wprep<<<g1t2, 256, 0, stream>>>(W1_r, wt1r, EMB, SEM, HID);
        k_wprep<<<g2t2, 256, 0, stream>>>(W2_r, wt2r, HID, SHID, EMB);
        dim3 g1t1((HID+31)/32, SEM/32, 1);
        k_wprep<<<g1t1, 256, 0, stream>>>(Wg1, wtg1, EMB, SEM, HID);
        k_wprep<<<g1t1, 256, 0, stream>>>(Wp1, wtp1, EMB, SEM, HID);
    }

    dim3 gm1((HID+255)/256, (NN+127)/128);  // (3, 235) TN=256
    dim3 gm2((EMB+255)/256, (NN+127)/128);  // (2, 235) TN=256

    // ---- node encoder (once) ----
    k_encoder<<<NB_NC, 256, 0, stream>>>(x, W_enc, b_enc, xfeat);

    // ---- rationale GIN stack (2 layers); layer 0 reads xfeat ----
    for (int l=0; l<2; l++){
        const bf16* in = (l==0) ? xfeat : cur;
        k_agg4 <<<NB_AG, 256, 0, stream>>>(in, We_r + l*3*EMB, be_r + l*EMB, epack, indptr, apx);
        k_gemmT<8><<<gm1, 256, 0, stream>>>(apx, wt1r + (size_t)l*HID*SEM, b1_r + l*HID, nullptr, mid,
                                            NN, HID, SEM, SHID, 1);
        k_gemmT<8><<<gm2, 256, 0, stream>>>(mid, wt2r + (size_t)l*EMB*SHID, b2_r + l*EMB, in, cur,
                                            NN, EMB, SHID, SEM, (l<1)?1:0);
    }
    // ---- gate from x_rat ----
    k_gemmT<8><<<gm1, 256, 0, stream>>>(cur, wtg1, bg1, nullptr, mid, NN, HID, SEM, SHID, 1);
    k_gate<<<NN/4, 256, 0, stream>>>(mid, Wg2, bg2, gumbel, gate);

    // ---- encoder GIN stack (5 layers); layer 0 reads xfeat ----
    for (int l=0; l<5; l++){
        const bf16* in = (l==0) ? xfeat : cur;
        k_agg4 <<<NB_AG, 256, 0, stream>>>(in, We_g + l*3*EMB, be_g + l*EMB, epack, indptr, apx);
        k_gemmT<8><<<gm1, 256, 0, stream>>>(apx, wt1g + (size_t)l*HID*SEM, b1_g + l*HID, nullptr, mid,
                                            NN, HID, SEM, SHID, 1);
        k_gemmT<8><<<gm2, 256, 0, stream>>>(mid, wt2g + (size_t)l*EMB*SHID, b2_g + l*EMB, in, cur,
                                            NN, EMB, SHID, SEM, (l<4)?1:0);
    }
    // cur now holds h_node (bf16, stride SEM)

    // ---- pooling (segment scan) ----
    k_pool  <<<NG, 320, 0, stream>>>(cur, gate, gstart, sumh, sumgh);
    k_rnum  <<<(NG+3)/4, 256, 0, stream>>>(gate, gstart, rnum, cntf);
    k_mean  <<<NB_GP, 256, 0, stream>>>(sumh, sumgh, cntf, hr, henv, hout, hrb, henvb);
    k_pbuild<<<NB_GP, 256, 0, stream>>>(hr, henv, perm, Pbuf);
    k_norm  <<<(NG+3)/4, 256, 0, stream>>>(hr, henv, hout, na, ncv, pos);
    // ---- contrastive sim (MFMA) ----
    dim3 gsim((NG+127)/128, (NG+127)/128);
    k_sim_mfma<<<gsim, 256, 0, stream>>>(hrb, henvb, na, ncv, simcp);
    k_rowsum<<<NG, 256, 0, stream>>>(simcp, Ssum);
    // ---- head (MFMA) ----
    dim3 gph((HID+255)/256, (2*NG+127)/128);
    k_gemmT<8><<<gph, 256, 0, stream>>>(Pbuf, wtp1, bp1, nullptr, hidP, 2*NG, HID, SEM, SHID, 1);
    k_pred  <<<(2*NG+3)/4, 256, 0, stream>>>(hidP, Wp2, bp2, out);
    k_loss  <<<1, 256, 0, stream>>>(cntf, rnum, pos, Ssum, out);
}

// Round 12
// 1037.765 us; speedup vs baseline: 1.6857x; 1.6857x over previous
//
#include <hip/hip_runtime.h>
#include <hip/hip_bf16.h>

typedef __hip_bfloat16 bf16;
typedef __attribute__((ext_vector_type(8))) short bf16x8;
typedef __attribute__((ext_vector_type(4))) float f32x4;

#define NN 30000      // nodes
#define NE 240000     // edges
#define NG 1500       // graphs
#define EMB 300
#define HID 600
#define NTASK 12
#define SEM 320       // padded stride for EMB-dim tensors
#define SHID 608      // padded stride for HID-dim tensors
#define CG 75         // 4-channel groups — 75 thr/node: best TLP (round-9 lesson)
#define NBLK_SCAN 118 // (NN+255)/256

__device__ __forceinline__ float tof(bf16 v){ return __bfloat162float(v); }
__device__ __forceinline__ bf16  tob(float v){ return __float2bfloat16(v); }
__device__ __forceinline__ float b2f(unsigned short u){ return __uint_as_float(((unsigned)u)<<16); }

// ---------------- utility ----------------
__global__ __launch_bounds__(256) void k_zero_i(int* __restrict__ p, int n){
    int i = blockIdx.x*256 + threadIdx.x;
    if (i < n) p[i] = 0;
}

// ---------------- CSR build (by dst) ----------------
__global__ __launch_bounds__(256) void k_hist(const int* __restrict__ dst, int* __restrict__ deg){
    int e = blockIdx.x*256 + threadIdx.x;
    if (e < NE) atomicAdd(&deg[dst[e]], 1);
}

__global__ __launch_bounds__(256) void k_scanA(const int* __restrict__ deg, int* __restrict__ bsum){
    __shared__ int red[256];
    int b = blockIdx.x, t = threadIdx.x;
    int i = b*256 + t;
    red[t] = (i < NN) ? deg[i] : 0;
    __syncthreads();
    for (int off=128; off>0; off>>=1){ if (t<off) red[t]+=red[t+off]; __syncthreads(); }
    if (t==0) bsum[b] = red[0];
}

__global__ __launch_bounds__(128) void k_scanB(const int* __restrict__ bsum, int* __restrict__ boff){
    __shared__ int s[128];
    int t = threadIdx.x;
    int v = (t < NBLK_SCAN) ? bsum[t] : 0;
    s[t] = v;
    __syncthreads();
    for (int off=1; off<128; off<<=1){
        int add = (t>=off) ? s[t-off] : 0;
        __syncthreads();
        s[t] += add;
        __syncthreads();
    }
    if (t < NBLK_SCAN) boff[t] = s[t] - v;   // exclusive
}

__global__ __launch_bounds__(256) void k_scanC(const int* __restrict__ deg, const int* __restrict__ boff,
                                               int* __restrict__ indptr, int* __restrict__ cursor){
    __shared__ int s[256];
    int b = blockIdx.x, t = threadIdx.x;
    int i = b*256 + t;
    int v = (i < NN) ? deg[i] : 0;
    s[t] = v;
    __syncthreads();
    for (int off=1; off<256; off<<=1){
        int add = (t>=off) ? s[t-off] : 0;
        __syncthreads();
        s[t] += add;
        __syncthreads();
    }
    int excl = s[t] - v + boff[b];
    if (i < NN){ indptr[i] = excl; cursor[i] = excl; }
    if (i == 0) indptr[NN] = NE;
}

__global__ __launch_bounds__(256) void k_scatter(const int* __restrict__ dst, int* __restrict__ cursor,
                                                 int* __restrict__ eid){
    int e = blockIdx.x*256 + threadIdx.x;
    if (e < NE){ int p = atomicAdd(&cursor[dst[e]], 1); eid[p] = e; }
}

__global__ __launch_bounds__(256) void k_eprep(const int* __restrict__ eid, const int* __restrict__ src,
                                               const float* __restrict__ eattr, float4* __restrict__ epack){
    int k = blockIdx.x*256 + threadIdx.x;
    if (k >= NE) return;
    int e = eid[k];
    float4 p;
    p.x = __int_as_float(src[e]);
    p.y = eattr[e*3]; p.z = eattr[e*3+1]; p.w = eattr[e*3+2];
    epack[k] = p;
}

__global__ __launch_bounds__(256) void k_gstart(const int* __restrict__ batch, int* __restrict__ gstart){
    int g = blockIdx.x*256 + threadIdx.x;
    if (g > NG) return;
    if (g == NG){ gstart[NG] = NN; return; }
    int lo=0, hi=NN;
    while (lo<hi){ int mid=(lo+hi)>>1; if (batch[mid] < g) lo=mid+1; else hi=mid; }
    gstart[g] = lo;
}

// ---------------- weight prep: Wt[n][kp] bf16 = W[k][n] fp32, zero-padded k>=K ----------------
__global__ __launch_bounds__(256) void k_wprep(const float* __restrict__ W, bf16* __restrict__ Wt,
                                               int K, int Kp, int N){
    __shared__ float t[32][33];
    const float* Wz = W + (size_t)blockIdx.z*K*N;
    bf16* Wtz = Wt + (size_t)blockIdx.z*N*Kp;
    int n0 = blockIdx.x*32, k0 = blockIdx.y*32;
    int tx = threadIdx.x & 31, ty = threadIdx.x >> 5;
    #pragma unroll
    for (int i=0;i<4;i++){
        int k = k0 + ty + i*8, n = n0 + tx;
        t[ty+i*8][tx] = (k<K && n<N) ? Wz[(size_t)k*N+n] : 0.f;
    }
    __syncthreads();
    #pragma unroll
    for (int i=0;i<4;i++){
        int n = n0 + ty + i*8, k = k0 + tx;
        if (n<N && k<Kp) Wtz[(size_t)n*Kp+k] = tob(t[tx][ty+i*8]);
    }
}

// ---------------- node encoder ----------------
__global__ __launch_bounds__(256) void k_encoder(const float* __restrict__ x, const float* __restrict__ W,
                                                 const float* __restrict__ b, bf16* __restrict__ xfeat){
    int idx = blockIdx.x*256 + threadIdx.x;
    if (idx >= NN*EMB) return;
    int n = idx / EMB, c = idx - n*EMB;
    float acc = b[c];
    #pragma unroll
    for (int k=0;k<9;k++) acc += x[n*9+k] * W[k*EMB+c];
    xfeat[(size_t)n*SEM + c] = tob(acc);
}

// ---------------- agg: thread=(node, 4-ch group); 2-deep epack+gather pipeline ----------------
__global__ __launch_bounds__(256) void k_agg4(const bf16* __restrict__ cur, const float* __restrict__ We,
                      const float* __restrict__ be, const float4* __restrict__ epack,
                      const int* __restrict__ indptr, bf16* __restrict__ apx){
    int idx = blockIdx.x*256 + threadIdx.x;
    if (idx >= NN*CG) return;
    int n = idx / CG, cg = idx - n*CG;
    int c0 = cg*4;
    float w0[4], w1[4], w2[4], bbv[4], acc[4];
    #pragma unroll
    for (int j=0;j<4;j++){
        w0[j] = We[c0+j]; w1[j] = We[EMB+c0+j]; w2[j] = We[2*EMB+c0+j]; bbv[j] = be[c0+j];
    }
    ushort4 hs = *(const ushort4*)&cur[(size_t)n*SEM + c0];
    acc[0]=b2f(hs.x); acc[1]=b2f(hs.y); acc[2]=b2f(hs.z); acc[3]=b2f(hs.w);
    int k  = indptr[n], k1 = indptr[n+1];

    auto accum4 = [&](float4 e0, float4 e1, float4 e2, float4 e3,
                      ushort4 ha, ushort4 hb, ushort4 hc, ushort4 hd){
        float fa[4] = {b2f(ha.x), b2f(ha.y), b2f(ha.z), b2f(ha.w)};
        float fb[4] = {b2f(hb.x), b2f(hb.y), b2f(hb.z), b2f(hb.w)};
        float fc[4] = {b2f(hc.x), b2f(hc.y), b2f(hc.z), b2f(hc.w)};
        float fd[4] = {b2f(hd.x), b2f(hd.y), b2f(hd.z), b2f(hd.w)};
        #pragma unroll
        for (int j=0;j<4;j++){
            float va = fa[j] + e0.y*w0[j] + e0.z*w1[j] + e0.w*w2[j] + bbv[j];
            float vb = fb[j] + e1.y*w0[j] + e1.z*w1[j] + e1.w*w2[j] + bbv[j];
            float vc = fc[j] + e2.y*w0[j] + e2.z*w1[j] + e2.w*w2[j] + bbv[j];
            float vd = fd[j] + e3.y*w0[j] + e3.z*w1[j] + e3.w*w2[j] + bbv[j];
            acc[j] += fmaxf(va, 0.f) + fmaxf(vb, 0.f) + fmaxf(vc, 0.f) + fmaxf(vd, 0.f);
        }
    };

    if (k + 4 <= k1){
        float4 e0 = epack[k], e1 = epack[k+1], e2 = epack[k+2], e3 = epack[k+3];
        ushort4 h0 = *(const ushort4*)&cur[(size_t)__float_as_int(e0.x)*SEM + c0];
        ushort4 h1 = *(const ushort4*)&cur[(size_t)__float_as_int(e1.x)*SEM + c0];
        ushort4 h2 = *(const ushort4*)&cur[(size_t)__float_as_int(e2.x)*SEM + c0];
        ushort4 h3 = *(const ushort4*)&cur[(size_t)__float_as_int(e3.x)*SEM + c0];
        while (k + 8 <= k1){
            float4 f0 = epack[k+4], f1 = epack[k+5], f2 = epack[k+6], f3 = epack[k+7];
            ushort4 g0 = *(const ushort4*)&cur[(size_t)__float_as_int(f0.x)*SEM + c0];
            ushort4 g1 = *(const ushort4*)&cur[(size_t)__float_as_int(f1.x)*SEM + c0];
            ushort4 g2 = *(const ushort4*)&cur[(size_t)__float_as_int(f2.x)*SEM + c0];
            ushort4 g3 = *(const ushort4*)&cur[(size_t)__float_as_int(f3.x)*SEM + c0];
            accum4(e0,e1,e2,e3, h0,h1,h2,h3);
            e0=f0; e1=f1; e2=f2; e3=f3;
            h0=g0; h1=g1; h2=g2; h3=g3;
            k += 4;
        }
        accum4(e0,e1,e2,e3, h0,h1,h2,h3);
        k += 4;
    }
    for (; k < k1; k++){
        float4 e0 = epack[k];
        int s0 = __float_as_int(e0.x);
        ushort4 ha = *(const ushort4*)&cur[(size_t)s0*SEM + c0];
        float fa[4] = {b2f(ha.x), b2f(ha.y), b2f(ha.z), b2f(ha.w)};
        #pragma unroll
        for (int j=0;j<4;j++){
            float va = fa[j] + e0.y*w0[j] + e0.z*w1[j] + e0.w*w2[j] + bbv[j];
            acc[j] += fmaxf(va, 0.f);
        }
    }
    ushort4 o;
    o.x = __bfloat16_as_ushort(tob(acc[0]));
    o.y = __bfloat16_as_ushort(tob(acc[1]));
    o.z = __bfloat16_as_ushort(tob(acc[2]));
    o.w = __bfloat16_as_ushort(tob(acc[3]));
    *(ushort4*)&apx[(size_t)n*SEM + c0] = o;
}

// ---------------- dual agg: one gather pass feeds BOTH weight sets (layer-0 fusion) ----------------
__global__ __launch_bounds__(256) void k_agg4d(const bf16* __restrict__ cur,
                      const float* __restrict__ WeA, const float* __restrict__ beA,
                      const float* __restrict__ WeB, const float* __restrict__ beB,
                      const float4* __restrict__ epack, const int* __restrict__ indptr,
                      bf16* __restrict__ apxA, bf16* __restrict__ apxB){
    int idx = blockIdx.x*256 + threadIdx.x;
    if (idx >= NN*CG) return;
    int n = idx / CG, cg = idx - n*CG;
    int c0 = cg*4;
    float a0[4], a1[4], a2[4], ab[4], accA[4];
    float b0[4], b1[4], b2[4], bb[4], accB[4];
    #pragma unroll
    for (int j=0;j<4;j++){
        a0[j]=WeA[c0+j]; a1[j]=WeA[EMB+c0+j]; a2[j]=WeA[2*EMB+c0+j]; ab[j]=beA[c0+j];
        b0[j]=WeB[c0+j]; b1[j]=WeB[EMB+c0+j]; b2[j]=WeB[2*EMB+c0+j]; bb[j]=beB[c0+j];
    }
    ushort4 hs = *(const ushort4*)&cur[(size_t)n*SEM + c0];
    float fs[4] = {b2f(hs.x), b2f(hs.y), b2f(hs.z), b2f(hs.w)};
    #pragma unroll
    for (int j=0;j<4;j++){ accA[j]=fs[j]; accB[j]=fs[j]; }
    int k = indptr[n], k1 = indptr[n+1];
    for (; k+2 <= k1; k += 2){
        float4 e0 = epack[k], e1 = epack[k+1];
        int s0 = __float_as_int(e0.x), s1 = __float_as_int(e1.x);
        ushort4 ha = *(const ushort4*)&cur[(size_t)s0*SEM + c0];
        ushort4 hb = *(const ushort4*)&cur[(size_t)s1*SEM + c0];
        float fa[4] = {b2f(ha.x), b2f(ha.y), b2f(ha.z), b2f(ha.w)};
        float fb[4] = {b2f(hb.x), b2f(hb.y), b2f(hb.z), b2f(hb.w)};
        #pragma unroll
        for (int j=0;j<4;j++){
            accA[j] += fmaxf(fa[j] + e0.y*a0[j] + e0.z*a1[j] + e0.w*a2[j] + ab[j], 0.f)
                     + fmaxf(fb[j] + e1.y*a0[j] + e1.z*a1[j] + e1.w*a2[j] + ab[j], 0.f);
            accB[j] += fmaxf(fa[j] + e0.y*b0[j] + e0.z*b1[j] + e0.w*b2[j] + bb[j], 0.f)
                     + fmaxf(fb[j] + e1.y*b0[j] + e1.z*b1[j] + e1.w*b2[j] + bb[j], 0.f);
        }
    }
    if (k < k1){
        float4 e0 = epack[k];
        int s0 = __float_as_int(e0.x);
        ushort4 ha = *(const ushort4*)&cur[(size_t)s0*SEM + c0];
        float fa[4] = {b2f(ha.x), b2f(ha.y), b2f(ha.z), b2f(ha.w)};
        #pragma unroll
        for (int j=0;j<4;j++){
            accA[j] += fmaxf(fa[j] + e0.y*a0[j] + e0.z*a1[j] + e0.w*a2[j] + ab[j], 0.f);
            accB[j] += fmaxf(fa[j] + e0.y*b0[j] + e0.z*b1[j] + e0.w*b2[j] + bb[j], 0.f);
        }
    }
    ushort4 oA, oB;
    oA.x=__bfloat16_as_ushort(tob(accA[0])); oA.y=__bfloat16_as_ushort(tob(accA[1]));
    oA.z=__bfloat16_as_ushort(tob(accA[2])); oA.w=__bfloat16_as_ushort(tob(accA[3]));
    oB.x=__bfloat16_as_ushort(tob(accB[0])); oB.y=__bfloat16_as_ushort(tob(accB[1]));
    oB.z=__bfloat16_as_ushort(tob(accB[2])); oB.w=__bfloat16_as_ushort(tob(accB[3]));
    *(ushort4*)&apxA[(size_t)n*SEM + c0] = oA;
    *(ushort4*)&apxB[(size_t)n*SEM + c0] = oB;
}

// ---------------- pipelined MFMA bf16 GEMM (TN=128), 2-pass epilogue (LDS 17 KB) ----------------
// C[M][ldc] = bf16( [relu](A[M][Kp] @ Bt[N][Kp]^T + bias[N]) [+ R[M][ldc]] )
__global__ __launch_bounds__(256) void k_gemm2(const bf16* __restrict__ A, const bf16* __restrict__ Bt,
        const float* __restrict__ bias, const bf16* __restrict__ R, bf16* __restrict__ C,
        int M, int N, int Kp, int ldc, int relu_out){
    __shared__ __align__(16) char ldsbuf[17408];   // staging 16 KB; reused as 64x136 bf16 C-half-tile
    short (*Asl)[64][8] = reinterpret_cast<short(*)[64][8]>(ldsbuf);
    short (*Bsl)[64][8] = reinterpret_cast<short(*)[64][8]>(ldsbuf + 8192);
    short* Ct = reinterpret_cast<short*>(ldsbuf);
    const int CS = 136;
    int tid = threadIdx.x;
    int wave = tid >> 6, lane = tid & 63;
    int wm = wave >> 1, wn = wave & 1;
    int m0 = blockIdx.y*128, n0 = blockIdx.x*128;

    int srow = tid >> 1;
    int sq   = (tid & 1) * 2;
    int grA = min(m0 + srow, M-1);
    int grB = min(n0 + srow, N-1);
    const bf16* pA = A  + (size_t)grA*Kp + sq*8;
    const bf16* pB = Bt + (size_t)grB*Kp + sq*8;
    short* ldsA0 = &Asl[srow>>4][ sq   *16 + (srow&15)][0];
    short* ldsA1 = &Asl[srow>>4][(sq+1)*16 + (srow&15)][0];
    short* ldsB0 = &Bsl[srow>>4][ sq   *16 + (srow&15)][0];
    short* ldsB1 = &Bsl[srow>>4][(sq+1)*16 + (srow&15)][0];

    f32x4 acc[4][4];
    #pragma unroll
    for (int i=0;i<4;i++){
        #pragma unroll
        for (int j=0;j<4;j++) acc[i][j] = (f32x4){0.f,0.f,0.f,0.f};
    }

    int KC = Kp >> 5;
    uint4 ra0 = *(const uint4*)(pA);
    uint4 ra1 = *(const uint4*)(pA + 8);
    uint4 rb0 = *(const uint4*)(pB);
    uint4 rb1 = *(const uint4*)(pB + 8);

    for (int kc=0; kc<KC; ++kc){
        *(uint4*)ldsA0 = ra0; *(uint4*)ldsA1 = ra1;
        *(uint4*)ldsB0 = rb0; *(uint4*)ldsB1 = rb1;
        __syncthreads();
        if (kc+1 < KC){
            const bf16* qA = pA + (kc+1)*32;
            const bf16* qB = pB + (kc+1)*32;
            ra0 = *(const uint4*)(qA); ra1 = *(const uint4*)(qA+8);
            rb0 = *(const uint4*)(qB); rb1 = *(const uint4*)(qB+8);
        }
        bf16x8 af[4], bfr[4];
        #pragma unroll
        for (int i=0;i<4;i++) af[i]  = *(const bf16x8*)&Asl[wm*4+i][lane][0];
        #pragma unroll
        for (int j=0;j<4;j++) bfr[j] = *(const bf16x8*)&Bsl[wn*4+j][lane][0];
        #pragma unroll
        for (int i=0;i<4;i++){
            #pragma unroll
            for (int j=0;j<4;j++)
                acc[i][j] = __builtin_amdgcn_mfma_f32_16x16x32_bf16(af[i], bfr[j], acc[i][j], 0, 0, 0);
        }
        __syncthreads();
    }

    // ---- 2-pass epilogue: 64-row half-tiles through LDS, coalesced 16B stores ----
    int lq = lane >> 4, lr = lane & 15;
    #pragma unroll
    for (int h=0; h<2; h++){
        if (wm == h){
            #pragma unroll
            for (int i=0;i<4;i++){
                int rl = i*16 + lq*4;          // local row in 64-row half
                #pragma unroll
                for (int j=0;j<4;j++){
                    int cl = (wn*4+j)*16 + lr;
                    float bv = bias[min(n0+cl, N-1)];
                    #pragma unroll
                    for (int r=0;r<4;r++){
                        float v = acc[i][j][r] + bv;
                        if (relu_out) v = fmaxf(v, 0.f);
                        Ct[(rl+r)*CS + cl] = (short)__bfloat16_as_ushort(tob(v));
                    }
                }
            }
        }
        __syncthreads();
        #pragma unroll
        for (int p=0;p<4;p++){
            int rl = p*16 + (tid>>4);
            int cl = (tid&15)*8;
            int row = m0 + h*64 + rl, col = n0 + cl;
            if (row < M && col < N){
                union { short s8[8]; uint4 v; } u;
                u.v = *(uint4*)&Ct[rl*CS + cl];
                if (R){
                    const bf16* rp = &R[(size_t)row*ldc + col];
                    #pragma unroll
                    for (int e=0;e<8;e++){
                        float v = b2f((unsigned short)u.s8[e]) + tof(rp[e]);
                        u.s8[e] = (short)__bfloat16_as_ushort(tob(v));
                    }
                }
                *(uint4*)&C[(size_t)row*ldc + col] = u.v;
            }
        }
        if (h == 0) __syncthreads();
    }
}

// ---------------- old-style MFMA machinery (kept for k_sim_mfma) ----------------
__device__ __forceinline__ void stage_tile(const short* __restrict__ P, int RB, int K, int r0, int k0,
                                           short (*lds)[64][8], int tid){
    #pragma unroll
    for (int s=0;s<2;s++){
        int seg = tid*2+s;
        int row = seg>>2, q = seg&3;
        int gr = r0 + row;
        int gk = k0 + q*8;
        union { short s8[8]; uint4 v; } u;
        if (gr < RB && gk + 8 <= K){
            const uint2* p = (const uint2*)(P + (size_t)gr*K + gk);
            uint2 lo = p[0], hi = p[1];
            u.v.x = lo.x; u.v.y = lo.y; u.v.z = hi.x; u.v.w = hi.y;
        } else {
            #pragma unroll
            for (int j=0;j<8;j++){
                int kk = gk + j;
                u.s8[j] = (gr < RB && kk < K) ? P[(size_t)gr*K + kk] : (short)0;
            }
        }
        *(uint4*)&lds[row>>4][q*16 + (row&15)][0] = u.v;
    }
}

// sim_cp[i][j] = exp( (hr_i . henv_j) * 5 / (na_i*nc_j + 1e-8) )
__global__ __launch_bounds__(256) void k_sim_mfma(const bf16* __restrict__ A, const bf16* __restrict__ Bt,
                      const float* __restrict__ na, const float* __restrict__ nc, float* __restrict__ C){
    __shared__ __align__(16) short Asl[8][64][8];
    __shared__ __align__(16) short Bsl[8][64][8];
    int tid = threadIdx.x;
    int wave = tid >> 6, lane = tid & 63;
    int wm = wave >> 1, wn = wave & 1;
    int m0 = blockIdx.y*128, n0 = blockIdx.x*128;
    f32x4 acc[4][4];
    #pragma unroll
    for (int i=0;i<4;i++){
        #pragma unroll
        for (int j=0;j<4;j++) acc[i][j] = (f32x4){0.f,0.f,0.f,0.f};
    }
    for (int k0=0; k0<SEM; k0+=32){
        stage_tile((const short*)A,  NG, SEM, m0, k0, Asl, tid);
        stage_tile((const short*)Bt, NG, SEM, n0, k0, Bsl, tid);
        __syncthreads();
        bf16x8 af[4], bfr[4];
        #pragma unroll
        for (int i=0;i<4;i++) af[i]  = *(const bf16x8*)&Asl[wm*4+i][lane][0];
        #pragma unroll
        for (int j=0;j<4;j++) bfr[j] = *(const bf16x8*)&Bsl[wn*4+j][lane][0];
        #pragma unroll
        for (int i=0;i<4;i++){
            #pragma unroll
            for (int j=0;j<4;j++)
                acc[i][j] = __builtin_amdgcn_mfma_f32_16x16x32_bf16(af[i], bfr[j], acc[i][j], 0, 0, 0);
        }
        __syncthreads();
    }
    int lq = lane >> 4, lr = lane & 15;
    #pragma unroll
    for (int i=0;i<4;i++){
        int rb = m0 + (wm*4+i)*16 + lq*4;
        #pragma unroll
        for (int j=0;j<4;j++){
            int col = n0 + (wn*4+j)*16 + lr;
            if (col >= NG) continue;
            float ncj = nc[col];
            #pragma unroll
            for (int r=0;r<4;r++){
                int row = rb + r;
                if (row >= NG) continue;
                C[(size_t)row*NG+col] = expf(acc[i][j][r] * 5.0f / (na[row]*ncj + 1e-8f));
            }
        }
    }
}

// ---------------- gate ----------------
__global__ __launch_bounds__(256) void k_gate(const bf16* __restrict__ mid, const float* __restrict__ Wg2,
                      const float* __restrict__ bg2, const float* __restrict__ gumbel, float* __restrict__ gate){
    int gw = blockIdx.x*4 + (threadIdx.x >> 6);
    int lane = threadIdx.x & 63;
    if (gw >= NN) return;
    float s0=0.f, s1=0.f;
    for (int i=lane;i<HID;i+=64){
        float h = tof(mid[(size_t)gw*SHID+i]);
        s0 += h * Wg2[i*2];
        s1 += h * Wg2[i*2+1];
    }
    for (int off=32; off>0; off>>=1){ s0 += __shfl_down(s0, off); s1 += __shfl_down(s1, off); }
    if (lane==0){
        float l0 = s0 + bg2[0] + gumbel[gw*2];
        float l1 = s1 + bg2[1] + gumbel[gw*2+1];
        float m = fmaxf(l0,l1);
        float e0 = expf(l0-m), e1 = expf(l1-m);
        gate[gw] = e1/(e0+e1);
    }
}

// ---------------- segment pooling ----------------
__global__ __launch_bounds__(320) void k_pool(const bf16* __restrict__ h, const float* __restrict__ gate,
                      const int* __restrict__ gstart, float* __restrict__ sumh, float* __restrict__ sumgh){
    int g = blockIdx.x, c = threadIdx.x;
    if (c >= EMB) return;
    int n0 = gstart[g], n1 = gstart[g+1];
    float sh=0.f, sg=0.f;
    for (int n=n0;n<n1;n++){
        float v = tof(h[(size_t)n*SEM+c]);
        float gt = gate[n];
        sh += v; sg += gt*v;
    }
    sumh[g*EMB+c] = sh; sumgh[g*EMB+c] = sg;
}

__global__ __launch_bounds__(256) void k_rnum(const float* __restrict__ gate, const int* __restrict__ gstart,
                      float* __restrict__ rnum, float* __restrict__ cntf){
    int g = blockIdx.x*4 + (threadIdx.x >> 6);
    int lane = threadIdx.x & 63;
    if (g >= NG) return;
    int n0 = gstart[g], n1 = gstart[g+1];
    float s=0.f;
    for (int n=n0+lane;n<n1;n+=64) s += gate[n];
    for (int off=32; off>0; off>>=1) s += __shfl_down(s, off);
    if (lane==0){ rnum[g] = s; cntf[g] = (float)(n1-n0); }
}

__global__ __launch_bounds__(256) void k_mean(const float* __restrict__ sumh, const float* __restrict__ sumgh,
                      const float* __restrict__ cntf, float* __restrict__ hr, float* __restrict__ henv,
                      float* __restrict__ hout, bf16* __restrict__ hrb, bf16* __restrict__ henvb){
    int idx = blockIdx.x*256 + threadIdx.x;
    if (idx >= NG*SEM) return;
    int g = idx / SEM, c = idx - g*SEM;
    if (c < EMB){
        int o = g*EMB + c;
        float inv = 1.f / fmaxf(cntf[g], 1.f);
        float sh = sumh[o], sg = sumgh[o];
        float r = sg*inv, e = (sh-sg)*inv;
        hr[o] = r; henv[o] = e; hout[o] = sh*inv;
        hrb[idx] = tob(r); henvb[idx] = tob(e);
    } else {
        hrb[idx] = tob(0.f); henvb[idx] = tob(0.f);   // zero pads (henvb is a B-operand!)
    }
}

__global__ __launch_bounds__(256) void k_pbuild(const float* __restrict__ hr, const float* __restrict__ henv,
                      const int* __restrict__ perm, bf16* __restrict__ P){
    int idx = blockIdx.x*256 + threadIdx.x;
    if (idx >= NG*SEM) return;
    int g = idx / SEM, c = idx - g*SEM;
    if (c < EMB){
        float v = hr[g*EMB+c];
        P[idx] = tob(v);
        P[(size_t)(NG+g)*SEM + c] = tob(v + henv[(size_t)perm[g]*EMB + c]);
    } else {
        P[idx] = tob(0.f);
        P[(size_t)(NG+g)*SEM + c] = tob(0.f);
    }
}

__global__ __launch_bounds__(256) void k_norm(const float* __restrict__ hr, const float* __restrict__ henv,
                      const float* __restrict__ hout, float* __restrict__ na, float* __restrict__ nc,
                      float* __restrict__ pos){
    int g = blockIdx.x*4 + (threadIdx.x >> 6);
    int lane = threadIdx.x & 63;
    if (g >= NG) return;
    float srr=0.f, soo=0.f, see=0.f, sro=0.f;
    for (int c=lane;c<EMB;c+=64){
        float r=hr[g*EMB+c], o=hout[g*EMB+c], e=henv[g*EMB+c];
        srr += r*r; soo += o*o; see += e*e; sro += r*o;
    }
    for (int off=32; off>0; off>>=1){
        srr += __shfl_down(srr,off); soo += __shfl_down(soo,off);
        see += __shfl_down(see,off); sro += __shfl_down(sro,off);
    }
    if (lane==0){
        float a = sqrtf(srr), b = sqrtf(soo), c2 = sqrtf(see);
        na[g] = a; nc[g] = c2;
        pos[g] = expf(sro/(a*b + 1e-8f) * 5.0f);
    }
}

__global__ __launch_bounds__(256) void k_rowsum(const float* __restrict__ simcp, float* __restrict__ S){
    __shared__ float red[256];
    int g = blockIdx.x, t = threadIdx.x;
    float s = 0.f;
    for (int j=t;j<NG;j+=256) s += simcp[(size_t)g*NG+j];
    red[t]=s; __syncthreads();
    for (int off=128; off>0; off>>=1){ if (t<off) red[t]+=red[t+off]; __syncthreads(); }
    if (t==0) S[g]=red[0];
}

__global__ __launch_bounds__(256) void k_pred(const bf16* __restrict__ hidP, const float* __restrict__ Wp2,
                      const float* __restrict__ bp2, float* __restrict__ out){
    int r = blockIdx.x*4 + (threadIdx.x >> 6);
    int lane = threadIdx.x & 63;
    if (r >= 2*NG) return;
    float acc[NTASK];
    #pragma unroll
    for (int t=0;t<NTASK;t++) acc[t] = 0.f;
    for (int i=lane;i<HID;i+=64){
        float h = tof(hidP[(size_t)r*SHID+i]);
        const float4* wp = (const float4*)&Wp2[i*NTASK];
        float4 wa = wp[0], wb = wp[1], wc = wp[2];
        acc[0]+=h*wa.x; acc[1]+=h*wa.y; acc[2]+=h*wa.z; acc[3]+=h*wa.w;
        acc[4]+=h*wb.x; acc[5]+=h*wb.y; acc[6]+=h*wb.z; acc[7]+=h*wb.w;
        acc[8]+=h*wc.x; acc[9]+=h*wc.y; acc[10]+=h*wc.z; acc[11]+=h*wc.w;
    }
    #pragma unroll
    for (int t=0;t<NTASK;t++){
        for (int off=32; off>0; off>>=1) acc[t] += __shfl_down(acc[t], off);
    }
    if (lane==0){
        float* dst = (r < NG) ? &out[NG*NTASK + r*NTASK] : &out[(r-NG)*NTASK];
        #pragma unroll
        for (int t=0;t<NTASK;t++) dst[t] = acc[t] + bp2[t];
    }
}

__global__ __launch_bounds__(256) void k_loss(const float* __restrict__ cntf, const float* __restrict__ rnum,
                      const float* __restrict__ pos, const float* __restrict__ S, float* __restrict__ out){
    __shared__ float ra[256], rb[256];
    int t = threadIdx.x;
    float a=0.f, b=0.f;
    for (int g=t; g<NG; g+=256){
        float r = rnum[g] + 1e-8f;
        float e = (cntf[g] - rnum[g]) + 1e-8f;
        a += fabsf(r/(r+e) - 0.4f);
        float p = pos[g];
        b += -logf(p/(S[g]+p));
    }
    ra[t]=a; rb[t]=b; __syncthreads();
    for (int off=128; off>0; off>>=1){ if (t<off){ ra[t]+=ra[t+off]; rb[t]+=rb[t+off]; } __syncthreads(); }
    if (t==0){
        out[2*NG*NTASK]   = ra[0]/NG;
        out[2*NG*NTASK+1] = rb[0]/NG;
    }
}

extern "C" void kernel_launch(void* const* d_in, const int* in_sizes, int n_in,
                              void* d_out, int out_size, void* d_ws, size_t ws_size,
                              hipStream_t stream) {
    const float* x      = (const float*)d_in[0];
    const float* eattr  = (const float*)d_in[1];
    const int*   eidx   = (const int*)d_in[2];
    const int*   batch  = (const int*)d_in[3];
    const float* gumbel = (const float*)d_in[4];
    const int*   perm   = (const int*)d_in[5];
    const float* W_enc  = (const float*)d_in[6];
    const float* b_enc  = (const float*)d_in[7];
    const float* We_g   = (const float*)d_in[8];
    const float* be_g   = (const float*)d_in[9];
    const float* W1_g   = (const float*)d_in[10];
    const float* b1_g   = (const float*)d_in[11];
    const float* W2_g   = (const float*)d_in[12];
    const float* b2_g   = (const float*)d_in[13];
    const float* We_r   = (const float*)d_in[14];
    const float* be_r   = (const float*)d_in[15];
    const float* W1_r   = (const float*)d_in[16];
    const float* b1_r   = (const float*)d_in[17];
    const float* W2_r   = (const float*)d_in[18];
    const float* b2_r   = (const float*)d_in[19];
    const float* Wg1    = (const float*)d_in[20];
    const float* bg1    = (const float*)d_in[21];
    const float* Wg2    = (const float*)d_in[22];
    const float* bg2    = (const float*)d_in[23];
    const float* Wp1    = (const float*)d_in[24];
    const float* bp1    = (const float*)d_in[25];
    const float* Wp2    = (const float*)d_in[26];
    const float* bp2    = (const float*)d_in[27];
    float* out = (float*)d_out;

    const int* srcArr = eidx;
    const int* dstArr = eidx + NE;

    // ---- workspace (bump allocator, 256B aligned) ----
    char* w = (char*)d_ws;
    size_t off = 0;
    auto alloc = [&](size_t bytes)->char*{ char* p = w + off; off += (bytes + 255) & ~(size_t)255; return p; };
    bf16* xfeat = (bf16*)alloc((size_t)NN*SEM*2);
    bf16* cur   = (bf16*)alloc((size_t)NN*SEM*2);
    bf16* apx   = (bf16*)alloc((size_t)NN*SEM*2);
    bf16* apx2  = (bf16*)alloc((size_t)NN*SEM*2);     // encoder-l0 agg output (fused dual agg)
    char* midc  = alloc((size_t)NN*SHID*2);           // 36.5 MB; reused after stacks
    bf16* mid   = (bf16*)midc;
    float* simcp = (float*)midc;                      // NG*NG*4 = 9 MB
    bf16* Pbuf   = (bf16*)(midc + 12*1024*1024);
    bf16* hidP   = (bf16*)(midc + 20*1024*1024);
    bf16* wt1g  = (bf16*)alloc((size_t)5*HID*SEM*2);
    bf16* wt2g  = (bf16*)alloc((size_t)5*EMB*SHID*2);
    bf16* wt1r  = (bf16*)alloc((size_t)2*HID*SEM*2);
    bf16* wt2r  = (bf16*)alloc((size_t)2*EMB*SHID*2);
    bf16* wtg1  = (bf16*)alloc((size_t)HID*SEM*2);
    bf16* wtp1  = (bf16*)alloc((size_t)HID*SEM*2);
    float4* epack = (float4*)alloc((size_t)NE*16);
    float* gate  = (float*)alloc((size_t)NN*4);
    float* sumh  = (float*)alloc((size_t)NG*EMB*4);
    float* sumgh = (float*)alloc((size_t)NG*EMB*4);
    float* hr    = (float*)alloc((size_t)NG*EMB*4);
    float* henv  = (float*)alloc((size_t)NG*EMB*4);
    float* hout  = (float*)alloc((size_t)NG*EMB*4);
    bf16* hrb    = (bf16*)alloc((size_t)NG*SEM*2);
    bf16* henvb  = (bf16*)alloc((size_t)NG*SEM*2);
    float* rnum  = (float*)alloc(NG*4);
    float* cntf  = (float*)alloc(NG*4);
    float* na    = (float*)alloc(NG*4);
    float* ncv   = (float*)alloc(NG*4);
    float* pos   = (float*)alloc(NG*4);
    float* Ssum  = (float*)alloc(NG*4);
    int* deg     = (int*)alloc((size_t)NN*4);
    int* indptr  = (int*)alloc((size_t)(NN+1)*4);
    int* cursor  = (int*)alloc((size_t)NN*4);
    int* eid     = (int*)alloc((size_t)NE*4);
    int* gstart  = (int*)alloc((size_t)(NG+1)*4);
    int* bsum    = (int*)alloc((size_t)NBLK_SCAN*4);
    int* boff    = (int*)alloc((size_t)NBLK_SCAN*4);

    const int NB_NE  = (NE+255)/256;
    const int NB_NC  = (NN*EMB+255)/256;
    const int NB_AG  = (NN*CG+255)/256;
    const int NB_GP  = (NG*SEM+255)/256;

    // ---- CSR build + edge pack + graph ranges ----
    k_zero_i <<<(NN+255)/256, 256, 0, stream>>>(deg, NN);
    k_hist   <<<NB_NE, 256, 0, stream>>>(dstArr, deg);
    k_scanA  <<<NBLK_SCAN, 256, 0, stream>>>(deg, bsum);
    k_scanB  <<<1, 128, 0, stream>>>(bsum, boff);
    k_scanC  <<<NBLK_SCAN, 256, 0, stream>>>(deg, boff, indptr, cursor);
    k_scatter<<<NB_NE, 256, 0, stream>>>(dstArr, cursor, eid);
    k_eprep  <<<NB_NE, 256, 0, stream>>>(eid, srcArr, eattr, epack);
    k_gstart <<<(NG+256)/256, 256, 0, stream>>>(batch, gstart);

    // ---- weight prep (transpose + bf16 + K-pad zeros) ----
    {
        dim3 g1t((HID+31)/32, SEM/32, 5);
        dim3 g2t((EMB+31)/32, SHID/32, 5);
        k_wprep<<<g1t, 256, 0, stream>>>(W1_g, wt1g, EMB, SEM, HID);
        k_wprep<<<g2t, 256, 0, stream>>>(W2_g, wt2g, HID, SHID, EMB);
        dim3 g1t2((HID+31)/32, SEM/32, 2);
        dim3 g2t2((EMB+31)/32, SHID/32, 2);
        k_wprep<<<g1t2, 256, 0, stream>>>(W1_r, wt1r, EMB, SEM, HID);
        k_wprep<<<g2t2, 256, 0, stream>>>(W2_r, wt2r, HID, SHID, EMB);
        dim3 g1t1((HID+31)/32, SEM/32, 1);
        k_wprep<<<g1t1, 256, 0, stream>>>(Wg1, wtg1, EMB, SEM, HID);
        k_wprep<<<g1t1, 256, 0, stream>>>(Wp1, wtp1, EMB, SEM, HID);
    }

    dim3 gm1((HID+127)/128, (NN+127)/128);  // (5, 235) TN=128
    dim3 gm2((EMB+127)/128, (NN+127)/128);  // (3, 235)

    // ---- node encoder (once) ----
    k_encoder<<<NB_NC, 256, 0, stream>>>(x, W_enc, b_enc, xfeat);

    // ---- fused layer-0 agg for BOTH stacks (shared gathers) ----
    k_agg4d<<<NB_AG, 256, 0, stream>>>(xfeat, We_r, be_r, We_g, be_g, epack, indptr, apx, apx2);

    // ---- rationale GIN stack (2 layers) ----
    for (int l=0; l<2; l++){
        const bf16* in = (l==0) ? xfeat : cur;
        if (l > 0)
            k_agg4 <<<NB_AG, 256, 0, stream>>>(in, We_r + l*3*EMB, be_r + l*EMB, epack, indptr, apx);
        k_gemm2<<<gm1, 256, 0, stream>>>(apx, wt1r + (size_t)l*HID*SEM, b1_r + l*HID, nullptr, mid,
                                         NN, HID, SEM, SHID, 1);
        k_gemm2<<<gm2, 256, 0, stream>>>(mid, wt2r + (size_t)l*EMB*SHID, b2_r + l*EMB, in, cur,
                                         NN, EMB, SHID, SEM, (l<1)?1:0);
    }
    // ---- gate from x_rat ----
    k_gemm2<<<gm1, 256, 0, stream>>>(cur, wtg1, bg1, nullptr, mid, NN, HID, SEM, SHID, 1);
    k_gate<<<NN/4, 256, 0, stream>>>(mid, Wg2, bg2, gumbel, gate);

    // ---- encoder GIN stack (5 layers); l0 uses pre-computed apx2 ----
    for (int l=0; l<5; l++){
        const bf16* in = (l==0) ? xfeat : cur;
        const bf16* ap = (l==0) ? apx2 : apx;
        if (l > 0)
            k_agg4 <<<NB_AG, 256, 0, stream>>>(in, We_g + l*3*EMB, be_g + l*EMB, epack, indptr, apx);
        k_gemm2<<<gm1, 256, 0, stream>>>(ap, wt1g + (size_t)l*HID*SEM, b1_g + l*HID, nullptr, mid,
                                         NN, HID, SEM, SHID, 1);
        k_gemm2<<<gm2, 256, 0, stream>>>(mid, wt2g + (size_t)l*EMB*SHID, b2_g + l*EMB, in, cur,
                                         NN, EMB, SHID, SEM, (l<4)?1:0);
    }
    // cur now holds h_node (bf16, stride SEM)

    // ---- pooling (segment scan) ----
    k_pool  <<<NG, 320, 0, stream>>>(cur, gate, gstart, sumh, sumgh);
    k_rnum  <<<(NG+3)/4, 256, 0, stream>>>(gate, gstart, rnum, cntf);
    k_mean  <<<NB_GP, 256, 0, stream>>>(sumh, sumgh, cntf, hr, henv, hout, hrb, henvb);
    k_pbuild<<<NB_GP, 256, 0, stream>>>(hr, henv, perm, Pbuf);
    k_norm  <<<(NG+3)/4, 256, 0, stream>>>(hr, henv, hout, na, ncv, pos);
    // ---- contrastive sim (MFMA) ----
    dim3 gsim((NG+127)/128, (NG+127)/128);
    k_sim_mfma<<<gsim, 256, 0, stream>>>(hrb, henvb, na, ncv, simcp);
    k_rowsum<<<NG, 256, 0, stream>>>(simcp, Ssum);
    // ---- head (MFMA) ----
    dim3 gph((HID+127)/128, (2*NG+127)/128);
    k_gemm2<<<gph, 256, 0, stream>>>(Pbuf, wtp1, bp1, nullptr, hidP, 2*NG, HID, SEM, SHID, 1);
    k_pred  <<<(2*NG+3)/4, 256, 0, stream>>>(hidP, Wp2, bp2, out);
    k_loss  <<<1, 256, 0, stream>>>(cntf, rnum, pos, Ssum, out);
}

// Round 13
// 999.877 us; speedup vs baseline: 1.7496x; 1.0379x over previous
//
#include <hip/hip_runtime.h>
#include <hip/hip_bf16.h>

typedef __hip_bfloat16 bf16;
typedef __attribute__((ext_vector_type(8))) short bf16x8;
typedef __attribute__((ext_vector_type(4))) float f32x4;

#define NN 30000      // nodes
#define NE 240000     // edges
#define NG 1500       // graphs
#define EMB 300
#define HID 600
#define NTASK 12
#define SEM 320       // padded stride for EMB-dim tensors
#define SHID 608      // padded stride for HID-dim tensors
#define CG 75         // 4-channel groups — 75 thr/node: best TLP (round-9 lesson)
#define NBLK_SCAN 118 // (NN+255)/256

__device__ __forceinline__ float tof(bf16 v){ return __bfloat162float(v); }
__device__ __forceinline__ bf16  tob(float v){ return __float2bfloat16(v); }
__device__ __forceinline__ float b2f(unsigned short u){ return __uint_as_float(((unsigned)u)<<16); }

// ---------------- utility ----------------
__global__ __launch_bounds__(256) void k_zero_i(int* __restrict__ p, int n){
    int i = blockIdx.x*256 + threadIdx.x;
    if (i < n) p[i] = 0;
}

// ---------------- CSR build (by dst) ----------------
__global__ __launch_bounds__(256) void k_hist(const int* __restrict__ dst, int* __restrict__ deg){
    int e = blockIdx.x*256 + threadIdx.x;
    if (e < NE) atomicAdd(&deg[dst[e]], 1);
}

__global__ __launch_bounds__(256) void k_scanA(const int* __restrict__ deg, int* __restrict__ bsum){
    __shared__ int red[256];
    int b = blockIdx.x, t = threadIdx.x;
    int i = b*256 + t;
    red[t] = (i < NN) ? deg[i] : 0;
    __syncthreads();
    for (int off=128; off>0; off>>=1){ if (t<off) red[t]+=red[t+off]; __syncthreads(); }
    if (t==0) bsum[b] = red[0];
}

__global__ __launch_bounds__(128) void k_scanB(const int* __restrict__ bsum, int* __restrict__ boff){
    __shared__ int s[128];
    int t = threadIdx.x;
    int v = (t < NBLK_SCAN) ? bsum[t] : 0;
    s[t] = v;
    __syncthreads();
    for (int off=1; off<128; off<<=1){
        int add = (t>=off) ? s[t-off] : 0;
        __syncthreads();
        s[t] += add;
        __syncthreads();
    }
    if (t < NBLK_SCAN) boff[t] = s[t] - v;   // exclusive
}

__global__ __launch_bounds__(256) void k_scanC(const int* __restrict__ deg, const int* __restrict__ boff,
                                               int* __restrict__ indptr, int* __restrict__ cursor){
    __shared__ int s[256];
    int b = blockIdx.x, t = threadIdx.x;
    int i = b*256 + t;
    int v = (i < NN) ? deg[i] : 0;
    s[t] = v;
    __syncthreads();
    for (int off=1; off<256; off<<=1){
        int add = (t>=off) ? s[t-off] : 0;
        __syncthreads();
        s[t] += add;
        __syncthreads();
    }
    int excl = s[t] - v + boff[b];
    if (i < NN){ indptr[i] = excl; cursor[i] = excl; }
    if (i == 0) indptr[NN] = NE;
}

__global__ __launch_bounds__(256) void k_scatter(const int* __restrict__ dst, int* __restrict__ cursor,
                                                 int* __restrict__ eid){
    int e = blockIdx.x*256 + threadIdx.x;
    if (e < NE){ int p = atomicAdd(&cursor[dst[e]], 1); eid[p] = e; }
}

__global__ __launch_bounds__(256) void k_eprep(const int* __restrict__ eid, const int* __restrict__ src,
                                               const float* __restrict__ eattr, float4* __restrict__ epack){
    int k = blockIdx.x*256 + threadIdx.x;
    if (k >= NE) return;
    int e = eid[k];
    float4 p;
    p.x = __int_as_float(src[e]);
    p.y = eattr[e*3]; p.z = eattr[e*3+1]; p.w = eattr[e*3+2];
    epack[k] = p;
}

__global__ __launch_bounds__(256) void k_gstart(const int* __restrict__ batch, int* __restrict__ gstart){
    int g = blockIdx.x*256 + threadIdx.x;
    if (g > NG) return;
    if (g == NG){ gstart[NG] = NN; return; }
    int lo=0, hi=NN;
    while (lo<hi){ int mid=(lo+hi)>>1; if (batch[mid] < g) lo=mid+1; else hi=mid; }
    gstart[g] = lo;
}

// ---------------- weight prep: Wt[n][kp] bf16 = W[k][n] fp32, zero-padded k>=K ----------------
__global__ __launch_bounds__(256) void k_wprep(const float* __restrict__ W, bf16* __restrict__ Wt,
                                               int K, int Kp, int N){
    __shared__ float t[32][33];
    const float* Wz = W + (size_t)blockIdx.z*K*N;
    bf16* Wtz = Wt + (size_t)blockIdx.z*N*Kp;
    int n0 = blockIdx.x*32, k0 = blockIdx.y*32;
    int tx = threadIdx.x & 31, ty = threadIdx.x >> 5;
    #pragma unroll
    for (int i=0;i<4;i++){
        int k = k0 + ty + i*8, n = n0 + tx;
        t[ty+i*8][tx] = (k<K && n<N) ? Wz[(size_t)k*N+n] : 0.f;
    }
    __syncthreads();
    #pragma unroll
    for (int i=0;i<4;i++){
        int n = n0 + ty + i*8, k = k0 + tx;
        if (n<N && k<Kp) Wtz[(size_t)n*Kp+k] = tob(t[tx][ty+i*8]);
    }
}

// ---------------- node encoder ----------------
__global__ __launch_bounds__(256) void k_encoder(const float* __restrict__ x, const float* __restrict__ W,
                                                 const float* __restrict__ b, bf16* __restrict__ xfeat){
    int idx = blockIdx.x*256 + threadIdx.x;
    if (idx >= NN*EMB) return;
    int n = idx / EMB, c = idx - n*EMB;
    float acc = b[c];
    #pragma unroll
    for (int k=0;k<9;k++) acc += x[n*9+k] * W[k*EMB+c];
    xfeat[(size_t)n*SEM + c] = tob(acc);
}

// ---------------- agg: thread=(node, 4-ch group); 2-deep epack+gather pipeline ----------------
__global__ __launch_bounds__(256) void k_agg4(const bf16* __restrict__ cur, const float* __restrict__ We,
                      const float* __restrict__ be, const float4* __restrict__ epack,
                      const int* __restrict__ indptr, bf16* __restrict__ apx){
    int idx = blockIdx.x*256 + threadIdx.x;
    if (idx >= NN*CG) return;
    int n = idx / CG, cg = idx - n*CG;
    int c0 = cg*4;
    float w0[4], w1[4], w2[4], bbv[4], acc[4];
    #pragma unroll
    for (int j=0;j<4;j++){
        w0[j] = We[c0+j]; w1[j] = We[EMB+c0+j]; w2[j] = We[2*EMB+c0+j]; bbv[j] = be[c0+j];
    }
    ushort4 hs = *(const ushort4*)&cur[(size_t)n*SEM + c0];
    acc[0]=b2f(hs.x); acc[1]=b2f(hs.y); acc[2]=b2f(hs.z); acc[3]=b2f(hs.w);
    int k  = indptr[n], k1 = indptr[n+1];

    auto accum4 = [&](float4 e0, float4 e1, float4 e2, float4 e3,
                      ushort4 ha, ushort4 hb, ushort4 hc, ushort4 hd){
        float fa[4] = {b2f(ha.x), b2f(ha.y), b2f(ha.z), b2f(ha.w)};
        float fb[4] = {b2f(hb.x), b2f(hb.y), b2f(hb.z), b2f(hb.w)};
        float fc[4] = {b2f(hc.x), b2f(hc.y), b2f(hc.z), b2f(hc.w)};
        float fd[4] = {b2f(hd.x), b2f(hd.y), b2f(hd.z), b2f(hd.w)};
        #pragma unroll
        for (int j=0;j<4;j++){
            float va = fa[j] + e0.y*w0[j] + e0.z*w1[j] + e0.w*w2[j] + bbv[j];
            float vb = fb[j] + e1.y*w0[j] + e1.z*w1[j] + e1.w*w2[j] + bbv[j];
            float vc = fc[j] + e2.y*w0[j] + e2.z*w1[j] + e2.w*w2[j] + bbv[j];
            float vd = fd[j] + e3.y*w0[j] + e3.z*w1[j] + e3.w*w2[j] + bbv[j];
            acc[j] += fmaxf(va, 0.f) + fmaxf(vb, 0.f) + fmaxf(vc, 0.f) + fmaxf(vd, 0.f);
        }
    };

    if (k + 4 <= k1){
        float4 e0 = epack[k], e1 = epack[k+1], e2 = epack[k+2], e3 = epack[k+3];
        ushort4 h0 = *(const ushort4*)&cur[(size_t)__float_as_int(e0.x)*SEM + c0];
        ushort4 h1 = *(const ushort4*)&cur[(size_t)__float_as_int(e1.x)*SEM + c0];
        ushort4 h2 = *(const ushort4*)&cur[(size_t)__float_as_int(e2.x)*SEM + c0];
        ushort4 h3 = *(const ushort4*)&cur[(size_t)__float_as_int(e3.x)*SEM + c0];
        while (k + 8 <= k1){
            float4 f0 = epack[k+4], f1 = epack[k+5], f2 = epack[k+6], f3 = epack[k+7];
            ushort4 g0 = *(const ushort4*)&cur[(size_t)__float_as_int(f0.x)*SEM + c0];
            ushort4 g1 = *(const ushort4*)&cur[(size_t)__float_as_int(f1.x)*SEM + c0];
            ushort4 g2 = *(const ushort4*)&cur[(size_t)__float_as_int(f2.x)*SEM + c0];
            ushort4 g3 = *(const ushort4*)&cur[(size_t)__float_as_int(f3.x)*SEM + c0];
            accum4(e0,e1,e2,e3, h0,h1,h2,h3);
            e0=f0; e1=f1; e2=f2; e3=f3;
            h0=g0; h1=g1; h2=g2; h3=g3;
            k += 4;
        }
        accum4(e0,e1,e2,e3, h0,h1,h2,h3);
        k += 4;
    }
    for (; k < k1; k++){
        float4 e0 = epack[k];
        int s0 = __float_as_int(e0.x);
        ushort4 ha = *(const ushort4*)&cur[(size_t)s0*SEM + c0];
        float fa[4] = {b2f(ha.x), b2f(ha.y), b2f(ha.z), b2f(ha.w)};
        #pragma unroll
        for (int j=0;j<4;j++){
            float va = fa[j] + e0.y*w0[j] + e0.z*w1[j] + e0.w*w2[j] + bbv[j];
            acc[j] += fmaxf(va, 0.f);
        }
    }
    ushort4 o;
    o.x = __bfloat16_as_ushort(tob(acc[0]));
    o.y = __bfloat16_as_ushort(tob(acc[1]));
    o.z = __bfloat16_as_ushort(tob(acc[2]));
    o.w = __bfloat16_as_ushort(tob(acc[3]));
    *(ushort4*)&apx[(size_t)n*SEM + c0] = o;
}

// ---------------- dual agg: one gather pass feeds BOTH weight sets (layer-0 fusion) ----------------
__global__ __launch_bounds__(256) void k_agg4d(const bf16* __restrict__ cur,
                      const float* __restrict__ WeA, const float* __restrict__ beA,
                      const float* __restrict__ WeB, const float* __restrict__ beB,
                      const float4* __restrict__ epack, const int* __restrict__ indptr,
                      bf16* __restrict__ apxA, bf16* __restrict__ apxB){
    int idx = blockIdx.x*256 + threadIdx.x;
    if (idx >= NN*CG) return;
    int n = idx / CG, cg = idx - n*CG;
    int c0 = cg*4;
    float a0[4], a1[4], a2[4], ab[4], accA[4];
    float b0[4], b1[4], b2[4], bb[4], accB[4];
    #pragma unroll
    for (int j=0;j<4;j++){
        a0[j]=WeA[c0+j]; a1[j]=WeA[EMB+c0+j]; a2[j]=WeA[2*EMB+c0+j]; ab[j]=beA[c0+j];
        b0[j]=WeB[c0+j]; b1[j]=WeB[EMB+c0+j]; b2[j]=WeB[2*EMB+c0+j]; bb[j]=beB[c0+j];
    }
    ushort4 hs = *(const ushort4*)&cur[(size_t)n*SEM + c0];
    float fs[4] = {b2f(hs.x), b2f(hs.y), b2f(hs.z), b2f(hs.w)};
    #pragma unroll
    for (int j=0;j<4;j++){ accA[j]=fs[j]; accB[j]=fs[j]; }
    int k = indptr[n], k1 = indptr[n+1];
    for (; k+2 <= k1; k += 2){
        float4 e0 = epack[k], e1 = epack[k+1];
        int s0 = __float_as_int(e0.x), s1 = __float_as_int(e1.x);
        ushort4 ha = *(const ushort4*)&cur[(size_t)s0*SEM + c0];
        ushort4 hb = *(const ushort4*)&cur[(size_t)s1*SEM + c0];
        float fa[4] = {b2f(ha.x), b2f(ha.y), b2f(ha.z), b2f(ha.w)};
        float fb[4] = {b2f(hb.x), b2f(hb.y), b2f(hb.z), b2f(hb.w)};
        #pragma unroll
        for (int j=0;j<4;j++){
            accA[j] += fmaxf(fa[j] + e0.y*a0[j] + e0.z*a1[j] + e0.w*a2[j] + ab[j], 0.f)
                     + fmaxf(fb[j] + e1.y*a0[j] + e1.z*a1[j] + e1.w*a2[j] + ab[j], 0.f);
            accB[j] += fmaxf(fa[j] + e0.y*b0[j] + e0.z*b1[j] + e0.w*b2[j] + bb[j], 0.f)
                     + fmaxf(fb[j] + e1.y*b0[j] + e1.z*b1[j] + e1.w*b2[j] + bb[j], 0.f);
        }
    }
    if (k < k1){
        float4 e0 = epack[k];
        int s0 = __float_as_int(e0.x);
        ushort4 ha = *(const ushort4*)&cur[(size_t)s0*SEM + c0];
        float fa[4] = {b2f(ha.x), b2f(ha.y), b2f(ha.z), b2f(ha.w)};
        #pragma unroll
        for (int j=0;j<4;j++){
            accA[j] += fmaxf(fa[j] + e0.y*a0[j] + e0.z*a1[j] + e0.w*a2[j] + ab[j], 0.f);
            accB[j] += fmaxf(fa[j] + e0.y*b0[j] + e0.z*b1[j] + e0.w*b2[j] + bb[j], 0.f);
        }
    }
    ushort4 oA, oB;
    oA.x=__bfloat16_as_ushort(tob(accA[0])); oA.y=__bfloat16_as_ushort(tob(accA[1]));
    oA.z=__bfloat16_as_ushort(tob(accA[2])); oA.w=__bfloat16_as_ushort(tob(accA[3]));
    oB.x=__bfloat16_as_ushort(tob(accB[0])); oB.y=__bfloat16_as_ushort(tob(accB[1]));
    oB.z=__bfloat16_as_ushort(tob(accB[2])); oB.w=__bfloat16_as_ushort(tob(accB[3]));
    *(ushort4*)&apxA[(size_t)n*SEM + c0] = oA;
    *(ushort4*)&apxB[(size_t)n*SEM + c0] = oB;
}

// ---------------- pipelined MFMA bf16 GEMM (round-10 exact: 1-pass epilogue) ----------------
// C[M][ldc] = bf16( [relu](A[M][Kp] @ Bt[N][Kp]^T + bias[N]) [+ R[M][ldc]] )
__global__ __launch_bounds__(256) void k_gemm2(const bf16* __restrict__ A, const bf16* __restrict__ Bt,
        const float* __restrict__ bias, const bf16* __restrict__ R, bf16* __restrict__ C,
        int M, int N, int Kp, int ldc, int relu_out){
    __shared__ __align__(16) char ldsbuf[34816];   // staging 16 KB, reused as 128x136 bf16 C-tile
    short (*Asl)[64][8] = reinterpret_cast<short(*)[64][8]>(ldsbuf);
    short (*Bsl)[64][8] = reinterpret_cast<short(*)[64][8]>(ldsbuf + 8192);
    short* Ct = reinterpret_cast<short*>(ldsbuf);
    const int CS = 136;
    int tid = threadIdx.x;
    int wave = tid >> 6, lane = tid & 63;
    int wm = wave >> 1, wn = wave & 1;
    int m0 = blockIdx.y*128, n0 = blockIdx.x*128;

    int srow = tid >> 1;
    int sq   = (tid & 1) * 2;
    int grA = min(m0 + srow, M-1);
    int grB = min(n0 + srow, N-1);
    const bf16* pA = A  + (size_t)grA*Kp + sq*8;
    const bf16* pB = Bt + (size_t)grB*Kp + sq*8;
    short* ldsA0 = &Asl[srow>>4][ sq   *16 + (srow&15)][0];
    short* ldsA1 = &Asl[srow>>4][(sq+1)*16 + (srow&15)][0];
    short* ldsB0 = &Bsl[srow>>4][ sq   *16 + (srow&15)][0];
    short* ldsB1 = &Bsl[srow>>4][(sq+1)*16 + (srow&15)][0];

    f32x4 acc[4][4];
    #pragma unroll
    for (int i=0;i<4;i++){
        #pragma unroll
        for (int j=0;j<4;j++) acc[i][j] = (f32x4){0.f,0.f,0.f,0.f};
    }

    int KC = Kp >> 5;
    uint4 ra0 = *(const uint4*)(pA);
    uint4 ra1 = *(const uint4*)(pA + 8);
    uint4 rb0 = *(const uint4*)(pB);
    uint4 rb1 = *(const uint4*)(pB + 8);

    for (int kc=0; kc<KC; ++kc){
        *(uint4*)ldsA0 = ra0; *(uint4*)ldsA1 = ra1;
        *(uint4*)ldsB0 = rb0; *(uint4*)ldsB1 = rb1;
        __syncthreads();
        if (kc+1 < KC){
            const bf16* qA = pA + (kc+1)*32;
            const bf16* qB = pB + (kc+1)*32;
            ra0 = *(const uint4*)(qA); ra1 = *(const uint4*)(qA+8);
            rb0 = *(const uint4*)(qB); rb1 = *(const uint4*)(qB+8);
        }
        bf16x8 af[4], bfr[4];
        #pragma unroll
        for (int i=0;i<4;i++) af[i]  = *(const bf16x8*)&Asl[wm*4+i][lane][0];
        #pragma unroll
        for (int j=0;j<4;j++) bfr[j] = *(const bf16x8*)&Bsl[wn*4+j][lane][0];
        #pragma unroll
        for (int i=0;i<4;i++){
            #pragma unroll
            for (int j=0;j<4;j++)
                acc[i][j] = __builtin_amdgcn_mfma_f32_16x16x32_bf16(af[i], bfr[j], acc[i][j], 0, 0, 0);
        }
        __syncthreads();
    }

    int lq = lane >> 4, lr = lane & 15;
    #pragma unroll
    for (int i=0;i<4;i++){
        int rl = (wm*4+i)*16 + lq*4;
        #pragma unroll
        for (int j=0;j<4;j++){
            int cl = (wn*4+j)*16 + lr;
            float bv = bias[min(n0+cl, N-1)];
            #pragma unroll
            for (int r=0;r<4;r++){
                float v = acc[i][j][r] + bv;
                if (relu_out) v = fmaxf(v, 0.f);
                Ct[(rl+r)*CS + cl] = (short)__bfloat16_as_ushort(tob(v));
            }
        }
    }
    __syncthreads();
    #pragma unroll
    for (int p=0;p<8;p++){
        int rl = p*16 + (tid>>4);
        int cl = (tid&15)*8;
        int row = m0 + rl, col = n0 + cl;
        if (row < M && col < N){
            union { short s8[8]; uint4 v; } u;
            u.v = *(uint4*)&Ct[rl*CS + cl];
            if (R){
                const bf16* rp = &R[(size_t)row*ldc + col];
                #pragma unroll
                for (int e=0;e<8;e++){
                    float v = b2f((unsigned short)u.s8[e]) + tof(rp[e]);
                    u.s8[e] = (short)__bfloat16_as_ushort(tob(v));
                }
            }
            *(uint4*)&C[(size_t)row*ldc + col] = u.v;
        }
    }
}

// ---------------- old-style MFMA machinery (kept for k_sim_mfma) ----------------
__device__ __forceinline__ void stage_tile(const short* __restrict__ P, int RB, int K, int r0, int k0,
                                           short (*lds)[64][8], int tid){
    #pragma unroll
    for (int s=0;s<2;s++){
        int seg = tid*2+s;
        int row = seg>>2, q = seg&3;
        int gr = r0 + row;
        int gk = k0 + q*8;
        union { short s8[8]; uint4 v; } u;
        if (gr < RB && gk + 8 <= K){
            const uint2* p = (const uint2*)(P + (size_t)gr*K + gk);
            uint2 lo = p[0], hi = p[1];
            u.v.x = lo.x; u.v.y = lo.y; u.v.z = hi.x; u.v.w = hi.y;
        } else {
            #pragma unroll
            for (int j=0;j<8;j++){
                int kk = gk + j;
                u.s8[j] = (gr < RB && kk < K) ? P[(size_t)gr*K + kk] : (short)0;
            }
        }
        *(uint4*)&lds[row>>4][q*16 + (row&15)][0] = u.v;
    }
}

// sim_cp[i][j] = exp( (hr_i . henv_j) * 5 / (na_i*nc_j + 1e-8) )
__global__ __launch_bounds__(256) void k_sim_mfma(const bf16* __restrict__ A, const bf16* __restrict__ Bt,
                      const float* __restrict__ na, const float* __restrict__ nc, float* __restrict__ C){
    __shared__ __align__(16) short Asl[8][64][8];
    __shared__ __align__(16) short Bsl[8][64][8];
    int tid = threadIdx.x;
    int wave = tid >> 6, lane = tid & 63;
    int wm = wave >> 1, wn = wave & 1;
    int m0 = blockIdx.y*128, n0 = blockIdx.x*128;
    f32x4 acc[4][4];
    #pragma unroll
    for (int i=0;i<4;i++){
        #pragma unroll
        for (int j=0;j<4;j++) acc[i][j] = (f32x4){0.f,0.f,0.f,0.f};
    }
    for (int k0=0; k0<SEM; k0+=32){
        stage_tile((const short*)A,  NG, SEM, m0, k0, Asl, tid);
        stage_tile((const short*)Bt, NG, SEM, n0, k0, Bsl, tid);
        __syncthreads();
        bf16x8 af[4], bfr[4];
        #pragma unroll
        for (int i=0;i<4;i++) af[i]  = *(const bf16x8*)&Asl[wm*4+i][lane][0];
        #pragma unroll
        for (int j=0;j<4;j++) bfr[j] = *(const bf16x8*)&Bsl[wn*4+j][lane][0];
        #pragma unroll
        for (int i=0;i<4;i++){
            #pragma unroll
            for (int j=0;j<4;j++)
                acc[i][j] = __builtin_amdgcn_mfma_f32_16x16x32_bf16(af[i], bfr[j], acc[i][j], 0, 0, 0);
        }
        __syncthreads();
    }
    int lq = lane >> 4, lr = lane & 15;
    #pragma unroll
    for (int i=0;i<4;i++){
        int rb = m0 + (wm*4+i)*16 + lq*4;
        #pragma unroll
        for (int j=0;j<4;j++){
            int col = n0 + (wn*4+j)*16 + lr;
            if (col >= NG) continue;
            float ncj = nc[col];
            #pragma unroll
            for (int r=0;r<4;r++){
                int row = rb + r;
                if (row >= NG) continue;
                C[(size_t)row*NG+col] = expf(acc[i][j][r] * 5.0f / (na[row]*ncj + 1e-8f));
            }
        }
    }
}

// ---------------- gate ----------------
__global__ __launch_bounds__(256) void k_gate(const bf16* __restrict__ mid, const float* __restrict__ Wg2,
                      const float* __restrict__ bg2, const float* __restrict__ gumbel, float* __restrict__ gate){
    int gw = blockIdx.x*4 + (threadIdx.x >> 6);
    int lane = threadIdx.x & 63;
    if (gw >= NN) return;
    float s0=0.f, s1=0.f;
    for (int i=lane;i<HID;i+=64){
        float h = tof(mid[(size_t)gw*SHID+i]);
        s0 += h * Wg2[i*2];
        s1 += h * Wg2[i*2+1];
    }
    for (int off=32; off>0; off>>=1){ s0 += __shfl_down(s0, off); s1 += __shfl_down(s1, off); }
    if (lane==0){
        float l0 = s0 + bg2[0] + gumbel[gw*2];
        float l1 = s1 + bg2[1] + gumbel[gw*2+1];
        float m = fmaxf(l0,l1);
        float e0 = expf(l0-m), e1 = expf(l1-m);
        gate[gw] = e1/(e0+e1);
    }
}

// ---------------- segment pooling ----------------
__global__ __launch_bounds__(320) void k_pool(const bf16* __restrict__ h, const float* __restrict__ gate,
                      const int* __restrict__ gstart, float* __restrict__ sumh, float* __restrict__ sumgh){
    int g = blockIdx.x, c = threadIdx.x;
    if (c >= EMB) return;
    int n0 = gstart[g], n1 = gstart[g+1];
    float sh=0.f, sg=0.f;
    for (int n=n0;n<n1;n++){
        float v = tof(h[(size_t)n*SEM+c]);
        float gt = gate[n];
        sh += v; sg += gt*v;
    }
    sumh[g*EMB+c] = sh; sumgh[g*EMB+c] = sg;
}

__global__ __launch_bounds__(256) void k_rnum(const float* __restrict__ gate, const int* __restrict__ gstart,
                      float* __restrict__ rnum, float* __restrict__ cntf){
    int g = blockIdx.x*4 + (threadIdx.x >> 6);
    int lane = threadIdx.x & 63;
    if (g >= NG) return;
    int n0 = gstart[g], n1 = gstart[g+1];
    float s=0.f;
    for (int n=n0+lane;n<n1;n+=64) s += gate[n];
    for (int off=32; off>0; off>>=1) s += __shfl_down(s, off);
    if (lane==0){ rnum[g] = s; cntf[g] = (float)(n1-n0); }
}

__global__ __launch_bounds__(256) void k_mean(const float* __restrict__ sumh, const float* __restrict__ sumgh,
                      const float* __restrict__ cntf, float* __restrict__ hr, float* __restrict__ henv,
                      float* __restrict__ hout, bf16* __restrict__ hrb, bf16* __restrict__ henvb){
    int idx = blockIdx.x*256 + threadIdx.x;
    if (idx >= NG*SEM) return;
    int g = idx / SEM, c = idx - g*SEM;
    if (c < EMB){
        int o = g*EMB + c;
        float inv = 1.f / fmaxf(cntf[g], 1.f);
        float sh = sumh[o], sg = sumgh[o];
        float r = sg*inv, e = (sh-sg)*inv;
        hr[o] = r; henv[o] = e; hout[o] = sh*inv;
        hrb[idx] = tob(r); henvb[idx] = tob(e);
    } else {
        hrb[idx] = tob(0.f); henvb[idx] = tob(0.f);   // zero pads (henvb is a B-operand!)
    }
}

__global__ __launch_bounds__(256) void k_pbuild(const float* __restrict__ hr, const float* __restrict__ henv,
                      const int* __restrict__ perm, bf16* __restrict__ P){
    int idx = blockIdx.x*256 + threadIdx.x;
    if (idx >= NG*SEM) return;
    int g = idx / SEM, c = idx - g*SEM;
    if (c < EMB){
        float v = hr[g*EMB+c];
        P[idx] = tob(v);
        P[(size_t)(NG+g)*SEM + c] = tob(v + henv[(size_t)perm[g]*EMB + c]);
    } else {
        P[idx] = tob(0.f);
        P[(size_t)(NG+g)*SEM + c] = tob(0.f);
    }
}

__global__ __launch_bounds__(256) void k_norm(const float* __restrict__ hr, const float* __restrict__ henv,
                      const float* __restrict__ hout, float* __restrict__ na, float* __restrict__ nc,
                      float* __restrict__ pos){
    int g = blockIdx.x*4 + (threadIdx.x >> 6);
    int lane = threadIdx.x & 63;
    if (g >= NG) return;
    float srr=0.f, soo=0.f, see=0.f, sro=0.f;
    for (int c=lane;c<EMB;c+=64){
        float r=hr[g*EMB+c], o=hout[g*EMB+c], e=henv[g*EMB+c];
        srr += r*r; soo += o*o; see += e*e; sro += r*o;
    }
    for (int off=32; off>0; off>>=1){
        srr += __shfl_down(srr,off); soo += __shfl_down(soo,off);
        see += __shfl_down(see,off); sro += __shfl_down(sro,off);
    }
    if (lane==0){
        float a = sqrtf(srr), b = sqrtf(soo), c2 = sqrtf(see);
        na[g] = a; nc[g] = c2;
        pos[g] = expf(sro/(a*b + 1e-8f) * 5.0f);
    }
}

__global__ __launch_bounds__(256) void k_rowsum(const float* __restrict__ simcp, float* __restrict__ S){
    __shared__ float red[256];
    int g = blockIdx.x, t = threadIdx.x;
    float s = 0.f;
    for (int j=t;j<NG;j+=256) s += simcp[(size_t)g*NG+j];
    red[t]=s; __syncthreads();
    for (int off=128; off>0; off>>=1){ if (t<off) red[t]+=red[t+off]; __syncthreads(); }
    if (t==0) S[g]=red[0];
}

__global__ __launch_bounds__(256) void k_pred(const bf16* __restrict__ hidP, const float* __restrict__ Wp2,
                      const float* __restrict__ bp2, float* __restrict__ out){
    int r = blockIdx.x*4 + (threadIdx.x >> 6);
    int lane = threadIdx.x & 63;
    if (r >= 2*NG) return;
    float acc[NTASK];
    #pragma unroll
    for (int t=0;t<NTASK;t++) acc[t] = 0.f;
    for (int i=lane;i<HID;i+=64){
        float h = tof(hidP[(size_t)r*SHID+i]);
        const float4* wp = (const float4*)&Wp2[i*NTASK];
        float4 wa = wp[0], wb = wp[1], wc = wp[2];
        acc[0]+=h*wa.x; acc[1]+=h*wa.y; acc[2]+=h*wa.z; acc[3]+=h*wa.w;
        acc[4]+=h*wb.x; acc[5]+=h*wb.y; acc[6]+=h*wb.z; acc[7]+=h*wb.w;
        acc[8]+=h*wc.x; acc[9]+=h*wc.y; acc[10]+=h*wc.z; acc[11]+=h*wc.w;
    }
    #pragma unroll
    for (int t=0;t<NTASK;t++){
        for (int off=32; off>0; off>>=1) acc[t] += __shfl_down(acc[t], off);
    }
    if (lane==0){
        float* dst = (r < NG) ? &out[NG*NTASK + r*NTASK] : &out[(r-NG)*NTASK];
        #pragma unroll
        for (int t=0;t<NTASK;t++) dst[t] = acc[t] + bp2[t];
    }
}

__global__ __launch_bounds__(256) void k_loss(const float* __restrict__ cntf, const float* __restrict__ rnum,
                      const float* __restrict__ pos, const float* __restrict__ S, float* __restrict__ out){
    __shared__ float ra[256], rb[256];
    int t = threadIdx.x;
    float a=0.f, b=0.f;
    for (int g=t; g<NG; g+=256){
        float r = rnum[g] + 1e-8f;
        float e = (cntf[g] - rnum[g]) + 1e-8f;
        a += fabsf(r/(r+e) - 0.4f);
        float p = pos[g];
        b += -logf(p/(S[g]+p));
    }
    ra[t]=a; rb[t]=b; __syncthreads();
    for (int off=128; off>0; off>>=1){ if (t<off){ ra[t]+=ra[t+off]; rb[t]+=rb[t+off]; } __syncthreads(); }
    if (t==0){
        out[2*NG*NTASK]   = ra[0]/NG;
        out[2*NG*NTASK+1] = rb[0]/NG;
    }
}

extern "C" void kernel_launch(void* const* d_in, const int* in_sizes, int n_in,
                              void* d_out, int out_size, void* d_ws, size_t ws_size,
                              hipStream_t stream) {
    const float* x      = (const float*)d_in[0];
    const float* eattr  = (const float*)d_in[1];
    const int*   eidx   = (const int*)d_in[2];
    const int*   batch  = (const int*)d_in[3];
    const float* gumbel = (const float*)d_in[4];
    const int*   perm   = (const int*)d_in[5];
    const float* W_enc  = (const float*)d_in[6];
    const float* b_enc  = (const float*)d_in[7];
    const float* We_g   = (const float*)d_in[8];
    const float* be_g   = (const float*)d_in[9];
    const float* W1_g   = (const float*)d_in[10];
    const float* b1_g   = (const float*)d_in[11];
    const float* W2_g   = (const float*)d_in[12];
    const float* b2_g   = (const float*)d_in[13];
    const float* We_r   = (const float*)d_in[14];
    const float* be_r   = (const float*)d_in[15];
    const float* W1_r   = (const float*)d_in[16];
    const float* b1_r   = (const float*)d_in[17];
    const float* W2_r   = (const float*)d_in[18];
    const float* b2_r   = (const float*)d_in[19];
    const float* Wg1    = (const float*)d_in[20];
    const float* bg1    = (const float*)d_in[21];
    const float* Wg2    = (const float*)d_in[22];
    const float* bg2    = (const float*)d_in[23];
    const float* Wp1    = (const float*)d_in[24];
    const float* bp1    = (const float*)d_in[25];
    const float* Wp2    = (const float*)d_in[26];
    const float* bp2    = (const float*)d_in[27];
    float* out = (float*)d_out;

    const int* srcArr = eidx;
    const int* dstArr = eidx + NE;

    // ---- workspace (bump allocator, 256B aligned) ----
    char* w = (char*)d_ws;
    size_t off = 0;
    auto alloc = [&](size_t bytes)->char*{ char* p = w + off; off += (bytes + 255) & ~(size_t)255; return p; };
    bf16* xfeat = (bf16*)alloc((size_t)NN*SEM*2);
    bf16* cur   = (bf16*)alloc((size_t)NN*SEM*2);
    bf16* apx   = (bf16*)alloc((size_t)NN*SEM*2);
    bf16* apx2  = (bf16*)alloc((size_t)NN*SEM*2);     // encoder-l0 agg output (fused dual agg)
    char* midc  = alloc((size_t)NN*SHID*2);           // 36.5 MB; reused after stacks
    bf16* mid   = (bf16*)midc;
    float* simcp = (float*)midc;                      // NG*NG*4 = 9 MB
    bf16* Pbuf   = (bf16*)(midc + 12*1024*1024);
    bf16* hidP   = (bf16*)(midc + 20*1024*1024);
    bf16* wt1g  = (bf16*)alloc((size_t)5*HID*SEM*2);
    bf16* wt2g  = (bf16*)alloc((size_t)5*EMB*SHID*2);
    bf16* wt1r  = (bf16*)alloc((size_t)2*HID*SEM*2);
    bf16* wt2r  = (bf16*)alloc((size_t)2*EMB*SHID*2);
    bf16* wtg1  = (bf16*)alloc((size_t)HID*SEM*2);
    bf16* wtp1  = (bf16*)alloc((size_t)HID*SEM*2);
    float4* epack = (float4*)alloc((size_t)NE*16);
    float* gate  = (float*)alloc((size_t)NN*4);
    float* sumh  = (float*)alloc((size_t)NG*EMB*4);
    float* sumgh = (float*)alloc((size_t)NG*EMB*4);
    float* hr    = (float*)alloc((size_t)NG*EMB*4);
    float* henv  = (float*)alloc((size_t)NG*EMB*4);
    float* hout  = (float*)alloc((size_t)NG*EMB*4);
    bf16* hrb    = (bf16*)alloc((size_t)NG*SEM*2);
    bf16* henvb  = (bf16*)alloc((size_t)NG*SEM*2);
    float* rnum  = (float*)alloc(NG*4);
    float* cntf  = (float*)alloc(NG*4);
    float* na    = (float*)alloc(NG*4);
    float* ncv   = (float*)alloc(NG*4);
    float* pos   = (float*)alloc(NG*4);
    float* Ssum  = (float*)alloc(NG*4);
    int* deg     = (int*)alloc((size_t)NN*4);
    int* indptr  = (int*)alloc((size_t)(NN+1)*4);
    int* cursor  = (int*)alloc((size_t)NN*4);
    int* eid     = (int*)alloc((size_t)NE*4);
    int* gstart  = (int*)alloc((size_t)(NG+1)*4);
    int* bsum    = (int*)alloc((size_t)NBLK_SCAN*4);
    int* boff    = (int*)alloc((size_t)NBLK_SCAN*4);

    const int NB_NE  = (NE+255)/256;
    const int NB_NC  = (NN*EMB+255)/256;
    const int NB_AG  = (NN*CG+255)/256;
    const int NB_GP  = (NG*SEM+255)/256;

    // ---- CSR build + edge pack + graph ranges ----
    k_zero_i <<<(NN+255)/256, 256, 0, stream>>>(deg, NN);
    k_hist   <<<NB_NE, 256, 0, stream>>>(dstArr, deg);
    k_scanA  <<<NBLK_SCAN, 256, 0, stream>>>(deg, bsum);
    k_scanB  <<<1, 128, 0, stream>>>(bsum, boff);
    k_scanC  <<<NBLK_SCAN, 256, 0, stream>>>(deg, boff, indptr, cursor);
    k_scatter<<<NB_NE, 256, 0, stream>>>(dstArr, cursor, eid);
    k_eprep  <<<NB_NE, 256, 0, stream>>>(eid, srcArr, eattr, epack);
    k_gstart <<<(NG+256)/256, 256, 0, stream>>>(batch, gstart);

    // ---- weight prep (transpose + bf16 + K-pad zeros) ----
    {
        dim3 g1t((HID+31)/32, SEM/32, 5);
        dim3 g2t((EMB+31)/32, SHID/32, 5);
        k_wprep<<<g1t, 256, 0, stream>>>(W1_g, wt1g, EMB, SEM, HID);
        k_wprep<<<g2t, 256, 0, stream>>>(W2_g, wt2g, HID, SHID, EMB);
        dim3 g1t2((HID+31)/32, SEM/32, 2);
        dim3 g2t2((EMB+31)/32, SHID/32, 2);
        k_wprep<<<g1t2, 256, 0, stream>>>(W1_r, wt1r, EMB, SEM, HID);
        k_wprep<<<g2t2, 256, 0, stream>>>(W2_r, wt2r, HID, SHID, EMB);
        dim3 g1t1((HID+31)/32, SEM/32, 1);
        k_wprep<<<g1t1, 256, 0, stream>>>(Wg1, wtg1, EMB, SEM, HID);
        k_wprep<<<g1t1, 256, 0, stream>>>(Wp1, wtp1, EMB, SEM, HID);
    }

    dim3 gm1((HID+127)/128, (NN+127)/128);  // (5, 235) TN=128
    dim3 gm2((EMB+127)/128, (NN+127)/128);  // (3, 235)

    // ---- node encoder (once) ----
    k_encoder<<<NB_NC, 256, 0, stream>>>(x, W_enc, b_enc, xfeat);

    // ---- fused layer-0 agg for BOTH stacks (shared gathers) ----
    k_agg4d<<<NB_AG, 256, 0, stream>>>(xfeat, We_r, be_r, We_g, be_g, epack, indptr, apx, apx2);

    // ---- rationale GIN stack (2 layers) ----
    for (int l=0; l<2; l++){
        const bf16* in = (l==0) ? xfeat : cur;
        if (l > 0)
            k_agg4 <<<NB_AG, 256, 0, stream>>>(in, We_r + l*3*EMB, be_r + l*EMB, epack, indptr, apx);
        k_gemm2<<<gm1, 256, 0, stream>>>(apx, wt1r + (size_t)l*HID*SEM, b1_r + l*HID, nullptr, mid,
                                         NN, HID, SEM, SHID, 1);
        k_gemm2<<<gm2, 256, 0, stream>>>(mid, wt2r + (size_t)l*EMB*SHID, b2_r + l*EMB, in, cur,
                                         NN, EMB, SHID, SEM, (l<1)?1:0);
    }
    // ---- gate from x_rat ----
    k_gemm2<<<gm1, 256, 0, stream>>>(cur, wtg1, bg1, nullptr, mid, NN, HID, SEM, SHID, 1);
    k_gate<<<NN/4, 256, 0, stream>>>(mid, Wg2, bg2, gumbel, gate);

    // ---- encoder GIN stack (5 layers); l0 uses pre-computed apx2 ----
    for (int l=0; l<5; l++){
        const bf16* in = (l==0) ? xfeat : cur;
        const bf16* ap = (l==0) ? apx2 : apx;
        if (l > 0)
            k_agg4 <<<NB_AG, 256, 0, stream>>>(in, We_g + l*3*EMB, be_g + l*EMB, epack, indptr, apx);
        k_gemm2<<<gm1, 256, 0, stream>>>(ap, wt1g + (size_t)l*HID*SEM, b1_g + l*HID, nullptr, mid,
                                         NN, HID, SEM, SHID, 1);
        k_gemm2<<<gm2, 256, 0, stream>>>(mid, wt2g + (size_t)l*EMB*SHID, b2_g + l*EMB, in, cur,
                                         NN, EMB, SHID, SEM, (l<4)?1:0);
    }
    // cur now holds h_node (bf16, stride SEM)

    // ---- pooling (segment scan) ----
    k_pool  <<<NG, 320, 0, stream>>>(cur, gate, gstart, sumh, sumgh);
    k_rnum  <<<(NG+3)/4, 256, 0, stream>>>(gate, gstart, rnum, cntf);
    k_mean  <<<NB_GP, 256, 0, stream>>>(sumh, sumgh, cntf, hr, henv, hout, hrb, henvb);
    k_pbuild<<<NB_GP, 256, 0, stream>>>(hr, henv, perm, Pbuf);
    k_norm  <<<(NG+3)/4, 256, 0, stream>>>(hr, henv, hout, na, ncv, pos);
    // ---- contrastive sim (MFMA) ----
    dim3 gsim((NG+127)/128, (NG+127)/128);
    k_sim_mfma<<<gsim, 256, 0, stream>>>(hrb, henvb, na, ncv, simcp);
    k_rowsum<<<NG, 256, 0, stream>>>(simcp, Ssum);
    // ---- head (MFMA) ----
    dim3 gph((HID+127)/128, (2*NG+127)/128);
    k_gemm2<<<gph, 256, 0, stream>>>(Pbuf, wtp1, bp1, nullptr, hidP, 2*NG, HID, SEM, SHID, 1);
    k_pred  <<<(2*NG+3)/4, 256, 0, stream>>>(hidP, Wp2, bp2, out);
    k_loss  <<<1, 256, 0, stream>>>(cntf, rnum, pos, Ssum, out);
}

// Round 14
// 997.431 us; speedup vs baseline: 1.7539x; 1.0025x over previous
//
#include <hip/hip_runtime.h>
#include <hip/hip_bf16.h>

typedef __hip_bfloat16 bf16;
typedef __attribute__((ext_vector_type(8))) short bf16x8;
typedef __attribute__((ext_vector_type(4))) float f32x4;

#define NN 30000      // nodes
#define NE 240000     // edges
#define NG 1500       // graphs
#define EMB 300
#define HID 600
#define NTASK 12
#define SEM 320       // padded stride for EMB-dim tensors
#define SHID 608      // padded stride for HID-dim tensors
#define CG 75         // 4-channel groups — 75 thr/node: best TLP (round-9 lesson)
#define NBLK_SCAN 118 // (NN+255)/256

__device__ __forceinline__ float tof(bf16 v){ return __bfloat162float(v); }
__device__ __forceinline__ bf16  tob(float v){ return __float2bfloat16(v); }
__device__ __forceinline__ float b2f(unsigned short u){ return __uint_as_float(((unsigned)u)<<16); }

// ---------------- utility ----------------
__global__ __launch_bounds__(256) void k_zero_i(int* __restrict__ p, int n){
    int i = blockIdx.x*256 + threadIdx.x;
    if (i < n) p[i] = 0;
}

// ---------------- CSR build (by dst) ----------------
__global__ __launch_bounds__(256) void k_hist(const int* __restrict__ dst, int* __restrict__ deg){
    int e = blockIdx.x*256 + threadIdx.x;
    if (e < NE) atomicAdd(&deg[dst[e]], 1);
}

__global__ __launch_bounds__(256) void k_scanA(const int* __restrict__ deg, int* __restrict__ bsum){
    __shared__ int red[256];
    int b = blockIdx.x, t = threadIdx.x;
    int i = b*256 + t;
    red[t] = (i < NN) ? deg[i] : 0;
    __syncthreads();
    for (int off=128; off>0; off>>=1){ if (t<off) red[t]+=red[t+off]; __syncthreads(); }
    if (t==0) bsum[b] = red[0];
}

__global__ __launch_bounds__(128) void k_scanB(const int* __restrict__ bsum, int* __restrict__ boff){
    __shared__ int s[128];
    int t = threadIdx.x;
    int v = (t < NBLK_SCAN) ? bsum[t] : 0;
    s[t] = v;
    __syncthreads();
    for (int off=1; off<128; off<<=1){
        int add = (t>=off) ? s[t-off] : 0;
        __syncthreads();
        s[t] += add;
        __syncthreads();
    }
    if (t < NBLK_SCAN) boff[t] = s[t] - v;   // exclusive
}

__global__ __launch_bounds__(256) void k_scanC(const int* __restrict__ deg, const int* __restrict__ boff,
                                               int* __restrict__ indptr, int* __restrict__ cursor){
    __shared__ int s[256];
    int b = blockIdx.x, t = threadIdx.x;
    int i = b*256 + t;
    int v = (i < NN) ? deg[i] : 0;
    s[t] = v;
    __syncthreads();
    for (int off=1; off<256; off<<=1){
        int add = (t>=off) ? s[t-off] : 0;
        __syncthreads();
        s[t] += add;
        __syncthreads();
    }
    int excl = s[t] - v + boff[b];
    if (i < NN){ indptr[i] = excl; cursor[i] = excl; }
    if (i == 0) indptr[NN] = NE;
}

__global__ __launch_bounds__(256) void k_scatter(const int* __restrict__ dst, int* __restrict__ cursor,
                                                 int* __restrict__ eid){
    int e = blockIdx.x*256 + threadIdx.x;
    if (e < NE){ int p = atomicAdd(&cursor[dst[e]], 1); eid[p] = e; }
}

__global__ __launch_bounds__(256) void k_eprep(const int* __restrict__ eid, const int* __restrict__ src,
                                               const float* __restrict__ eattr, float4* __restrict__ epack){
    int k = blockIdx.x*256 + threadIdx.x;
    if (k >= NE) return;
    int e = eid[k];
    float4 p;
    p.x = __int_as_float(src[e]);
    p.y = eattr[e*3]; p.z = eattr[e*3+1]; p.w = eattr[e*3+2];
    epack[k] = p;
}

__global__ __launch_bounds__(256) void k_gstart(const int* __restrict__ batch, int* __restrict__ gstart){
    int g = blockIdx.x*256 + threadIdx.x;
    if (g > NG) return;
    if (g == NG){ gstart[NG] = NN; return; }
    int lo=0, hi=NN;
    while (lo<hi){ int mid=(lo+hi)>>1; if (batch[mid] < g) lo=mid+1; else hi=mid; }
    gstart[g] = lo;
}

// ---------------- weight prep: Wt[n][kp] bf16 = W[k][n] fp32, zero-padded k>=K ----------------
__global__ __launch_bounds__(256) void k_wprep(const float* __restrict__ W, bf16* __restrict__ Wt,
                                               int K, int Kp, int N){
    __shared__ float t[32][33];
    const float* Wz = W + (size_t)blockIdx.z*K*N;
    bf16* Wtz = Wt + (size_t)blockIdx.z*N*Kp;
    int n0 = blockIdx.x*32, k0 = blockIdx.y*32;
    int tx = threadIdx.x & 31, ty = threadIdx.x >> 5;
    #pragma unroll
    for (int i=0;i<4;i++){
        int k = k0 + ty + i*8, n = n0 + tx;
        t[ty+i*8][tx] = (k<K && n<N) ? Wz[(size_t)k*N+n] : 0.f;
    }
    __syncthreads();
    #pragma unroll
    for (int i=0;i<4;i++){
        int n = n0 + ty + i*8, k = k0 + tx;
        if (n<N && k<Kp) Wtz[(size_t)n*Kp+k] = tob(t[tx][ty+i*8]);
    }
}

// ---------------- node encoder ----------------
__global__ __launch_bounds__(256) void k_encoder(const float* __restrict__ x, const float* __restrict__ W,
                                                 const float* __restrict__ b, bf16* __restrict__ xfeat){
    int idx = blockIdx.x*256 + threadIdx.x;
    if (idx >= NN*EMB) return;
    int n = idx / EMB, c = idx - n*EMB;
    float acc = b[c];
    #pragma unroll
    for (int k=0;k<9;k++) acc += x[n*9+k] * W[k*EMB+c];
    xfeat[(size_t)n*SEM + c] = tob(acc);
}

// ---------------- agg: thread=(node, 4-ch group); 2-deep epack+gather pipeline ----------------
__global__ __launch_bounds__(256) void k_agg4(const bf16* __restrict__ cur, const float* __restrict__ We,
                      const float* __restrict__ be, const float4* __restrict__ epack,
                      const int* __restrict__ indptr, bf16* __restrict__ apx){
    int idx = blockIdx.x*256 + threadIdx.x;
    if (idx >= NN*CG) return;
    int n = idx / CG, cg = idx - n*CG;
    int c0 = cg*4;
    float w0[4], w1[4], w2[4], bbv[4], acc[4];
    #pragma unroll
    for (int j=0;j<4;j++){
        w0[j] = We[c0+j]; w1[j] = We[EMB+c0+j]; w2[j] = We[2*EMB+c0+j]; bbv[j] = be[c0+j];
    }
    ushort4 hs = *(const ushort4*)&cur[(size_t)n*SEM + c0];
    acc[0]=b2f(hs.x); acc[1]=b2f(hs.y); acc[2]=b2f(hs.z); acc[3]=b2f(hs.w);
    int k  = indptr[n], k1 = indptr[n+1];

    auto accum4 = [&](float4 e0, float4 e1, float4 e2, float4 e3,
                      ushort4 ha, ushort4 hb, ushort4 hc, ushort4 hd){
        float fa[4] = {b2f(ha.x), b2f(ha.y), b2f(ha.z), b2f(ha.w)};
        float fb[4] = {b2f(hb.x), b2f(hb.y), b2f(hb.z), b2f(hb.w)};
        float fc[4] = {b2f(hc.x), b2f(hc.y), b2f(hc.z), b2f(hc.w)};
        float fd[4] = {b2f(hd.x), b2f(hd.y), b2f(hd.z), b2f(hd.w)};
        #pragma unroll
        for (int j=0;j<4;j++){
            float va = fa[j] + e0.y*w0[j] + e0.z*w1[j] + e0.w*w2[j] + bbv[j];
            float vb = fb[j] + e1.y*w0[j] + e1.z*w1[j] + e1.w*w2[j] + bbv[j];
            float vc = fc[j] + e2.y*w0[j] + e2.z*w1[j] + e2.w*w2[j] + bbv[j];
            float vd = fd[j] + e3.y*w0[j] + e3.z*w1[j] + e3.w*w2[j] + bbv[j];
            acc[j] += fmaxf(va, 0.f) + fmaxf(vb, 0.f) + fmaxf(vc, 0.f) + fmaxf(vd, 0.f);
        }
    };

    if (k + 4 <= k1){
        float4 e0 = epack[k], e1 = epack[k+1], e2 = epack[k+2], e3 = epack[k+3];
        ushort4 h0 = *(const ushort4*)&cur[(size_t)__float_as_int(e0.x)*SEM + c0];
        ushort4 h1 = *(const ushort4*)&cur[(size_t)__float_as_int(e1.x)*SEM + c0];
        ushort4 h2 = *(const ushort4*)&cur[(size_t)__float_as_int(e2.x)*SEM + c0];
        ushort4 h3 = *(const ushort4*)&cur[(size_t)__float_as_int(e3.x)*SEM + c0];
        while (k + 8 <= k1){
            float4 f0 = epack[k+4], f1 = epack[k+5], f2 = epack[k+6], f3 = epack[k+7];
            ushort4 g0 = *(const ushort4*)&cur[(size_t)__float_as_int(f0.x)*SEM + c0];
            ushort4 g1 = *(const ushort4*)&cur[(size_t)__float_as_int(f1.x)*SEM + c0];
            ushort4 g2 = *(const ushort4*)&cur[(size_t)__float_as_int(f2.x)*SEM + c0];
            ushort4 g3 = *(const ushort4*)&cur[(size_t)__float_as_int(f3.x)*SEM + c0];
            accum4(e0,e1,e2,e3, h0,h1,h2,h3);
            e0=f0; e1=f1; e2=f2; e3=f3;
            h0=g0; h1=g1; h2=g2; h3=g3;
            k += 4;
        }
        accum4(e0,e1,e2,e3, h0,h1,h2,h3);
        k += 4;
    }
    for (; k < k1; k++){
        float4 e0 = epack[k];
        int s0 = __float_as_int(e0.x);
        ushort4 ha = *(const ushort4*)&cur[(size_t)s0*SEM + c0];
        float fa[4] = {b2f(ha.x), b2f(ha.y), b2f(ha.z), b2f(ha.w)};
        #pragma unroll
        for (int j=0;j<4;j++){
            float va = fa[j] + e0.y*w0[j] + e0.z*w1[j] + e0.w*w2[j] + bbv[j];
            acc[j] += fmaxf(va, 0.f);
        }
    }
    ushort4 o;
    o.x = __bfloat16_as_ushort(tob(acc[0]));
    o.y = __bfloat16_as_ushort(tob(acc[1]));
    o.z = __bfloat16_as_ushort(tob(acc[2]));
    o.w = __bfloat16_as_ushort(tob(acc[3]));
    *(ushort4*)&apx[(size_t)n*SEM + c0] = o;
}

// ---------------- dual agg: one gather pass feeds BOTH weight sets (layer-0 fusion) ----------------
__global__ __launch_bounds__(256) void k_agg4d(const bf16* __restrict__ cur,
                      const float* __restrict__ WeA, const float* __restrict__ beA,
                      const float* __restrict__ WeB, const float* __restrict__ beB,
                      const float4* __restrict__ epack, const int* __restrict__ indptr,
                      bf16* __restrict__ apxA, bf16* __restrict__ apxB){
    int idx = blockIdx.x*256 + threadIdx.x;
    if (idx >= NN*CG) return;
    int n = idx / CG, cg = idx - n*CG;
    int c0 = cg*4;
    float a0[4], a1[4], a2[4], ab[4], accA[4];
    float b0[4], b1[4], b2[4], bb[4], accB[4];
    #pragma unroll
    for (int j=0;j<4;j++){
        a0[j]=WeA[c0+j]; a1[j]=WeA[EMB+c0+j]; a2[j]=WeA[2*EMB+c0+j]; ab[j]=beA[c0+j];
        b0[j]=WeB[c0+j]; b1[j]=WeB[EMB+c0+j]; b2[j]=WeB[2*EMB+c0+j]; bb[j]=beB[c0+j];
    }
    ushort4 hs = *(const ushort4*)&cur[(size_t)n*SEM + c0];
    float fs[4] = {b2f(hs.x), b2f(hs.y), b2f(hs.z), b2f(hs.w)};
    #pragma unroll
    for (int j=0;j<4;j++){ accA[j]=fs[j]; accB[j]=fs[j]; }
    int k = indptr[n], k1 = indptr[n+1];
    for (; k+2 <= k1; k += 2){
        float4 e0 = epack[k], e1 = epack[k+1];
        int s0 = __float_as_int(e0.x), s1 = __float_as_int(e1.x);
        ushort4 ha = *(const ushort4*)&cur[(size_t)s0*SEM + c0];
        ushort4 hb = *(const ushort4*)&cur[(size_t)s1*SEM + c0];
        float fa[4] = {b2f(ha.x), b2f(ha.y), b2f(ha.z), b2f(ha.w)};
        float fb[4] = {b2f(hb.x), b2f(hb.y), b2f(hb.z), b2f(hb.w)};
        #pragma unroll
        for (int j=0;j<4;j++){
            accA[j] += fmaxf(fa[j] + e0.y*a0[j] + e0.z*a1[j] + e0.w*a2[j] + ab[j], 0.f)
                     + fmaxf(fb[j] + e1.y*a0[j] + e1.z*a1[j] + e1.w*a2[j] + ab[j], 0.f);
            accB[j] += fmaxf(fa[j] + e0.y*b0[j] + e0.z*b1[j] + e0.w*b2[j] + bb[j], 0.f)
                     + fmaxf(fb[j] + e1.y*b0[j] + e1.z*b1[j] + e1.w*b2[j] + bb[j], 0.f);
        }
    }
    if (k < k1){
        float4 e0 = epack[k];
        int s0 = __float_as_int(e0.x);
        ushort4 ha = *(const ushort4*)&cur[(size_t)s0*SEM + c0];
        float fa[4] = {b2f(ha.x), b2f(ha.y), b2f(ha.z), b2f(ha.w)};
        #pragma unroll
        for (int j=0;j<4;j++){
            accA[j] += fmaxf(fa[j] + e0.y*a0[j] + e0.z*a1[j] + e0.w*a2[j] + ab[j], 0.f);
            accB[j] += fmaxf(fa[j] + e0.y*b0[j] + e0.z*b1[j] + e0.w*b2[j] + bb[j], 0.f);
        }
    }
    ushort4 oA, oB;
    oA.x=__bfloat16_as_ushort(tob(accA[0])); oA.y=__bfloat16_as_ushort(tob(accA[1]));
    oA.z=__bfloat16_as_ushort(tob(accA[2])); oA.w=__bfloat16_as_ushort(tob(accA[3]));
    oB.x=__bfloat16_as_ushort(tob(accB[0])); oB.y=__bfloat16_as_ushort(tob(accB[1]));
    oB.z=__bfloat16_as_ushort(tob(accB[2])); oB.w=__bfloat16_as_ushort(tob(accB[3]));
    *(ushort4*)&apxA[(size_t)n*SEM + c0] = oA;
    *(ushort4*)&apxB[(size_t)n*SEM + c0] = oB;
}

// ---------------- MFMA bf16 GEMM: LDS double-buffered K-loop (ONE barrier per chunk) ----------------
// C[M][ldc] = bf16( [relu](A[M][Kp] @ Bt[N][Kp]^T + bias[N]) [+ R[M][ldc]] )
// Staging ping-pong: buf b at b*16384 bytes (A 8KB + B 8KB). Epilogue C-tile reuses the 34KB buffer.
__global__ __launch_bounds__(256) void k_gemm2(const bf16* __restrict__ A, const bf16* __restrict__ Bt,
        const float* __restrict__ bias, const bf16* __restrict__ R, bf16* __restrict__ C,
        int M, int N, int Kp, int ldc, int relu_out){
    __shared__ __align__(16) char ldsbuf[34816];
    short* lds = reinterpret_cast<short*>(ldsbuf);
    short* Ct  = reinterpret_cast<short*>(ldsbuf);
    const int CS = 136;
    int tid = threadIdx.x;
    int wave = tid >> 6, lane = tid & 63;
    int wm = wave >> 1, wn = wave & 1;
    int m0 = blockIdx.y*128, n0 = blockIdx.x*128;

    // staging: thread -> row srow, quads sq, sq+1 (16B each)
    int srow = tid >> 1;
    int sq   = (tid & 1) * 2;
    int grA = min(m0 + srow, M-1);
    int grB = min(n0 + srow, N-1);
    const bf16* pA = A  + (size_t)grA*Kp + sq*8;
    const bf16* pB = Bt + (size_t)grB*Kp + sq*8;
    // slot offsets in shorts, within one staging buffer (A at 0, B at +4096)
    int aoff0 = ((srow>>4)*64 +  sq   *16 + (srow&15))*8;
    int aoff1 = ((srow>>4)*64 + (sq+1)*16 + (srow&15))*8;

    f32x4 acc[4][4];
    #pragma unroll
    for (int i=0;i<4;i++){
        #pragma unroll
        for (int j=0;j<4;j++) acc[i][j] = (f32x4){0.f,0.f,0.f,0.f};
    }

    int KC = Kp >> 5;
    // chunk 0: load + write buf0
    uint4 ra0 = *(const uint4*)(pA);
    uint4 ra1 = *(const uint4*)(pA + 8);
    uint4 rb0 = *(const uint4*)(pB);
    uint4 rb1 = *(const uint4*)(pB + 8);
    *(uint4*)(lds + aoff0)        = ra0;
    *(uint4*)(lds + aoff1)        = ra1;
    *(uint4*)(lds + 4096 + aoff0) = rb0;
    *(uint4*)(lds + 4096 + aoff1) = rb1;
    __syncthreads();
    if (KC > 1){
        ra0 = *(const uint4*)(pA + 32); ra1 = *(const uint4*)(pA + 40);
        rb0 = *(const uint4*)(pB + 32); rb1 = *(const uint4*)(pB + 40);
    }

    for (int kc=0; kc<KC; ++kc){
        short* cbuf = lds + (kc & 1)*8192;
        short* nbuf = lds + ((kc+1) & 1)*8192;
        if (kc+1 < KC){
            // write prefetched chunk kc+1 into the inactive buffer (no barrier needed before:
            // its previous contents were last read in iter kc-1, sealed by that iter's barrier)
            *(uint4*)(nbuf + aoff0)        = ra0;
            *(uint4*)(nbuf + aoff1)        = ra1;
            *(uint4*)(nbuf + 4096 + aoff0) = rb0;
            *(uint4*)(nbuf + 4096 + aoff1) = rb1;
            if (kc+2 < KC){
                const bf16* qA = pA + (kc+2)*32;
                const bf16* qB = pB + (kc+2)*32;
                ra0 = *(const uint4*)(qA); ra1 = *(const uint4*)(qA+8);
                rb0 = *(const uint4*)(qB); rb1 = *(const uint4*)(qB+8);
            }
        }
        bf16x8 af[4], bfr[4];
        #pragma unroll
        for (int i=0;i<4;i++) af[i]  = *(const bf16x8*)(cbuf + ((wm*4+i)*64 + lane)*8);
        #pragma unroll
        for (int j=0;j<4;j++) bfr[j] = *(const bf16x8*)(cbuf + 4096 + ((wn*4+j)*64 + lane)*8);
        #pragma unroll
        for (int i=0;i<4;i++){
            #pragma unroll
            for (int j=0;j<4;j++)
                acc[i][j] = __builtin_amdgcn_mfma_f32_16x16x32_bf16(af[i], bfr[j], acc[i][j], 0, 0, 0);
        }
        __syncthreads();   // seals: reads of cbuf done; writes to nbuf visible
    }

    // ---- epilogue: bias + relu into LDS C-tile (bf16), then coalesced 16B stores ----
    int lq = lane >> 4, lr = lane & 15;
    #pragma unroll
    for (int i=0;i<4;i++){
        int rl = (wm*4+i)*16 + lq*4;
        #pragma unroll
        for (int j=0;j<4;j++){
            int cl = (wn*4+j)*16 + lr;
            float bv = bias[min(n0+cl, N-1)];
            #pragma unroll
            for (int r=0;r<4;r++){
                float v = acc[i][j][r] + bv;
                if (relu_out) v = fmaxf(v, 0.f);
                Ct[(rl+r)*CS + cl] = (short)__bfloat16_as_ushort(tob(v));
            }
        }
    }
    __syncthreads();
    #pragma unroll
    for (int p=0;p<8;p++){
        int rl = p*16 + (tid>>4);
        int cl = (tid&15)*8;
        int row = m0 + rl, col = n0 + cl;
        if (row < M && col < N){
            union { short s8[8]; uint4 v; } u;
            u.v = *(uint4*)&Ct[rl*CS + cl];
            if (R){
                const bf16* rp = &R[(size_t)row*ldc + col];
                #pragma unroll
                for (int e=0;e<8;e++){
                    float v = b2f((unsigned short)u.s8[e]) + tof(rp[e]);
                    u.s8[e] = (short)__bfloat16_as_ushort(tob(v));
                }
            }
            *(uint4*)&C[(size_t)row*ldc + col] = u.v;
        }
    }
}

// ---------------- old-style MFMA machinery (kept for k_sim_mfma) ----------------
__device__ __forceinline__ void stage_tile(const short* __restrict__ P, int RB, int K, int r0, int k0,
                                           short (*lds)[64][8], int tid){
    #pragma unroll
    for (int s=0;s<2;s++){
        int seg = tid*2+s;
        int row = seg>>2, q = seg&3;
        int gr = r0 + row;
        int gk = k0 + q*8;
        union { short s8[8]; uint4 v; } u;
        if (gr < RB && gk + 8 <= K){
            const uint2* p = (const uint2*)(P + (size_t)gr*K + gk);
            uint2 lo = p[0], hi = p[1];
            u.v.x = lo.x; u.v.y = lo.y; u.v.z = hi.x; u.v.w = hi.y;
        } else {
            #pragma unroll
            for (int j=0;j<8;j++){
                int kk = gk + j;
                u.s8[j] = (gr < RB && kk < K) ? P[(size_t)gr*K + kk] : (short)0;
            }
        }
        *(uint4*)&lds[row>>4][q*16 + (row&15)][0] = u.v;
    }
}

// sim_cp[i][j] = exp( (hr_i . henv_j) * 5 / (na_i*nc_j + 1e-8) )
__global__ __launch_bounds__(256) void k_sim_mfma(const bf16* __restrict__ A, const bf16* __restrict__ Bt,
                      const float* __restrict__ na, const float* __restrict__ nc, float* __restrict__ C){
    __shared__ __align__(16) short Asl[8][64][8];
    __shared__ __align__(16) short Bsl[8][64][8];
    int tid = threadIdx.x;
    int wave = tid >> 6, lane = tid & 63;
    int wm = wave >> 1, wn = wave & 1;
    int m0 = blockIdx.y*128, n0 = blockIdx.x*128;
    f32x4 acc[4][4];
    #pragma unroll
    for (int i=0;i<4;i++){
        #pragma unroll
        for (int j=0;j<4;j++) acc[i][j] = (f32x4){0.f,0.f,0.f,0.f};
    }
    for (int k0=0; k0<SEM; k0+=32){
        stage_tile((const short*)A,  NG, SEM, m0, k0, Asl, tid);
        stage_tile((const short*)Bt, NG, SEM, n0, k0, Bsl, tid);
        __syncthreads();
        bf16x8 af[4], bfr[4];
        #pragma unroll
        for (int i=0;i<4;i++) af[i]  = *(const bf16x8*)&Asl[wm*4+i][lane][0];
        #pragma unroll
        for (int j=0;j<4;j++) bfr[j] = *(const bf16x8*)&Bsl[wn*4+j][lane][0];
        #pragma unroll
        for (int i=0;i<4;i++){
            #pragma unroll
            for (int j=0;j<4;j++)
                acc[i][j] = __builtin_amdgcn_mfma_f32_16x16x32_bf16(af[i], bfr[j], acc[i][j], 0, 0, 0);
        }
        __syncthreads();
    }
    int lq = lane >> 4, lr = lane & 15;
    #pragma unroll
    for (int i=0;i<4;i++){
        int rb = m0 + (wm*4+i)*16 + lq*4;
        #pragma unroll
        for (int j=0;j<4;j++){
            int col = n0 + (wn*4+j)*16 + lr;
            if (col >= NG) continue;
            float ncj = nc[col];
            #pragma unroll
            for (int r=0;r<4;r++){
                int row = rb + r;
                if (row >= NG) continue;
                C[(size_t)row*NG+col] = expf(acc[i][j][r] * 5.0f / (na[row]*ncj + 1e-8f));
            }
        }
    }
}

// ---------------- gate ----------------
__global__ __launch_bounds__(256) void k_gate(const bf16* __restrict__ mid, const float* __restrict__ Wg2,
                      const float* __restrict__ bg2, const float* __restrict__ gumbel, float* __restrict__ gate){
    int gw = blockIdx.x*4 + (threadIdx.x >> 6);
    int lane = threadIdx.x & 63;
    if (gw >= NN) return;
    float s0=0.f, s1=0.f;
    for (int i=lane;i<HID;i+=64){
        float h = tof(mid[(size_t)gw*SHID+i]);
        s0 += h * Wg2[i*2];
        s1 += h * Wg2[i*2+1];
    }
    for (int off=32; off>0; off>>=1){ s0 += __shfl_down(s0, off); s1 += __shfl_down(s1, off); }
    if (lane==0){
        float l0 = s0 + bg2[0] + gumbel[gw*2];
        float l1 = s1 + bg2[1] + gumbel[gw*2+1];
        float m = fmaxf(l0,l1);
        float e0 = expf(l0-m), e1 = expf(l1-m);
        gate[gw] = e1/(e0+e1);
    }
}

// ---------------- segment pooling ----------------
__global__ __launch_bounds__(320) void k_pool(const bf16* __restrict__ h, const float* __restrict__ gate,
                      const int* __restrict__ gstart, float* __restrict__ sumh, float* __restrict__ sumgh){
    int g = blockIdx.x, c = threadIdx.x;
    if (c >= EMB) return;
    int n0 = gstart[g], n1 = gstart[g+1];
    float sh=0.f, sg=0.f;
    for (int n=n0;n<n1;n++){
        float v = tof(h[(size_t)n*SEM+c]);
        float gt = gate[n];
        sh += v; sg += gt*v;
    }
    sumh[g*EMB+c] = sh; sumgh[g*EMB+c] = sg;
}

__global__ __launch_bounds__(256) void k_rnum(const float* __restrict__ gate, const int* __restrict__ gstart,
                      float* __restrict__ rnum, float* __restrict__ cntf){
    int g = blockIdx.x*4 + (threadIdx.x >> 6);
    int lane = threadIdx.x & 63;
    if (g >= NG) return;
    int n0 = gstart[g], n1 = gstart[g+1];
    float s=0.f;
    for (int n=n0+lane;n<n1;n+=64) s += gate[n];
    for (int off=32; off>0; off>>=1) s += __shfl_down(s, off);
    if (lane==0){ rnum[g] = s; cntf[g] = (float)(n1-n0); }
}

__global__ __launch_bounds__(256) void k_mean(const float* __restrict__ sumh, const float* __restrict__ sumgh,
                      const float* __restrict__ cntf, float* __restrict__ hr, float* __restrict__ henv,
                      float* __restrict__ hout, bf16* __restrict__ hrb, bf16* __restrict__ henvb){
    int idx = blockIdx.x*256 + threadIdx.x;
    if (idx >= NG*SEM) return;
    int g = idx / SEM, c = idx - g*SEM;
    if (c < EMB){
        int o = g*EMB + c;
        float inv = 1.f / fmaxf(cntf[g], 1.f);
        float sh = sumh[o], sg = sumgh[o];
        float r = sg*inv, e = (sh-sg)*inv;
        hr[o] = r; henv[o] = e; hout[o] = sh*inv;
        hrb[idx] = tob(r); henvb[idx] = tob(e);
    } else {
        hrb[idx] = tob(0.f); henvb[idx] = tob(0.f);   // zero pads (henvb is a B-operand!)
    }
}

__global__ __launch_bounds__(256) void k_pbuild(const float* __restrict__ hr, const float* __restrict__ henv,
                      const int* __restrict__ perm, bf16* __restrict__ P){
    int idx = blockIdx.x*256 + threadIdx.x;
    if (idx >= NG*SEM) return;
    int g = idx / SEM, c = idx - g*SEM;
    if (c < EMB){
        float v = hr[g*EMB+c];
        P[idx] = tob(v);
        P[(size_t)(NG+g)*SEM + c] = tob(v + henv[(size_t)perm[g]*EMB + c]);
    } else {
        P[idx] = tob(0.f);
        P[(size_t)(NG+g)*SEM + c] = tob(0.f);
    }
}

__global__ __launch_bounds__(256) void k_norm(const float* __restrict__ hr, const float* __restrict__ henv,
                      const float* __restrict__ hout, float* __restrict__ na, float* __restrict__ nc,
                      float* __restrict__ pos){
    int g = blockIdx.x*4 + (threadIdx.x >> 6);
    int lane = threadIdx.x & 63;
    if (g >= NG) return;
    float srr=0.f, soo=0.f, see=0.f, sro=0.f;
    for (int c=lane;c<EMB;c+=64){
        float r=hr[g*EMB+c], o=hout[g*EMB+c], e=henv[g*EMB+c];
        srr += r*r; soo += o*o; see += e*e; sro += r*o;
    }
    for (int off=32; off>0; off>>=1){
        srr += __shfl_down(srr,off); soo += __shfl_down(soo,off);
        see += __shfl_down(see,off); sro += __shfl_down(sro,off);
    }
    if (lane==0){
        float a = sqrtf(srr), b = sqrtf(soo), c2 = sqrtf(see);
        na[g] = a; nc[g] = c2;
        pos[g] = expf(sro/(a*b + 1e-8f) * 5.0f);
    }
}

__global__ __launch_bounds__(256) void k_rowsum(const float* __restrict__ simcp, float* __restrict__ S){
    __shared__ float red[256];
    int g = blockIdx.x, t = threadIdx.x;
    float s = 0.f;
    for (int j=t;j<NG;j+=256) s += simcp[(size_t)g*NG+j];
    red[t]=s; __syncthreads();
    for (int off=128; off>0; off>>=1){ if (t<off) red[t]+=red[t+off]; __syncthreads(); }
    if (t==0) S[g]=red[0];
}

__global__ __launch_bounds__(256) void k_pred(const bf16* __restrict__ hidP, const float* __restrict__ Wp2,
                      const float* __restrict__ bp2, float* __restrict__ out){
    int r = blockIdx.x*4 + (threadIdx.x >> 6);
    int lane = threadIdx.x & 63;
    if (r >= 2*NG) return;
    float acc[NTASK];
    #pragma unroll
    for (int t=0;t<NTASK;t++) acc[t] = 0.f;
    for (int i=lane;i<HID;i+=64){
        float h = tof(hidP[(size_t)r*SHID+i]);
        const float4* wp = (const float4*)&Wp2[i*NTASK];
        float4 wa = wp[0], wb = wp[1], wc = wp[2];
        acc[0]+=h*wa.x; acc[1]+=h*wa.y; acc[2]+=h*wa.z; acc[3]+=h*wa.w;
        acc[4]+=h*wb.x; acc[5]+=h*wb.y; acc[6]+=h*wb.z; acc[7]+=h*wb.w;
        acc[8]+=h*wc.x; acc[9]+=h*wc.y; acc[10]+=h*wc.z; acc[11]+=h*wc.w;
    }
    #pragma unroll
    for (int t=0;t<NTASK;t++){
        for (int off=32; off>0; off>>=1) acc[t] += __shfl_down(acc[t], off);
    }
    if (lane==0){
        float* dst = (r < NG) ? &out[NG*NTASK + r*NTASK] : &out[(r-NG)*NTASK];
        #pragma unroll
        for (int t=0;t<NTASK;t++) dst[t] = acc[t] + bp2[t];
    }
}

__global__ __launch_bounds__(256) void k_loss(const float* __restrict__ cntf, const float* __restrict__ rnum,
                      const float* __restrict__ pos, const float* __restrict__ S, float* __restrict__ out){
    __shared__ float ra[256], rb[256];
    int t = threadIdx.x;
    float a=0.f, b=0.f;
    for (int g=t; g<NG; g+=256){
        float r = rnum[g] + 1e-8f;
        float e = (cntf[g] - rnum[g]) + 1e-8f;
        a += fabsf(r/(r+e) - 0.4f);
        float p = pos[g];
        b += -logf(p/(S[g]+p));
    }
    ra[t]=a; rb[t]=b; __syncthreads();
    for (int off=128; off>0; off>>=1){ if (t<off){ ra[t]+=ra[t+off]; rb[t]+=rb[t+off]; } __syncthreads(); }
    if (t==0){
        out[2*NG*NTASK]   = ra[0]/NG;
        out[2*NG*NTASK+1] = rb[0]/NG;
    }
}

extern "C" void kernel_launch(void* const* d_in, const int* in_sizes, int n_in,
                              void* d_out, int out_size, void* d_ws, size_t ws_size,
                              hipStream_t stream) {
    const float* x      = (const float*)d_in[0];
    const float* eattr  = (const float*)d_in[1];
    const int*   eidx   = (const int*)d_in[2];
    const int*   batch  = (const int*)d_in[3];
    const float* gumbel = (const float*)d_in[4];
    const int*   perm   = (const int*)d_in[5];
    const float* W_enc  = (const float*)d_in[6];
    const float* b_enc  = (const float*)d_in[7];
    const float* We_g   = (const float*)d_in[8];
    const float* be_g   = (const float*)d_in[9];
    const float* W1_g   = (const float*)d_in[10];
    const float* b1_g   = (const float*)d_in[11];
    const float* W2_g   = (const float*)d_in[12];
    const float* b2_g   = (const float*)d_in[13];
    const float* We_r   = (const float*)d_in[14];
    const float* be_r   = (const float*)d_in[15];
    const float* W1_r   = (const float*)d_in[16];
    const float* b1_r   = (const float*)d_in[17];
    const float* W2_r   = (const float*)d_in[18];
    const float* b2_r   = (const float*)d_in[19];
    const float* Wg1    = (const float*)d_in[20];
    const float* bg1    = (const float*)d_in[21];
    const float* Wg2    = (const float*)d_in[22];
    const float* bg2    = (const float*)d_in[23];
    const float* Wp1    = (const float*)d_in[24];
    const float* bp1    = (const float*)d_in[25];
    const float* Wp2    = (const float*)d_in[26];
    const float* bp2    = (const float*)d_in[27];
    float* out = (float*)d_out;

    const int* srcArr = eidx;
    const int* dstArr = eidx + NE;

    // ---- workspace (bump allocator, 256B aligned) ----
    char* w = (char*)d_ws;
    size_t off = 0;
    auto alloc = [&](size_t bytes)->char*{ char* p = w + off; off += (bytes + 255) & ~(size_t)255; return p; };
    bf16* xfeat = (bf16*)alloc((size_t)NN*SEM*2);
    bf16* cur   = (bf16*)alloc((size_t)NN*SEM*2);
    bf16* apx   = (bf16*)alloc((size_t)NN*SEM*2);
    bf16* apx2  = (bf16*)alloc((size_t)NN*SEM*2);     // encoder-l0 agg output (fused dual agg)
    char* midc  = alloc((size_t)NN*SHID*2);           // 36.5 MB; reused after stacks
    bf16* mid   = (bf16*)midc;
    float* simcp = (float*)midc;                      // NG*NG*4 = 9 MB
    bf16* Pbuf   = (bf16*)(midc + 12*1024*1024);
    bf16* hidP   = (bf16*)(midc + 20*1024*1024);
    bf16* wt1g  = (bf16*)alloc((size_t)5*HID*SEM*2);
    bf16* wt2g  = (bf16*)alloc((size_t)5*EMB*SHID*2);
    bf16* wt1r  = (bf16*)alloc((size_t)2*HID*SEM*2);
    bf16* wt2r  = (bf16*)alloc((size_t)2*EMB*SHID*2);
    bf16* wtg1  = (bf16*)alloc((size_t)HID*SEM*2);
    bf16* wtp1  = (bf16*)alloc((size_t)HID*SEM*2);
    float4* epack = (float4*)alloc((size_t)NE*16);
    float* gate  = (float*)alloc((size_t)NN*4);
    float* sumh  = (float*)alloc((size_t)NG*EMB*4);
    float* sumgh = (float*)alloc((size_t)NG*EMB*4);
    float* hr    = (float*)alloc((size_t)NG*EMB*4);
    float* henv  = (float*)alloc((size_t)NG*EMB*4);
    float* hout  = (float*)alloc((size_t)NG*EMB*4);
    bf16* hrb    = (bf16*)alloc((size_t)NG*SEM*2);
    bf16* henvb  = (bf16*)alloc((size_t)NG*SEM*2);
    float* rnum  = (float*)alloc(NG*4);
    float* cntf  = (float*)alloc(NG*4);
    float* na    = (float*)alloc(NG*4);
    float* ncv   = (float*)alloc(NG*4);
    float* pos   = (float*)alloc(NG*4);
    float* Ssum  = (float*)alloc(NG*4);
    int* deg     = (int*)alloc((size_t)NN*4);
    int* indptr  = (int*)alloc((size_t)(NN+1)*4);
    int* cursor  = (int*)alloc((size_t)NN*4);
    int* eid     = (int*)alloc((size_t)NE*4);
    int* gstart  = (int*)alloc((size_t)(NG+1)*4);
    int* bsum    = (int*)alloc((size_t)NBLK_SCAN*4);
    int* boff    = (int*)alloc((size_t)NBLK_SCAN*4);

    const int NB_NE  = (NE+255)/256;
    const int NB_NC  = (NN*EMB+255)/256;
    const int NB_AG  = (NN*CG+255)/256;
    const int NB_GP  = (NG*SEM+255)/256;

    // ---- CSR build + edge pack + graph ranges ----
    k_zero_i <<<(NN+255)/256, 256, 0, stream>>>(deg, NN);
    k_hist   <<<NB_NE, 256, 0, stream>>>(dstArr, deg);
    k_scanA  <<<NBLK_SCAN, 256, 0, stream>>>(deg, bsum);
    k_scanB  <<<1, 128, 0, stream>>>(bsum, boff);
    k_scanC  <<<NBLK_SCAN, 256, 0, stream>>>(deg, boff, indptr, cursor);
    k_scatter<<<NB_NE, 256, 0, stream>>>(dstArr, cursor, eid);
    k_eprep  <<<NB_NE, 256, 0, stream>>>(eid, srcArr, eattr, epack);
    k_gstart <<<(NG+256)/256, 256, 0, stream>>>(batch, gstart);

    // ---- weight prep (transpose + bf16 + K-pad zeros) ----
    {
        dim3 g1t((HID+31)/32, SEM/32, 5);
        dim3 g2t((EMB+31)/32, SHID/32, 5);
        k_wprep<<<g1t, 256, 0, stream>>>(W1_g, wt1g, EMB, SEM, HID);
        k_wprep<<<g2t, 256, 0, stream>>>(W2_g, wt2g, HID, SHID, EMB);
        dim3 g1t2((HID+31)/32, SEM/32, 2);
        dim3 g2t2((EMB+31)/32, SHID/32, 2);
        k_wprep<<<g1t2, 256, 0, stream>>>(W1_r, wt1r, EMB, SEM, HID);
        k_wprep<<<g2t2, 256, 0, stream>>>(W2_r, wt2r, HID, SHID, EMB);
        dim3 g1t1((HID+31)/32, SEM/32, 1);
        k_wprep<<<g1t1, 256, 0, stream>>>(Wg1, wtg1, EMB, SEM, HID);
        k_wprep<<<g1t1, 256, 0, stream>>>(Wp1, wtp1, EMB, SEM, HID);
    }

    dim3 gm1((HID+127)/128, (NN+127)/128);  // (5, 235) TN=128
    dim3 gm2((EMB+127)/128, (NN+127)/128);  // (3, 235)

    // ---- node encoder (once) ----
    k_encoder<<<NB_NC, 256, 0, stream>>>(x, W_enc, b_enc, xfeat);

    // ---- fused layer-0 agg for BOTH stacks (shared gathers) ----
    k_agg4d<<<NB_AG, 256, 0, stream>>>(xfeat, We_r, be_r, We_g, be_g, epack, indptr, apx, apx2);

    // ---- rationale GIN stack (2 layers) ----
    for (int l=0; l<2; l++){
        const bf16* in = (l==0) ? xfeat : cur;
        if (l > 0)
            k_agg4 <<<NB_AG, 256, 0, stream>>>(in, We_r + l*3*EMB, be_r + l*EMB, epack, indptr, apx);
        k_gemm2<<<gm1, 256, 0, stream>>>(apx, wt1r + (size_t)l*HID*SEM, b1_r + l*HID, nullptr, mid,
                                         NN, HID, SEM, SHID, 1);
        k_gemm2<<<gm2, 256, 0, stream>>>(mid, wt2r + (size_t)l*EMB*SHID, b2_r + l*EMB, in, cur,
                                         NN, EMB, SHID, SEM, (l<1)?1:0);
    }
    // ---- gate from x_rat ----
    k_gemm2<<<gm1, 256, 0, stream>>>(cur, wtg1, bg1, nullptr, mid, NN, HID, SEM, SHID, 1);
    k_gate<<<NN/4, 256, 0, stream>>>(mid, Wg2, bg2, gumbel, gate);

    // ---- encoder GIN stack (5 layers); l0 uses pre-computed apx2 ----
    for (int l=0; l<5; l++){
        const bf16* in = (l==0) ? xfeat : cur;
        const bf16* ap = (l==0) ? apx2 : apx;
        if (l > 0)
            k_agg4 <<<NB_AG, 256, 0, stream>>>(in, We_g + l*3*EMB, be_g + l*EMB, epack, indptr, apx);
        k_gemm2<<<gm1, 256, 0, stream>>>(ap, wt1g + (size_t)l*HID*SEM, b1_g + l*HID, nullptr, mid,
                                         NN, HID, SEM, SHID, 1);
        k_gemm2<<<gm2, 256, 0, stream>>>(mid, wt2g + (size_t)l*EMB*SHID, b2_g + l*EMB, in, cur,
                                         NN, EMB, SHID, SEM, (l<4)?1:0);
    }
    // cur now holds h_node (bf16, stride SEM)

    // ---- pooling (segment scan) ----
    k_pool  <<<NG, 320, 0, stream>>>(cur, gate, gstart, sumh, sumgh);
    k_rnum  <<<(NG+3)/4, 256, 0, stream>>>(gate, gstart, rnum, cntf);
    k_mean  <<<NB_GP, 256, 0, stream>>>(sumh, sumgh, cntf, hr, henv, hout, hrb, henvb);
    k_pbuild<<<NB_GP, 256, 0, stream>>>(hr, henv, perm, Pbuf);
    k_norm  <<<(NG+3)/4, 256, 0, stream>>>(hr, henv, hout, na, ncv, pos);
    // ---- contrastive sim (MFMA) ----
    dim3 gsim((NG+127)/128, (NG+127)/128);
    k_sim_mfma<<<gsim, 256, 0, stream>>>(hrb, henvb, na, ncv, simcp);
    k_rowsum<<<NG, 256, 0, stream>>>(simcp, Ssum);
    // ---- head (MFMA) ----
    dim3 gph((HID+127)/128, (2*NG+127)/128);
    k_gemm2<<<gph, 256, 0, stream>>>(Pbuf, wtp1, bp1, nullptr, hidP, 2*NG, HID, SEM, SHID, 1);
    k_pred  <<<(2*NG+3)/4, 256, 0, stream>>>(hidP, Wp2, bp2, out);
    k_loss  <<<1, 256, 0, stream>>>(cntf, rnum, pos, Ssum, out);
}

// Round 15
// 986.054 us; speedup vs baseline: 1.7741x; 1.0115x over previous
//
#include <hip/hip_runtime.h>
#include <hip/hip_bf16.h>

typedef __hip_bfloat16 bf16;
typedef __attribute__((ext_vector_type(8))) short bf16x8;
typedef __attribute__((ext_vector_type(4))) float f32x4;

#define NN 30000      // nodes
#define NE 240000     // edges
#define NG 1500       // graphs
#define EMB 300
#define HID 600
#define NTASK 12
#define SEM 320       // padded stride for EMB-dim tensors
#define SHID 608      // padded stride for HID-dim tensors
#define CG 75         // 4-channel groups — 75 thr/node: best TLP (round-9 lesson)
#define NBLK_SCAN 118 // (NN+255)/256

__device__ __forceinline__ float tof(bf16 v){ return __bfloat162float(v); }
__device__ __forceinline__ bf16  tob(float v){ return __float2bfloat16(v); }
__device__ __forceinline__ float b2f(unsigned short u){ return __uint_as_float(((unsigned)u)<<16); }

// ---------------- utility ----------------
__global__ __launch_bounds__(256) void k_zero_i(int* __restrict__ p, int n){
    int i = blockIdx.x*256 + threadIdx.x;
    if (i < n) p[i] = 0;
}

// ---------------- CSR build (by dst) ----------------
__global__ __launch_bounds__(256) void k_hist(const int* __restrict__ dst, int* __restrict__ deg){
    int e = blockIdx.x*256 + threadIdx.x;
    if (e < NE) atomicAdd(&deg[dst[e]], 1);
}

__global__ __launch_bounds__(256) void k_scanA(const int* __restrict__ deg, int* __restrict__ bsum){
    __shared__ int red[256];
    int b = blockIdx.x, t = threadIdx.x;
    int i = b*256 + t;
    red[t] = (i < NN) ? deg[i] : 0;
    __syncthreads();
    for (int off=128; off>0; off>>=1){ if (t<off) red[t]+=red[t+off]; __syncthreads(); }
    if (t==0) bsum[b] = red[0];
}

__global__ __launch_bounds__(128) void k_scanB(const int* __restrict__ bsum, int* __restrict__ boff){
    __shared__ int s[128];
    int t = threadIdx.x;
    int v = (t < NBLK_SCAN) ? bsum[t] : 0;
    s[t] = v;
    __syncthreads();
    for (int off=1; off<128; off<<=1){
        int add = (t>=off) ? s[t-off] : 0;
        __syncthreads();
        s[t] += add;
        __syncthreads();
    }
    if (t < NBLK_SCAN) boff[t] = s[t] - v;   // exclusive
}

__global__ __launch_bounds__(256) void k_scanC(const int* __restrict__ deg, const int* __restrict__ boff,
                                               int* __restrict__ indptr, int* __restrict__ cursor){
    __shared__ int s[256];
    int b = blockIdx.x, t = threadIdx.x;
    int i = b*256 + t;
    int v = (i < NN) ? deg[i] : 0;
    s[t] = v;
    __syncthreads();
    for (int off=1; off<256; off<<=1){
        int add = (t>=off) ? s[t-off] : 0;
        __syncthreads();
        s[t] += add;
        __syncthreads();
    }
    int excl = s[t] - v + boff[b];
    if (i < NN){ indptr[i] = excl; cursor[i] = excl; }
    if (i == 0) indptr[NN] = NE;
}

__global__ __launch_bounds__(256) void k_scatter(const int* __restrict__ dst, int* __restrict__ cursor,
                                                 int* __restrict__ eid){
    int e = blockIdx.x*256 + threadIdx.x;
    if (e < NE){ int p = atomicAdd(&cursor[dst[e]], 1); eid[p] = e; }
}

__global__ __launch_bounds__(256) void k_eprep(const int* __restrict__ eid, const int* __restrict__ src,
                                               const float* __restrict__ eattr, float4* __restrict__ epack){
    int k = blockIdx.x*256 + threadIdx.x;
    if (k >= NE) return;
    int e = eid[k];
    float4 p;
    p.x = __int_as_float(src[e]);
    p.y = eattr[e*3]; p.z = eattr[e*3+1]; p.w = eattr[e*3+2];
    epack[k] = p;
}

__global__ __launch_bounds__(256) void k_gstart(const int* __restrict__ batch, int* __restrict__ gstart){
    int g = blockIdx.x*256 + threadIdx.x;
    if (g > NG) return;
    if (g == NG){ gstart[NG] = NN; return; }
    int lo=0, hi=NN;
    while (lo<hi){ int mid=(lo+hi)>>1; if (batch[mid] < g) lo=mid+1; else hi=mid; }
    gstart[g] = lo;
}

// ---------------- weight prep: Wt[n][kp] bf16 = W[k][n] fp32, zero-padded k>=K ----------------
__global__ __launch_bounds__(256) void k_wprep(const float* __restrict__ W, bf16* __restrict__ Wt,
                                               int K, int Kp, int N){
    __shared__ float t[32][33];
    const float* Wz = W + (size_t)blockIdx.z*K*N;
    bf16* Wtz = Wt + (size_t)blockIdx.z*N*Kp;
    int n0 = blockIdx.x*32, k0 = blockIdx.y*32;
    int tx = threadIdx.x & 31, ty = threadIdx.x >> 5;
    #pragma unroll
    for (int i=0;i<4;i++){
        int k = k0 + ty + i*8, n = n0 + tx;
        t[ty+i*8][tx] = (k<K && n<N) ? Wz[(size_t)k*N+n] : 0.f;
    }
    __syncthreads();
    #pragma unroll
    for (int i=0;i<4;i++){
        int n = n0 + ty + i*8, k = k0 + tx;
        if (n<N && k<Kp) Wtz[(size_t)n*Kp+k] = tob(t[tx][ty+i*8]);
    }
}

// ---------------- node encoder ----------------
__global__ __launch_bounds__(256) void k_encoder(const float* __restrict__ x, const float* __restrict__ W,
                                                 const float* __restrict__ b, bf16* __restrict__ xfeat){
    int idx = blockIdx.x*256 + threadIdx.x;
    if (idx >= NN*EMB) return;
    int n = idx / EMB, c = idx - n*EMB;
    float acc = b[c];
    #pragma unroll
    for (int k=0;k<9;k++) acc += x[n*9+k] * W[k*EMB+c];
    xfeat[(size_t)n*SEM + c] = tob(acc);
}

// ---------------- agg body (device): thread=(node, 4-ch group), 2-deep pipeline ----------------
__device__ __forceinline__ void agg4_body(const bf16* __restrict__ cur, const float* __restrict__ We,
                      const float* __restrict__ be, const float4* __restrict__ epack,
                      const int* __restrict__ indptr, bf16* __restrict__ apx, int idx){
    int n = idx / CG, cg = idx - n*CG;
    int c0 = cg*4;
    float w0[4], w1[4], w2[4], bbv[4], acc[4];
    #pragma unroll
    for (int j=0;j<4;j++){
        w0[j] = We[c0+j]; w1[j] = We[EMB+c0+j]; w2[j] = We[2*EMB+c0+j]; bbv[j] = be[c0+j];
    }
    ushort4 hs = *(const ushort4*)&cur[(size_t)n*SEM + c0];
    acc[0]=b2f(hs.x); acc[1]=b2f(hs.y); acc[2]=b2f(hs.z); acc[3]=b2f(hs.w);
    int k  = indptr[n], k1 = indptr[n+1];

    auto accum4 = [&](float4 e0, float4 e1, float4 e2, float4 e3,
                      ushort4 ha, ushort4 hb, ushort4 hc, ushort4 hd){
        float fa[4] = {b2f(ha.x), b2f(ha.y), b2f(ha.z), b2f(ha.w)};
        float fb[4] = {b2f(hb.x), b2f(hb.y), b2f(hb.z), b2f(hb.w)};
        float fc[4] = {b2f(hc.x), b2f(hc.y), b2f(hc.z), b2f(hc.w)};
        float fd[4] = {b2f(hd.x), b2f(hd.y), b2f(hd.z), b2f(hd.w)};
        #pragma unroll
        for (int j=0;j<4;j++){
            float va = fa[j] + e0.y*w0[j] + e0.z*w1[j] + e0.w*w2[j] + bbv[j];
            float vb = fb[j] + e1.y*w0[j] + e1.z*w1[j] + e1.w*w2[j] + bbv[j];
            float vc = fc[j] + e2.y*w0[j] + e2.z*w1[j] + e2.w*w2[j] + bbv[j];
            float vd = fd[j] + e3.y*w0[j] + e3.z*w1[j] + e3.w*w2[j] + bbv[j];
            acc[j] += fmaxf(va, 0.f) + fmaxf(vb, 0.f) + fmaxf(vc, 0.f) + fmaxf(vd, 0.f);
        }
    };

    if (k + 4 <= k1){
        float4 e0 = epack[k], e1 = epack[k+1], e2 = epack[k+2], e3 = epack[k+3];
        ushort4 h0 = *(const ushort4*)&cur[(size_t)__float_as_int(e0.x)*SEM + c0];
        ushort4 h1 = *(const ushort4*)&cur[(size_t)__float_as_int(e1.x)*SEM + c0];
        ushort4 h2 = *(const ushort4*)&cur[(size_t)__float_as_int(e2.x)*SEM + c0];
        ushort4 h3 = *(const ushort4*)&cur[(size_t)__float_as_int(e3.x)*SEM + c0];
        while (k + 8 <= k1){
            float4 f0 = epack[k+4], f1 = epack[k+5], f2 = epack[k+6], f3 = epack[k+7];
            ushort4 g0 = *(const ushort4*)&cur[(size_t)__float_as_int(f0.x)*SEM + c0];
            ushort4 g1 = *(const ushort4*)&cur[(size_t)__float_as_int(f1.x)*SEM + c0];
            ushort4 g2 = *(const ushort4*)&cur[(size_t)__float_as_int(f2.x)*SEM + c0];
            ushort4 g3 = *(const ushort4*)&cur[(size_t)__float_as_int(f3.x)*SEM + c0];
            accum4(e0,e1,e2,e3, h0,h1,h2,h3);
            e0=f0; e1=f1; e2=f2; e3=f3;
            h0=g0; h1=g1; h2=g2; h3=g3;
            k += 4;
        }
        accum4(e0,e1,e2,e3, h0,h1,h2,h3);
        k += 4;
    }
    for (; k < k1; k++){
        float4 e0 = epack[k];
        int s0 = __float_as_int(e0.x);
        ushort4 ha = *(const ushort4*)&cur[(size_t)s0*SEM + c0];
        float fa[4] = {b2f(ha.x), b2f(ha.y), b2f(ha.z), b2f(ha.w)};
        #pragma unroll
        for (int j=0;j<4;j++){
            float va = fa[j] + e0.y*w0[j] + e0.z*w1[j] + e0.w*w2[j] + bbv[j];
            acc[j] += fmaxf(va, 0.f);
        }
    }
    ushort4 o;
    o.x = __bfloat16_as_ushort(tob(acc[0]));
    o.y = __bfloat16_as_ushort(tob(acc[1]));
    o.z = __bfloat16_as_ushort(tob(acc[2]));
    o.w = __bfloat16_as_ushort(tob(acc[3]));
    *(ushort4*)&apx[(size_t)n*SEM + c0] = o;
}

__global__ __launch_bounds__(256) void k_agg4(const bf16* __restrict__ cur, const float* __restrict__ We,
                      const float* __restrict__ be, const float4* __restrict__ epack,
                      const int* __restrict__ indptr, bf16* __restrict__ apx){
    int idx = blockIdx.x*256 + threadIdx.x;
    if (idx >= NN*CG) return;
    agg4_body(cur, We, be, epack, indptr, apx, idx);
}

// z-paired agg: blockIdx.z selects arg set (independent chains in one dispatch)
__global__ __launch_bounds__(256) void k_agg4z(const bf16* __restrict__ cur0, const bf16* __restrict__ cur1,
                      const float* __restrict__ We0, const float* __restrict__ We1,
                      const float* __restrict__ be0, const float* __restrict__ be1,
                      const float4* __restrict__ epack, const int* __restrict__ indptr,
                      bf16* __restrict__ apx0, bf16* __restrict__ apx1){
    int idx = blockIdx.x*256 + threadIdx.x;
    if (idx >= NN*CG) return;
    if (blockIdx.z == 0) agg4_body(cur0, We0, be0, epack, indptr, apx0, idx);
    else                 agg4_body(cur1, We1, be1, epack, indptr, apx1, idx);
}

// ---------------- dual agg: one gather pass feeds BOTH weight sets (layer-0 fusion) ----------------
__global__ __launch_bounds__(256) void k_agg4d(const bf16* __restrict__ cur,
                      const float* __restrict__ WeA, const float* __restrict__ beA,
                      const float* __restrict__ WeB, const float* __restrict__ beB,
                      const float4* __restrict__ epack, const int* __restrict__ indptr,
                      bf16* __restrict__ apxA, bf16* __restrict__ apxB){
    int idx = blockIdx.x*256 + threadIdx.x;
    if (idx >= NN*CG) return;
    int n = idx / CG, cg = idx - n*CG;
    int c0 = cg*4;
    float a0[4], a1[4], a2[4], ab[4], accA[4];
    float b0[4], b1[4], b2[4], bb[4], accB[4];
    #pragma unroll
    for (int j=0;j<4;j++){
        a0[j]=WeA[c0+j]; a1[j]=WeA[EMB+c0+j]; a2[j]=WeA[2*EMB+c0+j]; ab[j]=beA[c0+j];
        b0[j]=WeB[c0+j]; b1[j]=WeB[EMB+c0+j]; b2[j]=WeB[2*EMB+c0+j]; bb[j]=beB[c0+j];
    }
    ushort4 hs = *(const ushort4*)&cur[(size_t)n*SEM + c0];
    float fs[4] = {b2f(hs.x), b2f(hs.y), b2f(hs.z), b2f(hs.w)};
    #pragma unroll
    for (int j=0;j<4;j++){ accA[j]=fs[j]; accB[j]=fs[j]; }
    int k = indptr[n], k1 = indptr[n+1];
    for (; k+2 <= k1; k += 2){
        float4 e0 = epack[k], e1 = epack[k+1];
        int s0 = __float_as_int(e0.x), s1 = __float_as_int(e1.x);
        ushort4 ha = *(const ushort4*)&cur[(size_t)s0*SEM + c0];
        ushort4 hb = *(const ushort4*)&cur[(size_t)s1*SEM + c0];
        float fa[4] = {b2f(ha.x), b2f(ha.y), b2f(ha.z), b2f(ha.w)};
        float fb[4] = {b2f(hb.x), b2f(hb.y), b2f(hb.z), b2f(hb.w)};
        #pragma unroll
        for (int j=0;j<4;j++){
            accA[j] += fmaxf(fa[j] + e0.y*a0[j] + e0.z*a1[j] + e0.w*a2[j] + ab[j], 0.f)
                     + fmaxf(fb[j] + e1.y*a0[j] + e1.z*a1[j] + e1.w*a2[j] + ab[j], 0.f);
            accB[j] += fmaxf(fa[j] + e0.y*b0[j] + e0.z*b1[j] + e0.w*b2[j] + bb[j], 0.f)
                     + fmaxf(fb[j] + e1.y*b0[j] + e1.z*b1[j] + e1.w*b2[j] + bb[j], 0.f);
        }
    }
    if (k < k1){
        float4 e0 = epack[k];
        int s0 = __float_as_int(e0.x);
        ushort4 ha = *(const ushort4*)&cur[(size_t)s0*SEM + c0];
        float fa[4] = {b2f(ha.x), b2f(ha.y), b2f(ha.z), b2f(ha.w)};
        #pragma unroll
        for (int j=0;j<4;j++){
            accA[j] += fmaxf(fa[j] + e0.y*a0[j] + e0.z*a1[j] + e0.w*a2[j] + ab[j], 0.f);
            accB[j] += fmaxf(fa[j] + e0.y*b0[j] + e0.z*b1[j] + e0.w*b2[j] + bb[j], 0.f);
        }
    }
    ushort4 oA, oB;
    oA.x=__bfloat16_as_ushort(tob(accA[0])); oA.y=__bfloat16_as_ushort(tob(accA[1]));
    oA.z=__bfloat16_as_ushort(tob(accA[2])); oA.w=__bfloat16_as_ushort(tob(accA[3]));
    oB.x=__bfloat16_as_ushort(tob(accB[0])); oB.y=__bfloat16_as_ushort(tob(accB[1]));
    oB.z=__bfloat16_as_ushort(tob(accB[2])); oB.w=__bfloat16_as_ushort(tob(accB[3]));
    *(ushort4*)&apxA[(size_t)n*SEM + c0] = oA;
    *(ushort4*)&apxB[(size_t)n*SEM + c0] = oB;
}

// ---------------- MFMA bf16 GEMM body (device): dbuf K-loop, coalesced epilogue ----------------
__device__ __forceinline__ void gemm_body(const bf16* __restrict__ A, const bf16* __restrict__ Bt,
        const float* __restrict__ bias, const bf16* __restrict__ R, bf16* __restrict__ C,
        int M, int N, int Kp, int ldc, int relu_out, short* lds){
    short* Ct = lds;
    const int CS = 136;
    int tid = threadIdx.x;
    int wave = tid >> 6, lane = tid & 63;
    int wm = wave >> 1, wn = wave & 1;
    int m0 = blockIdx.y*128, n0 = blockIdx.x*128;

    int srow = tid >> 1;
    int sq   = (tid & 1) * 2;
    int grA = min(m0 + srow, M-1);
    int grB = min(n0 + srow, N-1);
    const bf16* pA = A  + (size_t)grA*Kp + sq*8;
    const bf16* pB = Bt + (size_t)grB*Kp + sq*8;
    int aoff0 = ((srow>>4)*64 +  sq   *16 + (srow&15))*8;
    int aoff1 = ((srow>>4)*64 + (sq+1)*16 + (srow&15))*8;

    f32x4 acc[4][4];
    #pragma unroll
    for (int i=0;i<4;i++){
        #pragma unroll
        for (int j=0;j<4;j++) acc[i][j] = (f32x4){0.f,0.f,0.f,0.f};
    }

    int KC = Kp >> 5;
    uint4 ra0 = *(const uint4*)(pA);
    uint4 ra1 = *(const uint4*)(pA + 8);
    uint4 rb0 = *(const uint4*)(pB);
    uint4 rb1 = *(const uint4*)(pB + 8);
    *(uint4*)(lds + aoff0)        = ra0;
    *(uint4*)(lds + aoff1)        = ra1;
    *(uint4*)(lds + 4096 + aoff0) = rb0;
    *(uint4*)(lds + 4096 + aoff1) = rb1;
    __syncthreads();
    if (KC > 1){
        ra0 = *(const uint4*)(pA + 32); ra1 = *(const uint4*)(pA + 40);
        rb0 = *(const uint4*)(pB + 32); rb1 = *(const uint4*)(pB + 40);
    }

    for (int kc=0; kc<KC; ++kc){
        short* cbuf = lds + (kc & 1)*8192;
        short* nbuf = lds + ((kc+1) & 1)*8192;
        if (kc+1 < KC){
            *(uint4*)(nbuf + aoff0)        = ra0;
            *(uint4*)(nbuf + aoff1)        = ra1;
            *(uint4*)(nbuf + 4096 + aoff0) = rb0;
            *(uint4*)(nbuf + 4096 + aoff1) = rb1;
            if (kc+2 < KC){
                const bf16* qA = pA + (kc+2)*32;
                const bf16* qB = pB + (kc+2)*32;
                ra0 = *(const uint4*)(qA); ra1 = *(const uint4*)(qA+8);
                rb0 = *(const uint4*)(qB); rb1 = *(const uint4*)(qB+8);
            }
        }
        bf16x8 af[4], bfr[4];
        #pragma unroll
        for (int i=0;i<4;i++) af[i]  = *(const bf16x8*)(cbuf + ((wm*4+i)*64 + lane)*8);
        #pragma unroll
        for (int j=0;j<4;j++) bfr[j] = *(const bf16x8*)(cbuf + 4096 + ((wn*4+j)*64 + lane)*8);
        #pragma unroll
        for (int i=0;i<4;i++){
            #pragma unroll
            for (int j=0;j<4;j++)
                acc[i][j] = __builtin_amdgcn_mfma_f32_16x16x32_bf16(af[i], bfr[j], acc[i][j], 0, 0, 0);
        }
        __syncthreads();
    }

    int lq = lane >> 4, lr = lane & 15;
    #pragma unroll
    for (int i=0;i<4;i++){
        int rl = (wm*4+i)*16 + lq*4;
        #pragma unroll
        for (int j=0;j<4;j++){
            int cl = (wn*4+j)*16 + lr;
            float bv = bias[min(n0+cl, N-1)];
            #pragma unroll
            for (int r=0;r<4;r++){
                float v = acc[i][j][r] + bv;
                if (relu_out) v = fmaxf(v, 0.f);
                Ct[(rl+r)*CS + cl] = (short)__bfloat16_as_ushort(tob(v));
            }
        }
    }
    __syncthreads();
    #pragma unroll
    for (int p=0;p<8;p++){
        int rl = p*16 + (tid>>4);
        int cl = (tid&15)*8;
        int row = m0 + rl, col = n0 + cl;
        if (row < M && col < N){
            union { short s8[8]; uint4 v; } u;
            u.v = *(uint4*)&Ct[rl*CS + cl];
            if (R){
                const bf16* rp = &R[(size_t)row*ldc + col];
                #pragma unroll
                for (int e=0;e<8;e++){
                    float v = b2f((unsigned short)u.s8[e]) + tof(rp[e]);
                    u.s8[e] = (short)__bfloat16_as_ushort(tob(v));
                }
            }
            *(uint4*)&C[(size_t)row*ldc + col] = u.v;
        }
    }
}

__global__ __launch_bounds__(256) void k_gemm2(const bf16* __restrict__ A, const bf16* __restrict__ Bt,
        const float* __restrict__ bias, const bf16* __restrict__ R, bf16* __restrict__ C,
        int M, int N, int Kp, int ldc, int relu_out){
    __shared__ __align__(16) char ldsbuf[34816];
    gemm_body(A, Bt, bias, R, C, M, N, Kp, ldc, relu_out, (short*)ldsbuf);
}

// z-paired GEMM: blockIdx.z selects arg set (independent chains, one dispatch, better fill)
__global__ __launch_bounds__(256) void k_gemm2z(
        const bf16* __restrict__ A0, const bf16* __restrict__ A1,
        const bf16* __restrict__ Bt0, const bf16* __restrict__ Bt1,
        const float* __restrict__ bias0, const float* __restrict__ bias1,
        const bf16* __restrict__ R0, const bf16* __restrict__ R1,
        bf16* __restrict__ C0, bf16* __restrict__ C1,
        int M, int N, int Kp, int ldc, int relu0, int relu1){
    __shared__ __align__(16) char ldsbuf[34816];
    if (blockIdx.z == 0) gemm_body(A0, Bt0, bias0, R0, C0, M, N, Kp, ldc, relu0, (short*)ldsbuf);
    else                 gemm_body(A1, Bt1, bias1, R1, C1, M, N, Kp, ldc, relu1, (short*)ldsbuf);
}

// ---------------- old-style MFMA machinery (kept for k_sim_mfma) ----------------
__device__ __forceinline__ void stage_tile(const short* __restrict__ P, int RB, int K, int r0, int k0,
                                           short (*lds)[64][8], int tid){
    #pragma unroll
    for (int s=0;s<2;s++){
        int seg = tid*2+s;
        int row = seg>>2, q = seg&3;
        int gr = r0 + row;
        int gk = k0 + q*8;
        union { short s8[8]; uint4 v; } u;
        if (gr < RB && gk + 8 <= K){
            const uint2* p = (const uint2*)(P + (size_t)gr*K + gk);
            uint2 lo = p[0], hi = p[1];
            u.v.x = lo.x; u.v.y = lo.y; u.v.z = hi.x; u.v.w = hi.y;
        } else {
            #pragma unroll
            for (int j=0;j<8;j++){
                int kk = gk + j;
                u.s8[j] = (gr < RB && kk < K) ? P[(size_t)gr*K + kk] : (short)0;
            }
        }
        *(uint4*)&lds[row>>4][q*16 + (row&15)][0] = u.v;
    }
}

// sim_cp[i][j] = exp( (hr_i . henv_j) * 5 / (na_i*nc_j + 1e-8) )
__global__ __launch_bounds__(256) void k_sim_mfma(const bf16* __restrict__ A, const bf16* __restrict__ Bt,
                      const float* __restrict__ na, const float* __restrict__ nc, float* __restrict__ C){
    __shared__ __align__(16) short Asl[8][64][8];
    __shared__ __align__(16) short Bsl[8][64][8];
    int tid = threadIdx.x;
    int wave = tid >> 6, lane = tid & 63;
    int wm = wave >> 1, wn = wave & 1;
    int m0 = blockIdx.y*128, n0 = blockIdx.x*128;
    f32x4 acc[4][4];
    #pragma unroll
    for (int i=0;i<4;i++){
        #pragma unroll
        for (int j=0;j<4;j++) acc[i][j] = (f32x4){0.f,0.f,0.f,0.f};
    }
    for (int k0=0; k0<SEM; k0+=32){
        stage_tile((const short*)A,  NG, SEM, m0, k0, Asl, tid);
        stage_tile((const short*)Bt, NG, SEM, n0, k0, Bsl, tid);
        __syncthreads();
        bf16x8 af[4], bfr[4];
        #pragma unroll
        for (int i=0;i<4;i++) af[i]  = *(const bf16x8*)&Asl[wm*4+i][lane][0];
        #pragma unroll
        for (int j=0;j<4;j++) bfr[j] = *(const bf16x8*)&Bsl[wn*4+j][lane][0];
        #pragma unroll
        for (int i=0;i<4;i++){
            #pragma unroll
            for (int j=0;j<4;j++)
                acc[i][j] = __builtin_amdgcn_mfma_f32_16x16x32_bf16(af[i], bfr[j], acc[i][j], 0, 0, 0);
        }
        __syncthreads();
    }
    int lq = lane >> 4, lr = lane & 15;
    #pragma unroll
    for (int i=0;i<4;i++){
        int rb = m0 + (wm*4+i)*16 + lq*4;
        #pragma unroll
        for (int j=0;j<4;j++){
            int col = n0 + (wn*4+j)*16 + lr;
            if (col >= NG) continue;
            float ncj = nc[col];
            #pragma unroll
            for (int r=0;r<4;r++){
                int row = rb + r;
                if (row >= NG) continue;
                C[(size_t)row*NG+col] = expf(acc[i][j][r] * 5.0f / (na[row]*ncj + 1e-8f));
            }
        }
    }
}

// ---------------- gate ----------------
__global__ __launch_bounds__(256) void k_gate(const bf16* __restrict__ mid, const float* __restrict__ Wg2,
                      const float* __restrict__ bg2, const float* __restrict__ gumbel, float* __restrict__ gate){
    int gw = blockIdx.x*4 + (threadIdx.x >> 6);
    int lane = threadIdx.x & 63;
    if (gw >= NN) return;
    float s0=0.f, s1=0.f;
    for (int i=lane;i<HID;i+=64){
        float h = tof(mid[(size_t)gw*SHID+i]);
        s0 += h * Wg2[i*2];
        s1 += h * Wg2[i*2+1];
    }
    for (int off=32; off>0; off>>=1){ s0 += __shfl_down(s0, off); s1 += __shfl_down(s1, off); }
    if (lane==0){
        float l0 = s0 + bg2[0] + gumbel[gw*2];
        float l1 = s1 + bg2[1] + gumbel[gw*2+1];
        float m = fmaxf(l0,l1);
        float e0 = expf(l0-m), e1 = expf(l1-m);
        gate[gw] = e1/(e0+e1);
    }
}

// ---------------- segment pooling ----------------
__global__ __launch_bounds__(320) void k_pool(const bf16* __restrict__ h, const float* __restrict__ gate,
                      const int* __restrict__ gstart, float* __restrict__ sumh, float* __restrict__ sumgh){
    int g = blockIdx.x, c = threadIdx.x;
    if (c >= EMB) return;
    int n0 = gstart[g], n1 = gstart[g+1];
    float sh=0.f, sg=0.f;
    for (int n=n0;n<n1;n++){
        float v = tof(h[(size_t)n*SEM+c]);
        float gt = gate[n];
        sh += v; sg += gt*v;
    }
    sumh[g*EMB+c] = sh; sumgh[g*EMB+c] = sg;
}

__global__ __launch_bounds__(256) void k_rnum(const float* __restrict__ gate, const int* __restrict__ gstart,
                      float* __restrict__ rnum, float* __restrict__ cntf){
    int g = blockIdx.x*4 + (threadIdx.x >> 6);
    int lane = threadIdx.x & 63;
    if (g >= NG) return;
    int n0 = gstart[g], n1 = gstart[g+1];
    float s=0.f;
    for (int n=n0+lane;n<n1;n+=64) s += gate[n];
    for (int off=32; off>0; off>>=1) s += __shfl_down(s, off);
    if (lane==0){ rnum[g] = s; cntf[g] = (float)(n1-n0); }
}

__global__ __launch_bounds__(256) void k_mean(const float* __restrict__ sumh, const float* __restrict__ sumgh,
                      const float* __restrict__ cntf, float* __restrict__ hr, float* __restrict__ henv,
                      float* __restrict__ hout, bf16* __restrict__ hrb, bf16* __restrict__ henvb){
    int idx = blockIdx.x*256 + threadIdx.x;
    if (idx >= NG*SEM) return;
    int g = idx / SEM, c = idx - g*SEM;
    if (c < EMB){
        int o = g*EMB + c;
        float inv = 1.f / fmaxf(cntf[g], 1.f);
        float sh = sumh[o], sg = sumgh[o];
        float r = sg*inv, e = (sh-sg)*inv;
        hr[o] = r; henv[o] = e; hout[o] = sh*inv;
        hrb[idx] = tob(r); henvb[idx] = tob(e);
    } else {
        hrb[idx] = tob(0.f); henvb[idx] = tob(0.f);   // zero pads (henvb is a B-operand!)
    }
}

__global__ __launch_bounds__(256) void k_pbuild(const float* __restrict__ hr, const float* __restrict__ henv,
                      const int* __restrict__ perm, bf16* __restrict__ P){
    int idx = blockIdx.x*256 + threadIdx.x;
    if (idx >= NG*SEM) return;
    int g = idx / SEM, c = idx - g*SEM;
    if (c < EMB){
        float v = hr[g*EMB+c];
        P[idx] = tob(v);
        P[(size_t)(NG+g)*SEM + c] = tob(v + henv[(size_t)perm[g]*EMB + c]);
    } else {
        P[idx] = tob(0.f);
        P[(size_t)(NG+g)*SEM + c] = tob(0.f);
    }
}

__global__ __launch_bounds__(256) void k_norm(const float* __restrict__ hr, const float* __restrict__ henv,
                      const float* __restrict__ hout, float* __restrict__ na, float* __restrict__ nc,
                      float* __restrict__ pos){
    int g = blockIdx.x*4 + (threadIdx.x >> 6);
    int lane = threadIdx.x & 63;
    if (g >= NG) return;
    float srr=0.f, soo=0.f, see=0.f, sro=0.f;
    for (int c=lane;c<EMB;c+=64){
        float r=hr[g*EMB+c], o=hout[g*EMB+c], e=henv[g*EMB+c];
        srr += r*r; soo += o*o; see += e*e; sro += r*o;
    }
    for (int off=32; off>0; off>>=1){
        srr += __shfl_down(srr,off); soo += __shfl_down(soo,off);
        see += __shfl_down(see,off); sro += __shfl_down(sro,off);
    }
    if (lane==0){
        float a = sqrtf(srr), b = sqrtf(soo), c2 = sqrtf(see);
        na[g] = a; nc[g] = c2;
        pos[g] = expf(sro/(a*b + 1e-8f) * 5.0f);
    }
}

__global__ __launch_bounds__(256) void k_rowsum(const float* __restrict__ simcp, float* __restrict__ S){
    __shared__ float red[256];
    int g = blockIdx.x, t = threadIdx.x;
    float s = 0.f;
    for (int j=t;j<NG;j+=256) s += simcp[(size_t)g*NG+j];
    red[t]=s; __syncthreads();
    for (int off=128; off>0; off>>=1){ if (t<off) red[t]+=red[t+off]; __syncthreads(); }
    if (t==0) S[g]=red[0];
}

__global__ __launch_bounds__(256) void k_pred(const bf16* __restrict__ hidP, const float* __restrict__ Wp2,
                      const float* __restrict__ bp2, float* __restrict__ out){
    int r = blockIdx.x*4 + (threadIdx.x >> 6);
    int lane = threadIdx.x & 63;
    if (r >= 2*NG) return;
    float acc[NTASK];
    #pragma unroll
    for (int t=0;t<NTASK;t++) acc[t] = 0.f;
    for (int i=lane;i<HID;i+=64){
        float h = tof(hidP[(size_t)r*SHID+i]);
        const float4* wp = (const float4*)&Wp2[i*NTASK];
        float4 wa = wp[0], wb = wp[1], wc = wp[2];
        acc[0]+=h*wa.x; acc[1]+=h*wa.y; acc[2]+=h*wa.z; acc[3]+=h*wa.w;
        acc[4]+=h*wb.x; acc[5]+=h*wb.y; acc[6]+=h*wb.z; acc[7]+=h*wb.w;
        acc[8]+=h*wc.x; acc[9]+=h*wc.y; acc[10]+=h*wc.z; acc[11]+=h*wc.w;
    }
    #pragma unroll
    for (int t=0;t<NTASK;t++){
        for (int off=32; off>0; off>>=1) acc[t] += __shfl_down(acc[t], off);
    }
    if (lane==0){
        float* dst = (r < NG) ? &out[NG*NTASK + r*NTASK] : &out[(r-NG)*NTASK];
        #pragma unroll
        for (int t=0;t<NTASK;t++) dst[t] = acc[t] + bp2[t];
    }
}

__global__ __launch_bounds__(256) void k_loss(const float* __restrict__ cntf, const float* __restrict__ rnum,
                      const float* __restrict__ pos, const float* __restrict__ S, float* __restrict__ out){
    __shared__ float ra[256], rb[256];
    int t = threadIdx.x;
    float a=0.f, b=0.f;
    for (int g=t; g<NG; g+=256){
        float r = rnum[g] + 1e-8f;
        float e = (cntf[g] - rnum[g]) + 1e-8f;
        a += fabsf(r/(r+e) - 0.4f);
        float p = pos[g];
        b += -logf(p/(S[g]+p));
    }
    ra[t]=a; rb[t]=b; __syncthreads();
    for (int off=128; off>0; off>>=1){ if (t<off){ ra[t]+=ra[t+off]; rb[t]+=rb[t+off]; } __syncthreads(); }
    if (t==0){
        out[2*NG*NTASK]   = ra[0]/NG;
        out[2*NG*NTASK+1] = rb[0]/NG;
    }
}

extern "C" void kernel_launch(void* const* d_in, const int* in_sizes, int n_in,
                              void* d_out, int out_size, void* d_ws, size_t ws_size,
                              hipStream_t stream) {
    const float* x      = (const float*)d_in[0];
    const float* eattr  = (const float*)d_in[1];
    const int*   eidx   = (const int*)d_in[2];
    const int*   batch  = (const int*)d_in[3];
    const float* gumbel = (const float*)d_in[4];
    const int*   perm   = (const int*)d_in[5];
    const float* W_enc  = (const float*)d_in[6];
    const float* b_enc  = (const float*)d_in[7];
    const float* We_g   = (const float*)d_in[8];
    const float* be_g   = (const float*)d_in[9];
    const float* W1_g   = (const float*)d_in[10];
    const float* b1_g   = (const float*)d_in[11];
    const float* W2_g   = (const float*)d_in[12];
    const float* b2_g   = (const float*)d_in[13];
    const float* We_r   = (const float*)d_in[14];
    const float* be_r   = (const float*)d_in[15];
    const float* W1_r   = (const float*)d_in[16];
    const float* b1_r   = (const float*)d_in[17];
    const float* W2_r   = (const float*)d_in[18];
    const float* b2_r   = (const float*)d_in[19];
    const float* Wg1    = (const float*)d_in[20];
    const float* bg1    = (const float*)d_in[21];
    const float* Wg2    = (const float*)d_in[22];
    const float* bg2    = (const float*)d_in[23];
    const float* Wp1    = (const float*)d_in[24];
    const float* bp1    = (const float*)d_in[25];
    const float* Wp2    = (const float*)d_in[26];
    const float* bp2    = (const float*)d_in[27];
    float* out = (float*)d_out;

    const int* srcArr = eidx;
    const int* dstArr = eidx + NE;

    // ---- workspace (bump allocator, 256B aligned); ~205 MB of 268 ----
    char* w = (char*)d_ws;
    size_t off = 0;
    auto alloc = [&](size_t bytes)->char*{ char* p = w + off; off += (bytes + 255) & ~(size_t)255; return p; };
    bf16* xfeat = (bf16*)alloc((size_t)NN*SEM*2);
    bf16* cur_r = (bf16*)alloc((size_t)NN*SEM*2);
    bf16* cur_g = (bf16*)alloc((size_t)NN*SEM*2);
    bf16* apx   = (bf16*)alloc((size_t)NN*SEM*2);     // rationale-side agg out
    bf16* apx2  = (bf16*)alloc((size_t)NN*SEM*2);     // encoder-side agg out
    char* midc  = alloc((size_t)NN*SHID*2);           // mid_r; reused after trunk:
    bf16* mid_r = (bf16*)midc;
    float* simcp = (float*)midc;                      // NG*NG*4 = 9 MB
    bf16* Pbuf   = (bf16*)(midc + 12*1024*1024);
    bf16* hidP   = (bf16*)(midc + 20*1024*1024);
    bf16* mid_g = (bf16*)alloc((size_t)NN*SHID*2);
    bf16* wt1g  = (bf16*)alloc((size_t)5*HID*SEM*2);
    bf16* wt2g  = (bf16*)alloc((size_t)5*EMB*SHID*2);
    bf16* wt1r  = (bf16*)alloc((size_t)2*HID*SEM*2);
    bf16* wt2r  = (bf16*)alloc((size_t)2*EMB*SHID*2);
    bf16* wtg1  = (bf16*)alloc((size_t)HID*SEM*2);
    bf16* wtp1  = (bf16*)alloc((size_t)HID*SEM*2);
    float4* epack = (float4*)alloc((size_t)NE*16);
    float* gate  = (float*)alloc((size_t)NN*4);
    float* sumh  = (float*)alloc((size_t)NG*EMB*4);
    float* sumgh = (float*)alloc((size_t)NG*EMB*4);
    float* hr    = (float*)alloc((size_t)NG*EMB*4);
    float* henv  = (float*)alloc((size_t)NG*EMB*4);
    float* hout  = (float*)alloc((size_t)NG*EMB*4);
    bf16* hrb    = (bf16*)alloc((size_t)NG*SEM*2);
    bf16* henvb  = (bf16*)alloc((size_t)NG*SEM*2);
    float* rnum  = (float*)alloc(NG*4);
    float* cntf  = (float*)alloc(NG*4);
    float* na    = (float*)alloc(NG*4);
    float* ncv   = (float*)alloc(NG*4);
    float* pos   = (float*)alloc(NG*4);
    float* Ssum  = (float*)alloc(NG*4);
    int* deg     = (int*)alloc((size_t)NN*4);
    int* indptr  = (int*)alloc((size_t)(NN+1)*4);
    int* cursor  = (int*)alloc((size_t)NN*4);
    int* eid     = (int*)alloc((size_t)NE*4);
    int* gstart  = (int*)alloc((size_t)(NG+1)*4);
    int* bsum    = (int*)alloc((size_t)NBLK_SCAN*4);
    int* boff    = (int*)alloc((size_t)NBLK_SCAN*4);

    const int NB_NE  = (NE+255)/256;
    const int NB_NC  = (NN*EMB+255)/256;
    const int NB_AG  = (NN*CG+255)/256;
    const int NB_GP  = (NG*SEM+255)/256;

    // ---- CSR build + edge pack + graph ranges ----
    k_zero_i <<<(NN+255)/256, 256, 0, stream>>>(deg, NN);
    k_hist   <<<NB_NE, 256, 0, stream>>>(dstArr, deg);
    k_scanA  <<<NBLK_SCAN, 256, 0, stream>>>(deg, bsum);
    k_scanB  <<<1, 128, 0, stream>>>(bsum, boff);
    k_scanC  <<<NBLK_SCAN, 256, 0, stream>>>(deg, boff, indptr, cursor);
    k_scatter<<<NB_NE, 256, 0, stream>>>(dstArr, cursor, eid);
    k_eprep  <<<NB_NE, 256, 0, stream>>>(eid, srcArr, eattr, epack);
    k_gstart <<<(NG+256)/256, 256, 0, stream>>>(batch, gstart);

    // ---- weight prep (transpose + bf16 + K-pad zeros) ----
    {
        dim3 g1t((HID+31)/32, SEM/32, 5);
        dim3 g2t((EMB+31)/32, SHID/32, 5);
        k_wprep<<<g1t, 256, 0, stream>>>(W1_g, wt1g, EMB, SEM, HID);
        k_wprep<<<g2t, 256, 0, stream>>>(W2_g, wt2g, HID, SHID, EMB);
        dim3 g1t2((HID+31)/32, SEM/32, 2);
        dim3 g2t2((EMB+31)/32, SHID/32, 2);
        k_wprep<<<g1t2, 256, 0, stream>>>(W1_r, wt1r, EMB, SEM, HID);
        k_wprep<<<g2t2, 256, 0, stream>>>(W2_r, wt2r, HID, SHID, EMB);
        dim3 g1t1((HID+31)/32, SEM/32, 1);
        k_wprep<<<g1t1, 256, 0, stream>>>(Wg1, wtg1, EMB, SEM, HID);
        k_wprep<<<g1t1, 256, 0, stream>>>(Wp1, wtp1, EMB, SEM, HID);
    }

    dim3 gm1z((HID+127)/128, (NN+127)/128, 2);  // paired N=600 GEMMs
    dim3 gm2z((EMB+127)/128, (NN+127)/128, 2);  // paired N=300 GEMMs
    dim3 gm1((HID+127)/128, (NN+127)/128);      // solo
    dim3 gm2((EMB+127)/128, (NN+127)/128);
    dim3 gagz(NB_AG, 1, 2);

    // ---- node encoder (once) ----
    k_encoder<<<NB_NC, 256, 0, stream>>>(x, W_enc, b_enc, xfeat);

    // ---- layer 0 (both stacks): shared-gather dual agg, then paired GEMMs ----
    k_agg4d<<<NB_AG, 256, 0, stream>>>(xfeat, We_r, be_r, We_g, be_g, epack, indptr, apx, apx2);
    k_gemm2z<<<gm1z, 256, 0, stream>>>(apx, apx2, wt1r, wt1g, b1_r, b1_g,
                                       nullptr, nullptr, mid_r, mid_g, NN, HID, SEM, SHID, 1, 1);
    k_gemm2z<<<gm2z, 256, 0, stream>>>(mid_r, mid_g, wt2r, wt2g, b2_r, b2_g,
                                       xfeat, xfeat, cur_r, cur_g, NN, EMB, SHID, SEM, 1, 1);

    // ---- layer 1 (both stacks): paired agg + paired GEMMs ----
    k_agg4z<<<gagz, 256, 0, stream>>>(cur_r, cur_g, We_r + 3*EMB, We_g + 3*EMB, be_r + EMB, be_g + EMB,
                                      epack, indptr, apx, apx2);
    k_gemm2z<<<gm1z, 256, 0, stream>>>(apx, apx2, wt1r + (size_t)HID*SEM, wt1g + (size_t)HID*SEM,
                                       b1_r + HID, b1_g + HID, nullptr, nullptr, mid_r, mid_g,
                                       NN, HID, SEM, SHID, 1, 1);
    k_gemm2z<<<gm2z, 256, 0, stream>>>(mid_r, mid_g, wt2r + (size_t)EMB*SHID, wt2g + (size_t)EMB*SHID,
                                       b2_r + EMB, b2_g + EMB, cur_r, cur_g, cur_r, cur_g,
                                       NN, EMB, SHID, SEM, 0, 1);   // rationale last layer: no relu

    // ---- encoder layer 2 agg; then pair (gate GEMM, encoder-l2 GEMM1) ----
    k_agg4 <<<NB_AG, 256, 0, stream>>>(cur_g, We_g + 2*3*EMB, be_g + 2*EMB, epack, indptr, apx2);
    k_gemm2z<<<gm1z, 256, 0, stream>>>(cur_r, apx2, wtg1, wt1g + (size_t)2*HID*SEM,
                                       bg1, b1_g + 2*HID, nullptr, nullptr, mid_r, mid_g,
                                       NN, HID, SEM, SHID, 1, 1);
    k_gemm2<<<gm2, 256, 0, stream>>>(mid_g, wt2g + (size_t)2*EMB*SHID, b2_g + 2*EMB, cur_g, cur_g,
                                     NN, EMB, SHID, SEM, 1);
    k_gate<<<NN/4, 256, 0, stream>>>(mid_r, Wg2, bg2, gumbel, gate);

    // ---- encoder layers 3,4 (solo) ----
    for (int l=3; l<5; l++){
        k_agg4 <<<NB_AG, 256, 0, stream>>>(cur_g, We_g + l*3*EMB, be_g + l*EMB, epack, indptr, apx2);
        k_gemm2<<<gm1, 256, 0, stream>>>(apx2, wt1g + (size_t)l*HID*SEM, b1_g + l*HID, nullptr, mid_g,
                                         NN, HID, SEM, SHID, 1);
        k_gemm2<<<gm2, 256, 0, stream>>>(mid_g, wt2g + (size_t)l*EMB*SHID, b2_g + l*EMB, cur_g, cur_g,
                                         NN, EMB, SHID, SEM, (l<4)?1:0);
    }
    // cur_g now holds h_node (bf16, stride SEM)

    // ---- pooling (segment scan) ----
    k_pool  <<<NG, 320, 0, stream>>>(cur_g, gate, gstart, sumh, sumgh);
    k_rnum  <<<(NG+3)/4, 256, 0, stream>>>(gate, gstart, rnum, cntf);
    k_mean  <<<NB_GP, 256, 0, stream>>>(sumh, sumgh, cntf, hr, henv, hout, hrb, henvb);
    k_pbuild<<<NB_GP, 256, 0, stream>>>(hr, henv, perm, Pbuf);
    k_norm  <<<(NG+3)/4, 256, 0, stream>>>(hr, henv, hout, na, ncv, pos);
    // ---- contrastive sim (MFMA) ----
    dim3 gsim((NG+127)/128, (NG+127)/128);
    k_sim_mfma<<<gsim, 256, 0, stream>>>(hrb, henvb, na, ncv, simcp);
    k_rowsum<<<NG, 256, 0, stream>>>(simcp, Ssum);
    // ---- head (MFMA) ----
    dim3 gph((HID+127)/128, (2*NG+127)/128);
    k_gemm2<<<gph, 256, 0, stream>>>(Pbuf, wtp1, bp1, nullptr, hidP, 2*NG, HID, SEM, SHID, 1);
    k_pred  <<<(2*NG+3)/4, 256, 0, stream>>>(hidP, Wp2, bp2, out);
    k_loss  <<<1, 256, 0, stream>>>(cntf, rnum, pos, Ssum, out);
}